// Round 9
// baseline (85.831 us; speedup 1.0000x reference)
//
#include <hip/hip_runtime.h>

#define EPSF 1e-6f

typedef __bf16 bf16x8 __attribute__((ext_vector_type(8)));
typedef float f32x4 __attribute__((ext_vector_type(4)));
typedef __attribute__((address_space(3))) unsigned int as3_uint;
typedef __attribute__((address_space(1))) const unsigned int as1_uint;

__device__ __forceinline__ unsigned short f2bf(float f) {
  unsigned int u = __builtin_bit_cast(unsigned int, f);
  u += 0x7fffu + ((u >> 16) & 1u);
  return (unsigned short)(u >> 16);
}
__device__ __forceinline__ float bf2f(unsigned short u) {
  unsigned int v = (unsigned int)u << 16;
  return __builtin_bit_cast(float, v);
}

// ------- fused: log_map(x) -> vbf (blocks 0..2047) | weight conv (blocks 2048..6143) -------
__global__ __launch_bounds__(256) void prep_and_conv(
    const float* __restrict__ x, const float* __restrict__ Wq,
    const float* __restrict__ Wk, const float* __restrict__ Wv,
    const float* __restrict__ Wo, unsigned short* __restrict__ vbf,
    unsigned short* __restrict__ wqk, unsigned short* __restrict__ wvb,
    unsigned short* __restrict__ wob) {
  int bid = blockIdx.x;
  int tid = threadIdx.x;
  if (bid >= 2048) {
    int t = bid - 2048;
    int y = t >> 10;
    const float* src = (y == 0) ? Wq : (y == 1) ? Wk : (y == 2) ? Wv : Wo;
    unsigned short* dst = (y == 0) ? wqk : (y == 1) ? wqk + 1048576
                          : (y == 2) ? wvb : wob;
    int i = (t & 1023) * 256 + tid;
    f32x4 v = ((const f32x4*)src)[i];
    ushort4 o;
    o.x = f2bf(v[0]); o.y = f2bf(v[1]); o.z = f2bf(v[2]); o.w = f2bf(v[3]);
    ((ushort4*)dst)[i] = o;
    return;
  }
  int row = bid;
  const float* xr = x + (size_t)row * 1024;
  float vals[4];
  float ssq = 0.f;
#pragma unroll
  for (int i = 0; i < 4; ++i) {
    int c = tid + i * 256;
    float t = xr[c];
    if (c == 0) {
      vals[i] = 0.f;
    } else {
      t = fminf(fmaxf(t, -8.f), 8.f);
      vals[i] = t;
      ssq += t * t;
    }
  }
#pragma unroll
  for (int off = 32; off; off >>= 1) ssq += __shfl_xor(ssq, off);
  __shared__ float red[4];
  int wv = tid >> 6;
  if ((tid & 63) == 0) red[wv] = ssq;
  __syncthreads();
  ssq = red[0] + red[1] + red[2] + red[3];

  float y0 = sqrtf(1.f + ssq + EPSF);
  float xy = fminf(-y0, -(1.f + EPSF));
  float mxy = fmaxf(-xy, 1.f + EPSF);
  float dd = fmaxf(acoshf(mxy), 0.001f);
  float d0 = y0 + xy;
  float inn = ssq - d0 * d0;
  float dn = sqrtf(fmaxf(inn, EPSF));
  float inv = dd / (dn + EPSF);

  unsigned short* vr = vbf + (size_t)row * 1024;
#pragma unroll
  for (int i = 0; i < 4; ++i) {
    int c = tid + i * 256;
    float o = (c == 0) ? d0 * inv : vals[i] * inv;
    vr[c] = f2bf(o);
  }
}

// ---------- 128x128-tile GEMM body, double-buffered gload_lds staging ----------
__device__ __forceinline__ void gemm128_dbuf(
    const unsigned short* __restrict__ A, const unsigned short* __restrict__ Bw,
    int K, int row0, int col0, unsigned short* As, unsigned short* Bs,
    f32x4 (*acc)[4]) {
  int tid = threadIdx.x;
  int lane = tid & 63, w = tid >> 6;
  int wm = (w >> 1) * 64, wn = (w & 1) * 64;
  int lq = lane & 15, g = lane >> 4;
  const unsigned short* Ag =
      A + (size_t)(row0 + w * 8 + (lane >> 3)) * K + (lane & 7) * 8;
  const unsigned short* Bg =
      Bw + (size_t)(col0 + w * 8 + (lane >> 3)) * K + (lane & 7) * 8;

  auto stage = [&](int buf, int k0) {
#pragma unroll
    for (int it = 0; it < 4; ++it) {
      __builtin_amdgcn_global_load_lds(
          (as1_uint*)(Ag + (size_t)(it * 32) * K + k0),
          (as3_uint*)&As[buf * 8192 + (it * 32 + w * 8) * 64], 16, 0, 0);
      __builtin_amdgcn_global_load_lds(
          (as1_uint*)(Bg + (size_t)(it * 32) * K + k0),
          (as3_uint*)&Bs[buf * 8192 + (it * 32 + w * 8) * 64], 16, 0, 0);
    }
  };

  stage(0, 0);
  int buf = 0;
  for (int k0 = 0; k0 < K; k0 += 64) {
    __syncthreads();
    if (k0 + 64 < K) stage(buf ^ 1, k0 + 64);
#pragma unroll
    for (int ks = 0; ks < 2; ++ks) {
      bf16x8 af[4], bfr[4];
#pragma unroll
      for (int i = 0; i < 4; ++i)
        af[i] = *(const bf16x8*)&As[buf * 8192 + (wm + i * 16 + lq) * 64 + ks * 32 + g * 8];
#pragma unroll
      for (int j = 0; j < 4; ++j)
        bfr[j] = *(const bf16x8*)&Bs[buf * 8192 + (wn + j * 16 + lq) * 64 + ks * 32 + g * 8];
#pragma unroll
      for (int i = 0; i < 4; ++i)
#pragma unroll
        for (int j = 0; j < 4; ++j)
          acc[i][j] =
              __builtin_amdgcn_mfma_f32_16x16x32_bf16(af[i], bfr[j], acc[i][j], 0, 0, 0);
    }
    buf ^= 1;
  }
}

// QK gemm 128x128 (even bids, 256 tiles) | Vt gemm 128x64 (odd bids, 256 tiles)
// grid 512 = exactly 2 blocks/CU, balanced.
__global__ __launch_bounds__(256) void gemm_qkv(
    const unsigned short* __restrict__ vbf, const unsigned short* __restrict__ wqk,
    const unsigned short* __restrict__ wvb, unsigned short* __restrict__ qb,
    unsigned short* __restrict__ kb, unsigned short* __restrict__ vtb) {
  __shared__ unsigned short As[2 * 8192];
  __shared__ unsigned short Bs[2 * 8192];
  int tid = threadIdx.x;
  int lane = tid & 63, w = tid >> 6;
  int lq = lane & 15, g = lane >> 4;
  int bid = blockIdx.x;

  if ((bid & 1) == 0) {
    int q = bid >> 1;  // 0..255
    int wm = (w >> 1) * 64, wn = (w & 1) * 64;
    f32x4 acc[4][4] = {};
    int row0 = (q & 15) * 128, col0 = (q >> 4) * 128;
    gemm128_dbuf(vbf, wqk, 1024, row0, col0, As, Bs, acc);
    int headg = (col0 + wn) >> 6;  // 0..31 (0-15 q heads, 16-31 k heads)
    int qmode = (headg < 16) ? 1 : 0;
    unsigned short* dst = qmode ? qb : kb;
    size_t colb = (size_t)(headg & 15) * 64;
    float scale = qmode ? 0.125f : 1.f;
#pragma unroll
    for (int i = 0; i < 4; ++i)
#pragma unroll
      for (int r = 0; r < 4; ++r) {
        float s = 0.f;
#pragma unroll
        for (int j = 0; j < 4; ++j) {
          float vc = fminf(fmaxf(acc[i][j][r], -5.f), 5.f);
          s += (j == 0 && lq == 0) ? 0.f : vc * vc;  // exclude head col 0
        }
        s += __shfl_xor(s, 1);
        s += __shfl_xor(s, 2);
        s += __shfl_xor(s, 4);
        s += __shfl_xor(s, 8);
        float x0 = sqrtf(1.f + s + EPSF);
        int row = row0 + wm + i * 16 + g * 4 + r;
#pragma unroll
        for (int j = 0; j < 4; ++j) {
          float vc = fminf(fmaxf(acc[i][j][r], -5.f), 5.f);
          float o = (j == 0 && lq == 0) ? (qmode ? -x0 : x0) : vc;
          dst[(size_t)row * 1024 + colb + j * 16 + lq] = f2bf(o * scale);
        }
      }
  } else {
    int t = bid >> 1;  // 0..255 : Vt 128x64 tile
    int wm = (w >> 1) * 64, wn = (w & 1) * 32;
    int row0 = (t & 7) * 128, col0 = (t >> 3) * 64;
    f32x4 acc[4][2] = {};
    const unsigned short* Ag =
        wvb + (size_t)(row0 + w * 8 + (lane >> 3)) * 1024 + (lane & 7) * 8;
    const unsigned short* Bg =
        vbf + (size_t)(col0 + w * 8 + (lane >> 3)) * 1024 + (lane & 7) * 8;
    auto stage = [&](int buf, int k0) {
#pragma unroll
      for (int it = 0; it < 4; ++it)
        __builtin_amdgcn_global_load_lds(
            (as1_uint*)(Ag + (size_t)(it * 32) * 1024 + k0),
            (as3_uint*)&As[buf * 8192 + (it * 32 + w * 8) * 64], 16, 0, 0);
#pragma unroll
      for (int it = 0; it < 2; ++it)
        __builtin_amdgcn_global_load_lds(
            (as1_uint*)(Bg + (size_t)(it * 32) * 1024 + k0),
            (as3_uint*)&Bs[buf * 4096 + (it * 32 + w * 8) * 64], 16, 0, 0);
    };
    stage(0, 0);
    int buf = 0;
    for (int k0 = 0; k0 < 1024; k0 += 64) {
      __syncthreads();
      if (k0 + 64 < 1024) stage(buf ^ 1, k0 + 64);
#pragma unroll
      for (int ks = 0; ks < 2; ++ks) {
        bf16x8 af[4], bfr[2];
#pragma unroll
        for (int i = 0; i < 4; ++i)
          af[i] = *(const bf16x8*)&As[buf * 8192 + (wm + i * 16 + lq) * 64 + ks * 32 + g * 8];
#pragma unroll
        for (int j = 0; j < 2; ++j)
          bfr[j] = *(const bf16x8*)&Bs[buf * 4096 + (wn + j * 16 + lq) * 64 + ks * 32 + g * 8];
#pragma unroll
        for (int i = 0; i < 4; ++i)
#pragma unroll
          for (int j = 0; j < 2; ++j)
            acc[i][j] =
                __builtin_amdgcn_mfma_f32_16x16x32_bf16(af[i], bfr[j], acc[i][j], 0, 0, 0);
      }
      buf ^= 1;
    }
#pragma unroll
    for (int i = 0; i < 4; ++i)
#pragma unroll
      for (int j = 0; j < 2; ++j)
#pragma unroll
        for (int r = 0; r < 4; ++r)
          vtb[(size_t)(row0 + wm + i * 16 + g * 4 + r) * 2048 + col0 + wn + j * 16 + lq] =
              f2bf(acc[i][j][r]);
  }
}

// Wo gemm: BM=128 BN=64, dbuf staging; 256 blocks
__global__ __launch_bounds__(256) void gemm_wo(
    const unsigned short* __restrict__ A, const unsigned short* __restrict__ Bw,
    unsigned short* __restrict__ C) {
  __shared__ unsigned short As[2 * 8192];
  __shared__ unsigned short Bs[2 * 4096];
  int tid = threadIdx.x;
  int lane = tid & 63, w = tid >> 6;
  int wm = (w >> 1) * 64, wn = (w & 1) * 32;
  int lq = lane & 15, g = lane >> 4;
  int row0 = (blockIdx.x & 15) * 128, col0 = (blockIdx.x >> 4) * 64;
  f32x4 acc[4][2] = {};
  const unsigned short* Ag =
      A + (size_t)(row0 + w * 8 + (lane >> 3)) * 1024 + (lane & 7) * 8;
  const unsigned short* Bg =
      Bw + (size_t)(col0 + w * 8 + (lane >> 3)) * 1024 + (lane & 7) * 8;

  auto stage = [&](int buf, int k0) {
#pragma unroll
    for (int it = 0; it < 4; ++it)
      __builtin_amdgcn_global_load_lds(
          (as1_uint*)(Ag + (size_t)(it * 32) * 1024 + k0),
          (as3_uint*)&As[buf * 8192 + (it * 32 + w * 8) * 64], 16, 0, 0);
#pragma unroll
    for (int it = 0; it < 2; ++it)
      __builtin_amdgcn_global_load_lds(
          (as1_uint*)(Bg + (size_t)(it * 32) * 1024 + k0),
          (as3_uint*)&Bs[buf * 4096 + (it * 32 + w * 8) * 64], 16, 0, 0);
  };

  stage(0, 0);
  int buf = 0;
  for (int k0 = 0; k0 < 1024; k0 += 64) {
    __syncthreads();
    if (k0 + 64 < 1024) stage(buf ^ 1, k0 + 64);
#pragma unroll
    for (int ks = 0; ks < 2; ++ks) {
      bf16x8 af[4], bfr[2];
#pragma unroll
      for (int i = 0; i < 4; ++i)
        af[i] = *(const bf16x8*)&As[buf * 8192 + (wm + i * 16 + lq) * 64 + ks * 32 + g * 8];
#pragma unroll
      for (int j = 0; j < 2; ++j)
        bfr[j] = *(const bf16x8*)&Bs[buf * 4096 + (wn + j * 16 + lq) * 64 + ks * 32 + g * 8];
#pragma unroll
      for (int i = 0; i < 4; ++i)
#pragma unroll
        for (int j = 0; j < 2; ++j)
          acc[i][j] =
              __builtin_amdgcn_mfma_f32_16x16x32_bf16(af[i], bfr[j], acc[i][j], 0, 0, 0);
    }
    buf ^= 1;
  }
#pragma unroll
  for (int i = 0; i < 4; ++i)
#pragma unroll
    for (int j = 0; j < 2; ++j)
#pragma unroll
      for (int r = 0; r < 4; ++r)
        C[(size_t)(row0 + wm + i * 16 + g * 4 + r) * 1024 + col0 + wn + j * 16 + lq] =
            f2bf(acc[i][j][r]);
}

// ---- MFMA flash attention: QBLK=128 (8 waves), KVBLK=64, gload_lds dbuf,
//      XCD-grouped, defer-max, setprio ----
__global__ __launch_bounds__(512) void attn_mfma(
    const unsigned short* __restrict__ Qb, const unsigned short* __restrict__ Kb,
    const unsigned short* __restrict__ Vtb, unsigned short* __restrict__ Obf) {
  __shared__ unsigned short Ks[2][64 * 64];
  __shared__ unsigned short Vs[2][64 * 64];
  __shared__ unsigned short Ps[8 * 16 * 64];
  int tid = threadIdx.x;
  int lane = tid & 63, w = tid >> 6;  // 8 waves
  int g = lane >> 4, lq = lane & 15;
  // XCD grouping: all 8 q-blocks of one (b,h) share bid%8
  int bid = blockIdx.x;
  int idx = bid >> 3;               // 0..31
  int bh = (bid & 7) * 4 + (idx & 3);
  int qt = idx >> 2;                // 0..7
  int b = bh >> 4, h = bh & 15;

  const unsigned short* qrow =
      Qb + (size_t)(b * 1024 + qt * 128 + w * 16 + lq) * 1024 + h * 64;
  bf16x8 qf0 = *(const bf16x8*)(qrow + g * 8);
  bf16x8 qf1 = *(const bf16x8*)(qrow + 32 + g * 8);

  float mreg = -1e30f, lreg = 0.f;
  f32x4 acc[4] = {};
  unsigned short* Pw = Ps + w * 16 * 64;
  int sx = 8 * (lq & 7);

  const unsigned short* Ksrc = Kb + (size_t)(b * 1024) * 1024 + h * 64;
  const unsigned short* Vsrc = Vtb + (size_t)(h * 64) * 2048 + b * 1024;

  // staging: wave w covers LDS rows w*8+srow (w=0..7 -> all 64), slot lane&7
  int srow = lane >> 3;
  int scg = (lane & 7) ^ srow;  // pre-swizzled global source (row&7 == srow)
  const unsigned short* Kp = Ksrc + (size_t)(w * 8 + srow) * 1024 + scg * 8;
  const unsigned short* Vp = Vsrc + (size_t)(w * 8 + srow) * 2048 + scg * 8;

  auto stage = [&](int buf, int kt) {
    __builtin_amdgcn_global_load_lds(
        (as1_uint*)(Kp + (size_t)(kt * 64) * 1024),
        (as3_uint*)&Ks[buf][(w * 8) * 64], 16, 0, 0);
    __builtin_amdgcn_global_load_lds(
        (as1_uint*)(Vp + kt * 64),
        (as3_uint*)&Vs[buf][(w * 8) * 64], 16, 0, 0);
  };

  auto compute = [&](int buf) {
    f32x4 st[4];
    __builtin_amdgcn_s_setprio(1);
#pragma unroll
    for (int i = 0; i < 4; ++i) {
      int ro = i * 16 + lq;
      int rb = ro * 64, xx = 8 * (ro & 7);
      bf16x8 a0 = *(const bf16x8*)&Ks[buf][rb + ((g * 8) ^ xx)];
      bf16x8 a1 = *(const bf16x8*)&Ks[buf][rb + ((32 + g * 8) ^ xx)];
      f32x4 z = {};
      z = __builtin_amdgcn_mfma_f32_16x16x32_bf16(a0, qf0, z, 0, 0, 0);
      st[i] = __builtin_amdgcn_mfma_f32_16x16x32_bf16(a1, qf1, z, 0, 0, 0);
    }
    __builtin_amdgcn_s_setprio(0);
    float pmax = st[0][0];
#pragma unroll
    for (int i = 0; i < 4; ++i)
#pragma unroll
      for (int r = 0; r < 4; ++r) pmax = fmaxf(pmax, st[i][r]);
    pmax = fmaxf(pmax, __shfl_xor(pmax, 16));
    pmax = fmaxf(pmax, __shfl_xor(pmax, 32));
    if (__any(pmax > mreg + 8.f)) {
      float nm = fmaxf(mreg, pmax);
      float sc_ = __expf(mreg - nm);
      mreg = nm;
      lreg *= sc_;
      float scr[4];
#pragma unroll
      for (int r = 0; r < 4; ++r) scr[r] = __shfl(sc_, g * 4 + r);
#pragma unroll
      for (int jj = 0; jj < 4; ++jj)
#pragma unroll
        for (int r = 0; r < 4; ++r) acc[jj][r] *= scr[r];
    }
    float ps = 0.f;
#pragma unroll
    for (int i = 0; i < 4; ++i) {
      ushort4 pq;
      float p0 = __expf(st[i][0] - mreg);
      float p1 = __expf(st[i][1] - mreg);
      float p2 = __expf(st[i][2] - mreg);
      float p3 = __expf(st[i][3] - mreg);
      ps += (p0 + p1) + (p2 + p3);
      pq.x = f2bf(p0); pq.y = f2bf(p1); pq.z = f2bf(p2); pq.w = f2bf(p3);
      *(ushort4*)&Pw[lq * 64 + ((g * 4 + i * 16) ^ sx)] = pq;
    }
    ps += __shfl_xor(ps, 16);
    ps += __shfl_xor(ps, 32);
    lreg += ps;

    __builtin_amdgcn_s_setprio(1);
#pragma unroll
    for (int ks = 0; ks < 2; ++ks) {
      bf16x8 pa = *(const bf16x8*)&Pw[lq * 64 + ((ks * 32 + g * 8) ^ sx)];
#pragma unroll
      for (int jj = 0; jj < 4; ++jj) {
        int vr = 16 * jj + lq;
        bf16x8 vb = *(const bf16x8*)&Vs[buf][vr * 64 + ((ks * 32 + g * 8) ^ (8 * (vr & 7)))];
        acc[jj] = __builtin_amdgcn_mfma_f32_16x16x32_bf16(pa, vb, acc[jj], 0, 0, 0);
      }
    }
    __builtin_amdgcn_s_setprio(0);
  };

  stage(0, 0);
  int buf = 0;
  for (int kt = 0; kt < 16; ++kt) {
    __syncthreads();
    if (kt + 1 < 16) stage(buf ^ 1, kt + 1);
    compute(buf);
    buf ^= 1;
  }

  float linv = 1.f / lreg;
  float ilr[4];
#pragma unroll
  for (int r = 0; r < 4; ++r) ilr[r] = __shfl(linv, g * 4 + r);
  unsigned short* obase =
      Obf + (size_t)(b * 1024 + qt * 128 + w * 16) * 1024 + h * 64;
#pragma unroll
  for (int r = 0; r < 4; ++r)
#pragma unroll
    for (int jj = 0; jj < 4; ++jj)
      obase[(size_t)(g * 4 + r) * 1024 + 16 * jj + lq] = f2bf(acc[jj][r] * ilr[r]);
}

// ---------------- exp_map at origin + project (bf16 in, f32 out) ----------------
__global__ __launch_bounds__(256) void expmap_project(
    const unsigned short* __restrict__ c2, float* __restrict__ out) {
  int row = blockIdx.x;
  int tid = threadIdx.x;
  const unsigned short* cr = c2 + (size_t)row * 1024;
  float vals[4];
  float ssq = 0.f;
#pragma unroll
  for (int i = 0; i < 4; ++i) {
    int c = tid + i * 256;
    float t = bf2f(cr[c]);
    vals[i] = (c == 0) ? 0.f : t;
    ssq += vals[i] * vals[i];
  }
#pragma unroll
  for (int off = 32; off; off >>= 1) ssq += __shfl_xor(ssq, off);
  __shared__ float red1[4], red2[4];
  int wv = tid >> 6;
  if ((tid & 63) == 0) red1[wv] = ssq;
  __syncthreads();
  ssq = red1[0] + red1[1] + red1[2] + red1[3];
  float vn = fminf(sqrtf(ssq + EPSF), 5.f);
  float bf = sinhf(vn) / (vn + EPSF);
  float s2 = 0.f;
#pragma unroll
  for (int i = 0; i < 4; ++i) {
    float r = fminf(fmaxf(bf * vals[i], -8.f), 8.f);
    vals[i] = r;
    s2 += r * r;
  }
#pragma unroll
  for (int off = 32; off; off >>= 1) s2 += __shfl_xor(s2, off);
  if ((tid & 63) == 0) red2[wv] = s2;
  __syncthreads();
  s2 = red2[0] + red2[1] + red2[2] + red2[3];
  float x0 = sqrtf(1.f + s2 + EPSF);
  float* orow = out + (size_t)row * 1024;
#pragma unroll
  for (int i = 0; i < 4; ++i) {
    int c = tid + i * 256;
    orow[c] = (c == 0) ? x0 : vals[i];
  }
}

extern "C" void kernel_launch(void* const* d_in, const int* in_sizes, int n_in,
                              void* d_out, int out_size, void* d_ws, size_t ws_size,
                              hipStream_t stream) {
  (void)in_sizes; (void)n_in; (void)out_size; (void)ws_size;
  const float* x  = (const float*)d_in[0];
  const float* Wq = (const float*)d_in[1];
  const float* Wk = (const float*)d_in[2];
  const float* Wv = (const float*)d_in[3];
  const float* Wo = (const float*)d_in[4];
  float* out = (float*)d_out;

  char* w = (char*)d_ws;
  unsigned short* vbf = (unsigned short*)w; w += (size_t)2048 * 1024 * 2;
  unsigned short* wqk = (unsigned short*)w; w += (size_t)2048 * 1024 * 2;
  unsigned short* wvb = (unsigned short*)w; w += (size_t)1024 * 1024 * 2;
  unsigned short* wob = (unsigned short*)w; w += (size_t)1024 * 1024 * 2;
  unsigned short* vtb = (unsigned short*)w; w += (size_t)1024 * 2048 * 2;
  unsigned short* qb  = (unsigned short*)w; w += (size_t)2048 * 1024 * 2;
  unsigned short* kb  = (unsigned short*)w; w += (size_t)2048 * 1024 * 2;
  unsigned short* aob = (unsigned short*)w; w += (size_t)2048 * 1024 * 2;
  unsigned short* c2  = (unsigned short*)w; w += (size_t)2048 * 1024 * 2;

  prep_and_conv<<<6144, 256, 0, stream>>>(x, Wq, Wk, Wv, Wo, vbf, wqk, wvb, wob);

  gemm_qkv<<<512, 256, 0, stream>>>(vbf, wqk, wvb, qb, kb, vtb);

  attn_mfma<<<256, 512, 0, stream>>>(qb, kb, vtb, aob);

  gemm_wo<<<256, 256, 0, stream>>>(aob, wob, c2);
  expmap_project<<<2048, 256, 0, stream>>>(c2, out);
}

// Round 10
// 84.101 us; speedup vs baseline: 1.0206x; 1.0206x over previous
//
#include <hip/hip_runtime.h>

#define EPSF 1e-6f

typedef __bf16 bf16x8 __attribute__((ext_vector_type(8)));
typedef float f32x4 __attribute__((ext_vector_type(4)));
typedef __attribute__((address_space(3))) unsigned int as3_uint;
typedef __attribute__((address_space(1))) const unsigned int as1_uint;

__device__ __forceinline__ unsigned short f2bf(float f) {
  unsigned int u = __builtin_bit_cast(unsigned int, f);
  u += 0x7fffu + ((u >> 16) & 1u);
  return (unsigned short)(u >> 16);
}
__device__ __forceinline__ float bf2f(unsigned short u) {
  unsigned int v = (unsigned int)u << 16;
  return __builtin_bit_cast(float, v);
}

// ------- fused: log_map(x) -> vbf (blocks 0..2047) | weight conv (blocks 2048..6143) -------
__global__ __launch_bounds__(256) void prep_and_conv(
    const float* __restrict__ x, const float* __restrict__ Wq,
    const float* __restrict__ Wk, const float* __restrict__ Wv,
    const float* __restrict__ Wo, unsigned short* __restrict__ vbf,
    unsigned short* __restrict__ wqk, unsigned short* __restrict__ wvb,
    unsigned short* __restrict__ wob) {
  int bid = blockIdx.x;
  int tid = threadIdx.x;
  if (bid >= 2048) {
    int t = bid - 2048;
    int y = t >> 10;
    const float* src = (y == 0) ? Wq : (y == 1) ? Wk : (y == 2) ? Wv : Wo;
    unsigned short* dst = (y == 0) ? wqk : (y == 1) ? wqk + 1048576
                          : (y == 2) ? wvb : wob;
    int i = (t & 1023) * 256 + tid;
    f32x4 v = ((const f32x4*)src)[i];
    ushort4 o;
    o.x = f2bf(v[0]); o.y = f2bf(v[1]); o.z = f2bf(v[2]); o.w = f2bf(v[3]);
    ((ushort4*)dst)[i] = o;
    return;
  }
  int row = bid;
  const float* xr = x + (size_t)row * 1024;
  float vals[4];
  float ssq = 0.f;
#pragma unroll
  for (int i = 0; i < 4; ++i) {
    int c = tid + i * 256;
    float t = xr[c];
    if (c == 0) {
      vals[i] = 0.f;
    } else {
      t = fminf(fmaxf(t, -8.f), 8.f);
      vals[i] = t;
      ssq += t * t;
    }
  }
#pragma unroll
  for (int off = 32; off; off >>= 1) ssq += __shfl_xor(ssq, off);
  __shared__ float red[4];
  int wv = tid >> 6;
  if ((tid & 63) == 0) red[wv] = ssq;
  __syncthreads();
  ssq = red[0] + red[1] + red[2] + red[3];

  float y0 = sqrtf(1.f + ssq + EPSF);
  float xy = fminf(-y0, -(1.f + EPSF));
  float mxy = fmaxf(-xy, 1.f + EPSF);
  float dd = fmaxf(acoshf(mxy), 0.001f);
  float d0 = y0 + xy;
  float inn = ssq - d0 * d0;
  float dn = sqrtf(fmaxf(inn, EPSF));
  float inv = dd / (dn + EPSF);

  unsigned short* vr = vbf + (size_t)row * 1024;
#pragma unroll
  for (int i = 0; i < 4; ++i) {
    int c = tid + i * 256;
    float o = (c == 0) ? d0 * inv : vals[i] * inv;
    vr[c] = f2bf(o);
  }
}

// ---------- 128x128-tile GEMM body, double-buffered gload_lds staging ----------
__device__ __forceinline__ void gemm128_dbuf(
    const unsigned short* __restrict__ A, const unsigned short* __restrict__ Bw,
    int K, int row0, int col0, unsigned short* As, unsigned short* Bs,
    f32x4 (*acc)[4]) {
  int tid = threadIdx.x;
  int lane = tid & 63, w = tid >> 6;
  int wm = (w >> 1) * 64, wn = (w & 1) * 64;
  int lq = lane & 15, g = lane >> 4;
  const unsigned short* Ag =
      A + (size_t)(row0 + w * 8 + (lane >> 3)) * K + (lane & 7) * 8;
  const unsigned short* Bg =
      Bw + (size_t)(col0 + w * 8 + (lane >> 3)) * K + (lane & 7) * 8;

  auto stage = [&](int buf, int k0) {
#pragma unroll
    for (int it = 0; it < 4; ++it) {
      __builtin_amdgcn_global_load_lds(
          (as1_uint*)(Ag + (size_t)(it * 32) * K + k0),
          (as3_uint*)&As[buf * 8192 + (it * 32 + w * 8) * 64], 16, 0, 0);
      __builtin_amdgcn_global_load_lds(
          (as1_uint*)(Bg + (size_t)(it * 32) * K + k0),
          (as3_uint*)&Bs[buf * 8192 + (it * 32 + w * 8) * 64], 16, 0, 0);
    }
  };

  stage(0, 0);
  int buf = 0;
  for (int k0 = 0; k0 < K; k0 += 64) {
    __syncthreads();
    if (k0 + 64 < K) stage(buf ^ 1, k0 + 64);
#pragma unroll
    for (int ks = 0; ks < 2; ++ks) {
      bf16x8 af[4], bfr[4];
#pragma unroll
      for (int i = 0; i < 4; ++i)
        af[i] = *(const bf16x8*)&As[buf * 8192 + (wm + i * 16 + lq) * 64 + ks * 32 + g * 8];
#pragma unroll
      for (int j = 0; j < 4; ++j)
        bfr[j] = *(const bf16x8*)&Bs[buf * 8192 + (wn + j * 16 + lq) * 64 + ks * 32 + g * 8];
#pragma unroll
      for (int i = 0; i < 4; ++i)
#pragma unroll
        for (int j = 0; j < 4; ++j)
          acc[i][j] =
              __builtin_amdgcn_mfma_f32_16x16x32_bf16(af[i], bfr[j], acc[i][j], 0, 0, 0);
    }
    buf ^= 1;
  }
}

// QK gemm 128x128 (even bids, 256 tiles) | Vt gemm 128x64 (odd bids, 256 tiles)
__global__ __launch_bounds__(256) void gemm_qkv(
    const unsigned short* __restrict__ vbf, const unsigned short* __restrict__ wqk,
    const unsigned short* __restrict__ wvb, unsigned short* __restrict__ qb,
    unsigned short* __restrict__ kb, unsigned short* __restrict__ vtb) {
  __shared__ unsigned short As[2 * 8192];
  __shared__ unsigned short Bs[2 * 8192];
  int tid = threadIdx.x;
  int lane = tid & 63, w = tid >> 6;
  int lq = lane & 15, g = lane >> 4;
  int bid = blockIdx.x;

  if ((bid & 1) == 0) {
    int q = bid >> 1;  // 0..255
    int wm = (w >> 1) * 64, wn = (w & 1) * 64;
    f32x4 acc[4][4] = {};
    int row0 = (q & 15) * 128, col0 = (q >> 4) * 128;
    gemm128_dbuf(vbf, wqk, 1024, row0, col0, As, Bs, acc);
    int headg = (col0 + wn) >> 6;  // 0..31 (0-15 q heads, 16-31 k heads)
    int qmode = (headg < 16) ? 1 : 0;
    unsigned short* dst = qmode ? qb : kb;
    size_t colb = (size_t)(headg & 15) * 64;
    float scale = qmode ? 0.125f : 1.f;
#pragma unroll
    for (int i = 0; i < 4; ++i)
#pragma unroll
      for (int r = 0; r < 4; ++r) {
        float s = 0.f;
#pragma unroll
        for (int j = 0; j < 4; ++j) {
          float vc = fminf(fmaxf(acc[i][j][r], -5.f), 5.f);
          s += (j == 0 && lq == 0) ? 0.f : vc * vc;  // exclude head col 0
        }
        s += __shfl_xor(s, 1);
        s += __shfl_xor(s, 2);
        s += __shfl_xor(s, 4);
        s += __shfl_xor(s, 8);
        float x0 = sqrtf(1.f + s + EPSF);
        int row = row0 + wm + i * 16 + g * 4 + r;
#pragma unroll
        for (int j = 0; j < 4; ++j) {
          float vc = fminf(fmaxf(acc[i][j][r], -5.f), 5.f);
          float o = (j == 0 && lq == 0) ? (qmode ? -x0 : x0) : vc;
          dst[(size_t)row * 1024 + colb + j * 16 + lq] = f2bf(o * scale);
        }
      }
  } else {
    int t = bid >> 1;  // 0..255 : Vt 128x64 tile
    int wm = (w >> 1) * 64, wn = (w & 1) * 32;
    int row0 = (t & 7) * 128, col0 = (t >> 3) * 64;
    f32x4 acc[4][2] = {};
    const unsigned short* Ag =
        wvb + (size_t)(row0 + w * 8 + (lane >> 3)) * 1024 + (lane & 7) * 8;
    const unsigned short* Bg =
        vbf + (size_t)(col0 + w * 8 + (lane >> 3)) * 1024 + (lane & 7) * 8;
    auto stage = [&](int buf, int k0) {
#pragma unroll
      for (int it = 0; it < 4; ++it)
        __builtin_amdgcn_global_load_lds(
            (as1_uint*)(Ag + (size_t)(it * 32) * 1024 + k0),
            (as3_uint*)&As[buf * 8192 + (it * 32 + w * 8) * 64], 16, 0, 0);
#pragma unroll
      for (int it = 0; it < 2; ++it)
        __builtin_amdgcn_global_load_lds(
            (as1_uint*)(Bg + (size_t)(it * 32) * 1024 + k0),
            (as3_uint*)&Bs[buf * 4096 + (it * 32 + w * 8) * 64], 16, 0, 0);
    };
    stage(0, 0);
    int buf = 0;
    for (int k0 = 0; k0 < 1024; k0 += 64) {
      __syncthreads();
      if (k0 + 64 < 1024) stage(buf ^ 1, k0 + 64);
#pragma unroll
      for (int ks = 0; ks < 2; ++ks) {
        bf16x8 af[4], bfr[2];
#pragma unroll
        for (int i = 0; i < 4; ++i)
          af[i] = *(const bf16x8*)&As[buf * 8192 + (wm + i * 16 + lq) * 64 + ks * 32 + g * 8];
#pragma unroll
        for (int j = 0; j < 2; ++j)
          bfr[j] = *(const bf16x8*)&Bs[buf * 4096 + (wn + j * 16 + lq) * 64 + ks * 32 + g * 8];
#pragma unroll
        for (int i = 0; i < 4; ++i)
#pragma unroll
          for (int j = 0; j < 2; ++j)
            acc[i][j] =
                __builtin_amdgcn_mfma_f32_16x16x32_bf16(af[i], bfr[j], acc[i][j], 0, 0, 0);
      }
      buf ^= 1;
    }
#pragma unroll
    for (int i = 0; i < 4; ++i)
#pragma unroll
      for (int j = 0; j < 2; ++j)
#pragma unroll
        for (int r = 0; r < 4; ++r)
          vtb[(size_t)(row0 + wm + i * 16 + g * 4 + r) * 2048 + col0 + wn + j * 16 + lq] =
              f2bf(acc[i][j][r]);
  }
}

// Wo gemm: BM=128 BN=64, dbuf staging; 256 blocks
__global__ __launch_bounds__(256) void gemm_wo(
    const unsigned short* __restrict__ A, const unsigned short* __restrict__ Bw,
    unsigned short* __restrict__ C) {
  __shared__ unsigned short As[2 * 8192];
  __shared__ unsigned short Bs[2 * 4096];
  int tid = threadIdx.x;
  int lane = tid & 63, w = tid >> 6;
  int wm = (w >> 1) * 64, wn = (w & 1) * 32;
  int lq = lane & 15, g = lane >> 4;
  int row0 = (blockIdx.x & 15) * 128, col0 = (blockIdx.x >> 4) * 64;
  f32x4 acc[4][2] = {};
  const unsigned short* Ag =
      A + (size_t)(row0 + w * 8 + (lane >> 3)) * 1024 + (lane & 7) * 8;
  const unsigned short* Bg =
      Bw + (size_t)(col0 + w * 8 + (lane >> 3)) * 1024 + (lane & 7) * 8;

  auto stage = [&](int buf, int k0) {
#pragma unroll
    for (int it = 0; it < 4; ++it)
      __builtin_amdgcn_global_load_lds(
          (as1_uint*)(Ag + (size_t)(it * 32) * 1024 + k0),
          (as3_uint*)&As[buf * 8192 + (it * 32 + w * 8) * 64], 16, 0, 0);
#pragma unroll
    for (int it = 0; it < 2; ++it)
      __builtin_amdgcn_global_load_lds(
          (as1_uint*)(Bg + (size_t)(it * 32) * 1024 + k0),
          (as3_uint*)&Bs[buf * 4096 + (it * 32 + w * 8) * 64], 16, 0, 0);
  };

  stage(0, 0);
  int buf = 0;
  for (int k0 = 0; k0 < 1024; k0 += 64) {
    __syncthreads();
    if (k0 + 64 < 1024) stage(buf ^ 1, k0 + 64);
#pragma unroll
    for (int ks = 0; ks < 2; ++ks) {
      bf16x8 af[4], bfr[2];
#pragma unroll
      for (int i = 0; i < 4; ++i)
        af[i] = *(const bf16x8*)&As[buf * 8192 + (wm + i * 16 + lq) * 64 + ks * 32 + g * 8];
#pragma unroll
      for (int j = 0; j < 2; ++j)
        bfr[j] = *(const bf16x8*)&Bs[buf * 4096 + (wn + j * 16 + lq) * 64 + ks * 32 + g * 8];
#pragma unroll
      for (int i = 0; i < 4; ++i)
#pragma unroll
        for (int j = 0; j < 2; ++j)
          acc[i][j] =
              __builtin_amdgcn_mfma_f32_16x16x32_bf16(af[i], bfr[j], acc[i][j], 0, 0, 0);
    }
    buf ^= 1;
  }
#pragma unroll
  for (int i = 0; i < 4; ++i)
#pragma unroll
    for (int j = 0; j < 2; ++j)
#pragma unroll
      for (int r = 0; r < 4; ++r)
        C[(size_t)(row0 + wm + i * 16 + g * 4 + r) * 1024 + col0 + wn + j * 16 + lq] =
            f2bf(acc[i][j][r]);
}

// ---- MFMA flash attention (R7/R8-proven config): 4 waves, QBLK=64, KVBLK=64,
//      gload_lds dbuf, XCD-grouped, defer-max, setprio ----
__global__ __launch_bounds__(256) void attn_mfma(
    const unsigned short* __restrict__ Qb, const unsigned short* __restrict__ Kb,
    const unsigned short* __restrict__ Vtb, unsigned short* __restrict__ Obf) {
  __shared__ unsigned short Ks[2][64 * 64];
  __shared__ unsigned short Vs[2][64 * 64];
  __shared__ unsigned short Ps[4 * 16 * 64];
  int tid = threadIdx.x;
  int lane = tid & 63, w = tid >> 6;
  int g = lane >> 4, lq = lane & 15;
  int bid = blockIdx.x;
  int idx = bid >> 3;               // 0..63
  int bh = (bid & 7) * 4 + (idx & 3);
  int qt = idx >> 2;                // 0..15
  int b = bh >> 4, h = bh & 15;

  const unsigned short* qrow =
      Qb + (size_t)(b * 1024 + qt * 64 + w * 16 + lq) * 1024 + h * 64;
  bf16x8 qf0 = *(const bf16x8*)(qrow + g * 8);
  bf16x8 qf1 = *(const bf16x8*)(qrow + 32 + g * 8);

  float mreg = -1e30f, lreg = 0.f;
  f32x4 acc[4] = {};
  unsigned short* Pw = Ps + w * 16 * 64;
  int sx = 8 * (lq & 7);

  const unsigned short* Ksrc = Kb + (size_t)(b * 1024) * 1024 + h * 64;
  const unsigned short* Vsrc = Vtb + (size_t)(h * 64) * 2048 + b * 1024;

  int srow = lane >> 3;
  int scg = (lane & 7) ^ srow;  // pre-swizzled global source (involution)
  const unsigned short* Kp = Ksrc + (size_t)(w * 8 + srow) * 1024 + scg * 8;
  const unsigned short* Vp = Vsrc + (size_t)(w * 8 + srow) * 2048 + scg * 8;

  auto stage = [&](int buf, int kt) {
#pragma unroll
    for (int it = 0; it < 2; ++it) {
      __builtin_amdgcn_global_load_lds(
          (as1_uint*)(Kp + (size_t)(kt * 64 + it * 32) * 1024),
          (as3_uint*)&Ks[buf][(it * 32 + w * 8) * 64], 16, 0, 0);
      __builtin_amdgcn_global_load_lds(
          (as1_uint*)(Vp + (size_t)(it * 32) * 2048 + kt * 64),
          (as3_uint*)&Vs[buf][(it * 32 + w * 8) * 64], 16, 0, 0);
    }
  };

  auto compute = [&](int buf) {
    f32x4 st[4];
    __builtin_amdgcn_s_setprio(1);
#pragma unroll
    for (int i = 0; i < 4; ++i) {
      int ro = i * 16 + lq;
      int rb = ro * 64, xx = 8 * (ro & 7);
      bf16x8 a0 = *(const bf16x8*)&Ks[buf][rb + ((g * 8) ^ xx)];
      bf16x8 a1 = *(const bf16x8*)&Ks[buf][rb + ((32 + g * 8) ^ xx)];
      f32x4 z = {};
      z = __builtin_amdgcn_mfma_f32_16x16x32_bf16(a0, qf0, z, 0, 0, 0);
      st[i] = __builtin_amdgcn_mfma_f32_16x16x32_bf16(a1, qf1, z, 0, 0, 0);
    }
    __builtin_amdgcn_s_setprio(0);
    float pmax = st[0][0];
#pragma unroll
    for (int i = 0; i < 4; ++i)
#pragma unroll
      for (int r = 0; r < 4; ++r) pmax = fmaxf(pmax, st[i][r]);
    pmax = fmaxf(pmax, __shfl_xor(pmax, 16));
    pmax = fmaxf(pmax, __shfl_xor(pmax, 32));
    if (__any(pmax > mreg + 8.f)) {
      float nm = fmaxf(mreg, pmax);
      float sc_ = __expf(mreg - nm);
      mreg = nm;
      lreg *= sc_;
      float scr[4];
#pragma unroll
      for (int r = 0; r < 4; ++r) scr[r] = __shfl(sc_, g * 4 + r);
#pragma unroll
      for (int jj = 0; jj < 4; ++jj)
#pragma unroll
        for (int r = 0; r < 4; ++r) acc[jj][r] *= scr[r];
    }
    float ps = 0.f;
#pragma unroll
    for (int i = 0; i < 4; ++i) {
      ushort4 pq;
      float p0 = __expf(st[i][0] - mreg);
      float p1 = __expf(st[i][1] - mreg);
      float p2 = __expf(st[i][2] - mreg);
      float p3 = __expf(st[i][3] - mreg);
      ps += (p0 + p1) + (p2 + p3);
      pq.x = f2bf(p0); pq.y = f2bf(p1); pq.z = f2bf(p2); pq.w = f2bf(p3);
      *(ushort4*)&Pw[lq * 64 + ((g * 4 + i * 16) ^ sx)] = pq;
    }
    ps += __shfl_xor(ps, 16);
    ps += __shfl_xor(ps, 32);
    lreg += ps;

    __builtin_amdgcn_s_setprio(1);
#pragma unroll
    for (int ks = 0; ks < 2; ++ks) {
      bf16x8 pa = *(const bf16x8*)&Pw[lq * 64 + ((ks * 32 + g * 8) ^ sx)];
#pragma unroll
      for (int jj = 0; jj < 4; ++jj) {
        int vr = 16 * jj + lq;
        bf16x8 vb = *(const bf16x8*)&Vs[buf][vr * 64 + ((ks * 32 + g * 8) ^ (8 * (vr & 7)))];
        acc[jj] = __builtin_amdgcn_mfma_f32_16x16x32_bf16(pa, vb, acc[jj], 0, 0, 0);
      }
    }
    __builtin_amdgcn_s_setprio(0);
  };

  stage(0, 0);
  int buf = 0;
  for (int kt = 0; kt < 16; ++kt) {
    __syncthreads();
    if (kt + 1 < 16) stage(buf ^ 1, kt + 1);
    compute(buf);
    buf ^= 1;
  }

  float linv = 1.f / lreg;
  float ilr[4];
#pragma unroll
  for (int r = 0; r < 4; ++r) ilr[r] = __shfl(linv, g * 4 + r);
  unsigned short* obase =
      Obf + (size_t)(b * 1024 + qt * 64 + w * 16) * 1024 + h * 64;
#pragma unroll
  for (int r = 0; r < 4; ++r)
#pragma unroll
    for (int jj = 0; jj < 4; ++jj)
      obase[(size_t)(g * 4 + r) * 1024 + 16 * jj + lq] = f2bf(acc[jj][r] * ilr[r]);
}

// ---------------- exp_map at origin + project (bf16 in, f32 out) ----------------
__global__ __launch_bounds__(256) void expmap_project(
    const unsigned short* __restrict__ c2, float* __restrict__ out) {
  int row = blockIdx.x;
  int tid = threadIdx.x;
  const unsigned short* cr = c2 + (size_t)row * 1024;
  float vals[4];
  float ssq = 0.f;
#pragma unroll
  for (int i = 0; i < 4; ++i) {
    int c = tid + i * 256;
    float t = bf2f(cr[c]);
    vals[i] = (c == 0) ? 0.f : t;
    ssq += vals[i] * vals[i];
  }
#pragma unroll
  for (int off = 32; off; off >>= 1) ssq += __shfl_xor(ssq, off);
  __shared__ float red1[4], red2[4];
  int wv = tid >> 6;
  if ((tid & 63) == 0) red1[wv] = ssq;
  __syncthreads();
  ssq = red1[0] + red1[1] + red1[2] + red1[3];
  float vn = fminf(sqrtf(ssq + EPSF), 5.f);
  float bf = sinhf(vn) / (vn + EPSF);
  float s2 = 0.f;
#pragma unroll
  for (int i = 0; i < 4; ++i) {
    float r = fminf(fmaxf(bf * vals[i], -8.f), 8.f);
    vals[i] = r;
    s2 += r * r;
  }
#pragma unroll
  for (int off = 32; off; off >>= 1) s2 += __shfl_xor(s2, off);
  if ((tid & 63) == 0) red2[wv] = s2;
  __syncthreads();
  s2 = red2[0] + red2[1] + red2[2] + red2[3];
  float x0 = sqrtf(1.f + s2 + EPSF);
  float* orow = out + (size_t)row * 1024;
#pragma unroll
  for (int i = 0; i < 4; ++i) {
    int c = tid + i * 256;
    orow[c] = (c == 0) ? x0 : vals[i];
  }
}

extern "C" void kernel_launch(void* const* d_in, const int* in_sizes, int n_in,
                              void* d_out, int out_size, void* d_ws, size_t ws_size,
                              hipStream_t stream) {
  (void)in_sizes; (void)n_in; (void)out_size; (void)ws_size;
  const float* x  = (const float*)d_in[0];
  const float* Wq = (const float*)d_in[1];
  const float* Wk = (const float*)d_in[2];
  const float* Wv = (const float*)d_in[3];
  const float* Wo = (const float*)d_in[4];
  float* out = (float*)d_out;

  char* w = (char*)d_ws;
  unsigned short* vbf = (unsigned short*)w; w += (size_t)2048 * 1024 * 2;
  unsigned short* wqk = (unsigned short*)w; w += (size_t)2048 * 1024 * 2;
  unsigned short* wvb = (unsigned short*)w; w += (size_t)1024 * 1024 * 2;
  unsigned short* wob = (unsigned short*)w; w += (size_t)1024 * 1024 * 2;
  unsigned short* vtb = (unsigned short*)w; w += (size_t)1024 * 2048 * 2;
  unsigned short* qb  = (unsigned short*)w; w += (size_t)2048 * 1024 * 2;
  unsigned short* kb  = (unsigned short*)w; w += (size_t)2048 * 1024 * 2;
  unsigned short* aob = (unsigned short*)w; w += (size_t)2048 * 1024 * 2;
  unsigned short* c2  = (unsigned short*)w; w += (size_t)2048 * 1024 * 2;

  prep_and_conv<<<6144, 256, 0, stream>>>(x, Wq, Wk, Wv, Wo, vbf, wqk, wvb, wob);

  gemm_qkv<<<512, 256, 0, stream>>>(vbf, wqk, wvb, qb, kb, vtb);

  attn_mfma<<<512, 256, 0, stream>>>(qb, kb, vtb, aob);

  gemm_wo<<<256, 256, 0, stream>>>(aob, wob, c2);
  expmap_project<<<2048, 256, 0, stream>>>(c2, out);
}

// Round 11
// 81.779 us; speedup vs baseline: 1.0495x; 1.0284x over previous
//
#include <hip/hip_runtime.h>

#define EPSF 1e-6f

typedef __bf16 bf16x8 __attribute__((ext_vector_type(8)));
typedef float f32x4 __attribute__((ext_vector_type(4)));
typedef __attribute__((address_space(3))) unsigned int as3_uint;
typedef __attribute__((address_space(1))) const unsigned int as1_uint;

__device__ __forceinline__ unsigned short f2bf(float f) {
  unsigned int u = __builtin_bit_cast(unsigned int, f);
  u += 0x7fffu + ((u >> 16) & 1u);
  return (unsigned short)(u >> 16);
}
__device__ __forceinline__ float bf2f(unsigned short u) {
  unsigned int v = (unsigned int)u << 16;
  return __builtin_bit_cast(float, v);
}

// ------- fused: log_map(x) -> vbf (blocks 0..2047) | weight conv (blocks 2048..6143) -------
__global__ __launch_bounds__(256) void prep_and_conv(
    const float* __restrict__ x, const float* __restrict__ Wq,
    const float* __restrict__ Wk, const float* __restrict__ Wv,
    const float* __restrict__ Wo, unsigned short* __restrict__ vbf,
    unsigned short* __restrict__ wqk, unsigned short* __restrict__ wvb,
    unsigned short* __restrict__ wob) {
  int bid = blockIdx.x;
  int tid = threadIdx.x;
  if (bid >= 2048) {
    int t = bid - 2048;
    int y = t >> 10;
    const float* src = (y == 0) ? Wq : (y == 1) ? Wk : (y == 2) ? Wv : Wo;
    unsigned short* dst = (y == 0) ? wqk : (y == 1) ? wqk + 1048576
                          : (y == 2) ? wvb : wob;
    int i = (t & 1023) * 256 + tid;
    f32x4 v = ((const f32x4*)src)[i];
    ushort4 o;
    o.x = f2bf(v[0]); o.y = f2bf(v[1]); o.z = f2bf(v[2]); o.w = f2bf(v[3]);
    ((ushort4*)dst)[i] = o;
    return;
  }
  int row = bid;
  const float* xr = x + (size_t)row * 1024;
  float vals[4];
  float ssq = 0.f;
#pragma unroll
  for (int i = 0; i < 4; ++i) {
    int c = tid + i * 256;
    float t = xr[c];
    if (c == 0) {
      vals[i] = 0.f;
    } else {
      t = fminf(fmaxf(t, -8.f), 8.f);
      vals[i] = t;
      ssq += t * t;
    }
  }
#pragma unroll
  for (int off = 32; off; off >>= 1) ssq += __shfl_xor(ssq, off);
  __shared__ float red[4];
  int wv = tid >> 6;
  if ((tid & 63) == 0) red[wv] = ssq;
  __syncthreads();
  ssq = red[0] + red[1] + red[2] + red[3];

  float y0 = sqrtf(1.f + ssq + EPSF);
  float xy = fminf(-y0, -(1.f + EPSF));
  float mxy = fmaxf(-xy, 1.f + EPSF);
  float dd = fmaxf(acoshf(mxy), 0.001f);
  float d0 = y0 + xy;
  float inn = ssq - d0 * d0;
  float dn = sqrtf(fmaxf(inn, EPSF));
  float inv = dd / (dn + EPSF);

  unsigned short* vr = vbf + (size_t)row * 1024;
#pragma unroll
  for (int i = 0; i < 4; ++i) {
    int c = tid + i * 256;
    float o = (c == 0) ? d0 * inv : vals[i] * inv;
    vr[c] = f2bf(o);
  }
}

// ---------- 128x128-tile GEMM body, double-buffered gload_lds staging ----------
__device__ __forceinline__ void gemm128_dbuf(
    const unsigned short* __restrict__ A, const unsigned short* __restrict__ Bw,
    int K, int row0, int col0, unsigned short* As, unsigned short* Bs,
    f32x4 (*acc)[4]) {
  int tid = threadIdx.x;
  int lane = tid & 63, w = tid >> 6;
  int wm = (w >> 1) * 64, wn = (w & 1) * 64;
  int lq = lane & 15, g = lane >> 4;
  const unsigned short* Ag =
      A + (size_t)(row0 + w * 8 + (lane >> 3)) * K + (lane & 7) * 8;
  const unsigned short* Bg =
      Bw + (size_t)(col0 + w * 8 + (lane >> 3)) * K + (lane & 7) * 8;

  auto stage = [&](int buf, int k0) {
#pragma unroll
    for (int it = 0; it < 4; ++it) {
      __builtin_amdgcn_global_load_lds(
          (as1_uint*)(Ag + (size_t)(it * 32) * K + k0),
          (as3_uint*)&As[buf * 8192 + (it * 32 + w * 8) * 64], 16, 0, 0);
      __builtin_amdgcn_global_load_lds(
          (as1_uint*)(Bg + (size_t)(it * 32) * K + k0),
          (as3_uint*)&Bs[buf * 8192 + (it * 32 + w * 8) * 64], 16, 0, 0);
    }
  };

  stage(0, 0);
  int buf = 0;
  for (int k0 = 0; k0 < K; k0 += 64) {
    __syncthreads();
    if (k0 + 64 < K) stage(buf ^ 1, k0 + 64);
#pragma unroll
    for (int ks = 0; ks < 2; ++ks) {
      bf16x8 af[4], bfr[4];
#pragma unroll
      for (int i = 0; i < 4; ++i)
        af[i] = *(const bf16x8*)&As[buf * 8192 + (wm + i * 16 + lq) * 64 + ks * 32 + g * 8];
#pragma unroll
      for (int j = 0; j < 4; ++j)
        bfr[j] = *(const bf16x8*)&Bs[buf * 8192 + (wn + j * 16 + lq) * 64 + ks * 32 + g * 8];
#pragma unroll
      for (int i = 0; i < 4; ++i)
#pragma unroll
        for (int j = 0; j < 4; ++j)
          acc[i][j] =
              __builtin_amdgcn_mfma_f32_16x16x32_bf16(af[i], bfr[j], acc[i][j], 0, 0, 0);
    }
    buf ^= 1;
  }
}

// QK gemm 128x128 (even bids, 256 tiles) | Vt gemm 128x64 (odd bids, 256 tiles)
__global__ __launch_bounds__(256) void gemm_qkv(
    const unsigned short* __restrict__ vbf, const unsigned short* __restrict__ wqk,
    const unsigned short* __restrict__ wvb, unsigned short* __restrict__ qb,
    unsigned short* __restrict__ kb, unsigned short* __restrict__ vtb) {
  __shared__ unsigned short As[2 * 8192];
  __shared__ unsigned short Bs[2 * 8192];
  int tid = threadIdx.x;
  int lane = tid & 63, w = tid >> 6;
  int lq = lane & 15, g = lane >> 4;
  int bid = blockIdx.x;

  if ((bid & 1) == 0) {
    int q = bid >> 1;  // 0..255
    int wm = (w >> 1) * 64, wn = (w & 1) * 64;
    f32x4 acc[4][4] = {};
    int row0 = (q & 15) * 128, col0 = (q >> 4) * 128;
    gemm128_dbuf(vbf, wqk, 1024, row0, col0, As, Bs, acc);
    int headg = (col0 + wn) >> 6;  // 0..31 (0-15 q heads, 16-31 k heads)
    int qmode = (headg < 16) ? 1 : 0;
    unsigned short* dst = qmode ? qb : kb;
    size_t colb = (size_t)(headg & 15) * 64;
    float scale = qmode ? 0.125f : 1.f;
#pragma unroll
    for (int i = 0; i < 4; ++i)
#pragma unroll
      for (int r = 0; r < 4; ++r) {
        float s = 0.f;
#pragma unroll
        for (int j = 0; j < 4; ++j) {
          float vc = fminf(fmaxf(acc[i][j][r], -5.f), 5.f);
          s += (j == 0 && lq == 0) ? 0.f : vc * vc;  // exclude head col 0
        }
        s += __shfl_xor(s, 1);
        s += __shfl_xor(s, 2);
        s += __shfl_xor(s, 4);
        s += __shfl_xor(s, 8);
        float x0 = sqrtf(1.f + s + EPSF);
        int row = row0 + wm + i * 16 + g * 4 + r;
#pragma unroll
        for (int j = 0; j < 4; ++j) {
          float vc = fminf(fmaxf(acc[i][j][r], -5.f), 5.f);
          float o = (j == 0 && lq == 0) ? (qmode ? -x0 : x0) : vc;
          dst[(size_t)row * 1024 + colb + j * 16 + lq] = f2bf(o * scale);
        }
      }
  } else {
    int t = bid >> 1;  // 0..255 : Vt 128x64 tile
    int wm = (w >> 1) * 64, wn = (w & 1) * 32;
    int row0 = (t & 7) * 128, col0 = (t >> 3) * 64;
    f32x4 acc[4][2] = {};
    const unsigned short* Ag =
        wvb + (size_t)(row0 + w * 8 + (lane >> 3)) * 1024 + (lane & 7) * 8;
    const unsigned short* Bg =
        vbf + (size_t)(col0 + w * 8 + (lane >> 3)) * 1024 + (lane & 7) * 8;
    auto stage = [&](int buf, int k0) {
#pragma unroll
      for (int it = 0; it < 4; ++it)
        __builtin_amdgcn_global_load_lds(
            (as1_uint*)(Ag + (size_t)(it * 32) * 1024 + k0),
            (as3_uint*)&As[buf * 8192 + (it * 32 + w * 8) * 64], 16, 0, 0);
#pragma unroll
      for (int it = 0; it < 2; ++it)
        __builtin_amdgcn_global_load_lds(
            (as1_uint*)(Bg + (size_t)(it * 32) * 1024 + k0),
            (as3_uint*)&Bs[buf * 4096 + (it * 32 + w * 8) * 64], 16, 0, 0);
    };
    stage(0, 0);
    int buf = 0;
    for (int k0 = 0; k0 < 1024; k0 += 64) {
      __syncthreads();
      if (k0 + 64 < 1024) stage(buf ^ 1, k0 + 64);
#pragma unroll
      for (int ks = 0; ks < 2; ++ks) {
        bf16x8 af[4], bfr[2];
#pragma unroll
        for (int i = 0; i < 4; ++i)
          af[i] = *(const bf16x8*)&As[buf * 8192 + (wm + i * 16 + lq) * 64 + ks * 32 + g * 8];
#pragma unroll
        for (int j = 0; j < 2; ++j)
          bfr[j] = *(const bf16x8*)&Bs[buf * 4096 + (wn + j * 16 + lq) * 64 + ks * 32 + g * 8];
#pragma unroll
        for (int i = 0; i < 4; ++i)
#pragma unroll
          for (int j = 0; j < 2; ++j)
            acc[i][j] =
                __builtin_amdgcn_mfma_f32_16x16x32_bf16(af[i], bfr[j], acc[i][j], 0, 0, 0);
      }
      buf ^= 1;
    }
#pragma unroll
    for (int i = 0; i < 4; ++i)
#pragma unroll
      for (int j = 0; j < 2; ++j)
#pragma unroll
        for (int r = 0; r < 4; ++r)
          vtb[(size_t)(row0 + wm + i * 16 + g * 4 + r) * 2048 + col0 + wn + j * 16 + lq] =
              f2bf(acc[i][j][r]);
  }
}

// Wo gemm: BM=128 BN=64, dbuf staging; 256 blocks
__global__ __launch_bounds__(256) void gemm_wo(
    const unsigned short* __restrict__ A, const unsigned short* __restrict__ Bw,
    unsigned short* __restrict__ C) {
  __shared__ unsigned short As[2 * 8192];
  __shared__ unsigned short Bs[2 * 4096];
  int tid = threadIdx.x;
  int lane = tid & 63, w = tid >> 6;
  int wm = (w >> 1) * 64, wn = (w & 1) * 32;
  int lq = lane & 15, g = lane >> 4;
  int row0 = (blockIdx.x & 15) * 128, col0 = (blockIdx.x >> 4) * 64;
  f32x4 acc[4][2] = {};
  const unsigned short* Ag =
      A + (size_t)(row0 + w * 8 + (lane >> 3)) * 1024 + (lane & 7) * 8;
  const unsigned short* Bg =
      Bw + (size_t)(col0 + w * 8 + (lane >> 3)) * 1024 + (lane & 7) * 8;

  auto stage = [&](int buf, int k0) {
#pragma unroll
    for (int it = 0; it < 4; ++it)
      __builtin_amdgcn_global_load_lds(
          (as1_uint*)(Ag + (size_t)(it * 32) * 1024 + k0),
          (as3_uint*)&As[buf * 8192 + (it * 32 + w * 8) * 64], 16, 0, 0);
#pragma unroll
    for (int it = 0; it < 2; ++it)
      __builtin_amdgcn_global_load_lds(
          (as1_uint*)(Bg + (size_t)(it * 32) * 1024 + k0),
          (as3_uint*)&Bs[buf * 4096 + (it * 32 + w * 8) * 64], 16, 0, 0);
  };

  stage(0, 0);
  int buf = 0;
  for (int k0 = 0; k0 < 1024; k0 += 64) {
    __syncthreads();
    if (k0 + 64 < 1024) stage(buf ^ 1, k0 + 64);
#pragma unroll
    for (int ks = 0; ks < 2; ++ks) {
      bf16x8 af[4], bfr[2];
#pragma unroll
      for (int i = 0; i < 4; ++i)
        af[i] = *(const bf16x8*)&As[buf * 8192 + (wm + i * 16 + lq) * 64 + ks * 32 + g * 8];
#pragma unroll
      for (int j = 0; j < 2; ++j)
        bfr[j] = *(const bf16x8*)&Bs[buf * 4096 + (wn + j * 16 + lq) * 64 + ks * 32 + g * 8];
#pragma unroll
      for (int i = 0; i < 4; ++i)
#pragma unroll
        for (int j = 0; j < 2; ++j)
          acc[i][j] =
              __builtin_amdgcn_mfma_f32_16x16x32_bf16(af[i], bfr[j], acc[i][j], 0, 0, 0);
    }
    buf ^= 1;
  }
#pragma unroll
  for (int i = 0; i < 4; ++i)
#pragma unroll
    for (int j = 0; j < 2; ++j)
#pragma unroll
      for (int r = 0; r < 4; ++r)
        C[(size_t)(row0 + wm + i * 16 + g * 4 + r) * 1024 + col0 + wn + j * 16 + lq] =
            f2bf(acc[i][j][r]);
}

// ---- MFMA flash attention: 4 waves, QBLK=64, KVBLK=128, gload_lds dbuf,
//      XCD-grouped, defer-max, setprio ----
__global__ __launch_bounds__(256) void attn_mfma(
    const unsigned short* __restrict__ Qb, const unsigned short* __restrict__ Kb,
    const unsigned short* __restrict__ Vtb, unsigned short* __restrict__ Obf) {
  __shared__ unsigned short Ks[2][128 * 64];   // K rows x d
  __shared__ unsigned short Vs[2][64 * 128];   // d rows x tokens
  __shared__ unsigned short Ps[4 * 16 * 128];
  int tid = threadIdx.x;
  int lane = tid & 63, w = tid >> 6;
  int g = lane >> 4, lq = lane & 15;
  int bid = blockIdx.x;
  int idx = bid >> 3;               // 0..63
  int bh = (bid & 7) * 4 + (idx & 3);
  int qt = idx >> 2;                // 0..15
  int b = bh >> 4, h = bh & 15;

  const unsigned short* qrow =
      Qb + (size_t)(b * 1024 + qt * 64 + w * 16 + lq) * 1024 + h * 64;
  bf16x8 qf0 = *(const bf16x8*)(qrow + g * 8);
  bf16x8 qf1 = *(const bf16x8*)(qrow + 32 + g * 8);

  float mreg = -1e30f, lreg = 0.f;
  f32x4 acc[4] = {};
  unsigned short* Pw = Ps + w * 16 * 128;
  int sx = 8 * (lq & 7);

  const unsigned short* Ksrc = Kb + (size_t)(b * 1024) * 1024 + h * 64;
  const unsigned short* Vsrc = Vtb + (size_t)(h * 64) * 2048 + b * 1024;

  // K staging: per it, wave w fills rows it*32 + w*8 + (lane>>3), slot lane&7.
  int skr = lane >> 3;
  int scgk = (lane & 7) ^ skr;  // involution: row&7 == skr
  const unsigned short* Kp = Ksrc + (size_t)(w * 8 + skr) * 1024 + scgk * 8;
  // V staging: per it, wave w fills rows it*16 + w*4 + (lane>>4), slot lane&15.
  int svr = w * 4 + (lane >> 4);  // 0..15
  int scgv = (lane & 15) ^ (svr & 7);
  const unsigned short* Vp = Vsrc + (size_t)svr * 2048 + scgv * 8;

  auto stage = [&](int buf, int kt) {
#pragma unroll
    for (int it = 0; it < 4; ++it) {
      __builtin_amdgcn_global_load_lds(
          (as1_uint*)(Kp + (size_t)(kt * 128 + it * 32) * 1024),
          (as3_uint*)&Ks[buf][(it * 32 + w * 8) * 64], 16, 0, 0);
      __builtin_amdgcn_global_load_lds(
          (as1_uint*)(Vp + (size_t)(it * 16) * 2048 + kt * 128),
          (as3_uint*)&Vs[buf][(it * 16 + w * 4) * 128], 16, 0, 0);
    }
  };

  auto compute = [&](int buf) {
    f32x4 st[8];
    __builtin_amdgcn_s_setprio(1);
#pragma unroll
    for (int i = 0; i < 8; ++i) {
      int ro = i * 16 + lq;
      int rb = ro * 64, xx = 8 * (ro & 7);
      bf16x8 a0 = *(const bf16x8*)&Ks[buf][rb + ((g * 8) ^ xx)];
      bf16x8 a1 = *(const bf16x8*)&Ks[buf][rb + ((32 + g * 8) ^ xx)];
      f32x4 z = {};
      z = __builtin_amdgcn_mfma_f32_16x16x32_bf16(a0, qf0, z, 0, 0, 0);
      st[i] = __builtin_amdgcn_mfma_f32_16x16x32_bf16(a1, qf1, z, 0, 0, 0);
    }
    __builtin_amdgcn_s_setprio(0);
    float pmax = st[0][0];
#pragma unroll
    for (int i = 0; i < 8; ++i)
#pragma unroll
      for (int r = 0; r < 4; ++r) pmax = fmaxf(pmax, st[i][r]);
    pmax = fmaxf(pmax, __shfl_xor(pmax, 16));
    pmax = fmaxf(pmax, __shfl_xor(pmax, 32));
    if (__any(pmax > mreg + 8.f)) {
      float nm = fmaxf(mreg, pmax);
      float sc_ = __expf(mreg - nm);
      mreg = nm;
      lreg *= sc_;
      float scr[4];
#pragma unroll
      for (int r = 0; r < 4; ++r) scr[r] = __shfl(sc_, g * 4 + r);
#pragma unroll
      for (int jj = 0; jj < 4; ++jj)
#pragma unroll
        for (int r = 0; r < 4; ++r) acc[jj][r] *= scr[r];
    }
    float ps = 0.f;
#pragma unroll
    for (int i = 0; i < 8; ++i) {
      ushort4 pq;
      float p0 = __expf(st[i][0] - mreg);
      float p1 = __expf(st[i][1] - mreg);
      float p2 = __expf(st[i][2] - mreg);
      float p3 = __expf(st[i][3] - mreg);
      ps += (p0 + p1) + (p2 + p3);
      pq.x = f2bf(p0); pq.y = f2bf(p1); pq.z = f2bf(p2); pq.w = f2bf(p3);
      *(ushort4*)&Pw[lq * 128 + ((g * 4 + i * 16) ^ sx)] = pq;
    }
    ps += __shfl_xor(ps, 16);
    ps += __shfl_xor(ps, 32);
    lreg += ps;

    __builtin_amdgcn_s_setprio(1);
#pragma unroll
    for (int ks = 0; ks < 4; ++ks) {
      bf16x8 pa = *(const bf16x8*)&Pw[lq * 128 + ((ks * 32 + g * 8) ^ sx)];
#pragma unroll
      for (int jj = 0; jj < 4; ++jj) {
        int vr = 16 * jj + lq;
        bf16x8 vb = *(const bf16x8*)&Vs[buf][vr * 128 + ((ks * 32 + g * 8) ^ (8 * (vr & 7)))];
        acc[jj] = __builtin_amdgcn_mfma_f32_16x16x32_bf16(pa, vb, acc[jj], 0, 0, 0);
      }
    }
    __builtin_amdgcn_s_setprio(0);
  };

  stage(0, 0);
  int buf = 0;
  for (int kt = 0; kt < 8; ++kt) {
    __syncthreads();
    if (kt + 1 < 8) stage(buf ^ 1, kt + 1);
    compute(buf);
    buf ^= 1;
  }

  float linv = 1.f / lreg;
  float ilr[4];
#pragma unroll
  for (int r = 0; r < 4; ++r) ilr[r] = __shfl(linv, g * 4 + r);
  unsigned short* obase =
      Obf + (size_t)(b * 1024 + qt * 64 + w * 16) * 1024 + h * 64;
#pragma unroll
  for (int r = 0; r < 4; ++r)
#pragma unroll
    for (int jj = 0; jj < 4; ++jj)
      obase[(size_t)(g * 4 + r) * 1024 + 16 * jj + lq] = f2bf(acc[jj][r] * ilr[r]);
}

// ---------------- exp_map at origin + project (bf16 in, f32 out) ----------------
__global__ __launch_bounds__(256) void expmap_project(
    const unsigned short* __restrict__ c2, float* __restrict__ out) {
  int row = blockIdx.x;
  int tid = threadIdx.x;
  const unsigned short* cr = c2 + (size_t)row * 1024;
  float vals[4];
  float ssq = 0.f;
#pragma unroll
  for (int i = 0; i < 4; ++i) {
    int c = tid + i * 256;
    float t = bf2f(cr[c]);
    vals[i] = (c == 0) ? 0.f : t;
    ssq += vals[i] * vals[i];
  }
#pragma unroll
  for (int off = 32; off; off >>= 1) ssq += __shfl_xor(ssq, off);
  __shared__ float red1[4], red2[4];
  int wv = tid >> 6;
  if ((tid & 63) == 0) red1[wv] = ssq;
  __syncthreads();
  ssq = red1[0] + red1[1] + red1[2] + red1[3];
  float vn = fminf(sqrtf(ssq + EPSF), 5.f);
  float bf = sinhf(vn) / (vn + EPSF);
  float s2 = 0.f;
#pragma unroll
  for (int i = 0; i < 4; ++i) {
    float r = fminf(fmaxf(bf * vals[i], -8.f), 8.f);
    vals[i] = r;
    s2 += r * r;
  }
#pragma unroll
  for (int off = 32; off; off >>= 1) s2 += __shfl_xor(s2, off);
  if ((tid & 63) == 0) red2[wv] = s2;
  __syncthreads();
  s2 = red2[0] + red2[1] + red2[2] + red2[3];
  float x0 = sqrtf(1.f + s2 + EPSF);
  float* orow = out + (size_t)row * 1024;
#pragma unroll
  for (int i = 0; i < 4; ++i) {
    int c = tid + i * 256;
    orow[c] = (c == 0) ? x0 : vals[i];
  }
}

extern "C" void kernel_launch(void* const* d_in, const int* in_sizes, int n_in,
                              void* d_out, int out_size, void* d_ws, size_t ws_size,
                              hipStream_t stream) {
  (void)in_sizes; (void)n_in; (void)out_size; (void)ws_size;
  const float* x  = (const float*)d_in[0];
  const float* Wq = (const float*)d_in[1];
  const float* Wk = (const float*)d_in[2];
  const float* Wv = (const float*)d_in[3];
  const float* Wo = (const float*)d_in[4];
  float* out = (float*)d_out;

  char* w = (char*)d_ws;
  unsigned short* vbf = (unsigned short*)w; w += (size_t)2048 * 1024 * 2;
  unsigned short* wqk = (unsigned short*)w; w += (size_t)2048 * 1024 * 2;
  unsigned short* wvb = (unsigned short*)w; w += (size_t)1024 * 1024 * 2;
  unsigned short* wob = (unsigned short*)w; w += (size_t)1024 * 1024 * 2;
  unsigned short* vtb = (unsigned short*)w; w += (size_t)1024 * 2048 * 2;
  unsigned short* qb  = (unsigned short*)w; w += (size_t)2048 * 1024 * 2;
  unsigned short* kb  = (unsigned short*)w; w += (size_t)2048 * 1024 * 2;
  unsigned short* aob = (unsigned short*)w; w += (size_t)2048 * 1024 * 2;
  unsigned short* c2  = (unsigned short*)w; w += (size_t)2048 * 1024 * 2;

  prep_and_conv<<<6144, 256, 0, stream>>>(x, Wq, Wk, Wv, Wo, vbf, wqk, wvb, wob);

  gemm_qkv<<<512, 256, 0, stream>>>(vbf, wqk, wvb, qb, kb, vtb);

  attn_mfma<<<512, 256, 0, stream>>>(qb, kb, vtb, aob);

  gemm_wo<<<256, 256, 0, stream>>>(aob, wob, c2);
  expmap_project<<<2048, 256, 0, stream>>>(c2, out);
}

// Round 12
// 80.347 us; speedup vs baseline: 1.0683x; 1.0178x over previous
//
#include <hip/hip_runtime.h>

#define EPSF 1e-6f

typedef __bf16 bf16x8 __attribute__((ext_vector_type(8)));
typedef float f32x4 __attribute__((ext_vector_type(4)));
typedef __attribute__((address_space(3))) unsigned int as3_uint;
typedef __attribute__((address_space(1))) const unsigned int as1_uint;

__device__ __forceinline__ unsigned short f2bf(float f) {
  unsigned int u = __builtin_bit_cast(unsigned int, f);
  u += 0x7fffu + ((u >> 16) & 1u);
  return (unsigned short)(u >> 16);
}
__device__ __forceinline__ float bf2f(unsigned short u) {
  unsigned int v = (unsigned int)u << 16;
  return __builtin_bit_cast(float, v);
}

// ------- fused: log_map(x) -> vbf (blocks 0..2047) | weight conv (blocks 2048..6143) -------
__global__ __launch_bounds__(256) void prep_and_conv(
    const float* __restrict__ x, const float* __restrict__ Wq,
    const float* __restrict__ Wk, const float* __restrict__ Wv,
    const float* __restrict__ Wo, unsigned short* __restrict__ vbf,
    unsigned short* __restrict__ wqk, unsigned short* __restrict__ wvb,
    unsigned short* __restrict__ wob) {
  int bid = blockIdx.x;
  int tid = threadIdx.x;
  if (bid >= 2048) {
    int t = bid - 2048;
    int y = t >> 10;
    const float* src = (y == 0) ? Wq : (y == 1) ? Wk : (y == 2) ? Wv : Wo;
    unsigned short* dst = (y == 0) ? wqk : (y == 1) ? wqk + 1048576
                          : (y == 2) ? wvb : wob;
    int i = (t & 1023) * 256 + tid;
    f32x4 v = ((const f32x4*)src)[i];
    ushort4 o;
    o.x = f2bf(v[0]); o.y = f2bf(v[1]); o.z = f2bf(v[2]); o.w = f2bf(v[3]);
    ((ushort4*)dst)[i] = o;
    return;
  }
  int row = bid;
  const float* xr = x + (size_t)row * 1024;
  float vals[4];
  float ssq = 0.f;
#pragma unroll
  for (int i = 0; i < 4; ++i) {
    int c = tid + i * 256;
    float t = xr[c];
    if (c == 0) {
      vals[i] = 0.f;
    } else {
      t = fminf(fmaxf(t, -8.f), 8.f);
      vals[i] = t;
      ssq += t * t;
    }
  }
#pragma unroll
  for (int off = 32; off; off >>= 1) ssq += __shfl_xor(ssq, off);
  __shared__ float red[4];
  int wv = tid >> 6;
  if ((tid & 63) == 0) red[wv] = ssq;
  __syncthreads();
  ssq = red[0] + red[1] + red[2] + red[3];

  float y0 = sqrtf(1.f + ssq + EPSF);
  float xy = fminf(-y0, -(1.f + EPSF));
  float mxy = fmaxf(-xy, 1.f + EPSF);
  float dd = fmaxf(acoshf(mxy), 0.001f);
  float d0 = y0 + xy;
  float inn = ssq - d0 * d0;
  float dn = sqrtf(fmaxf(inn, EPSF));
  float inv = dd / (dn + EPSF);

  unsigned short* vr = vbf + (size_t)row * 1024;
#pragma unroll
  for (int i = 0; i < 4; ++i) {
    int c = tid + i * 256;
    float o = (c == 0) ? d0 * inv : vals[i] * inv;
    vr[c] = f2bf(o);
  }
}

// ---------- 128x128-tile GEMM body, double-buffered gload_lds staging ----------
__device__ __forceinline__ void gemm128_dbuf(
    const unsigned short* __restrict__ A, const unsigned short* __restrict__ Bw,
    int K, int row0, int col0, unsigned short* As, unsigned short* Bs,
    f32x4 (*acc)[4]) {
  int tid = threadIdx.x;
  int lane = tid & 63, w = tid >> 6;
  int wm = (w >> 1) * 64, wn = (w & 1) * 64;
  int lq = lane & 15, g = lane >> 4;
  const unsigned short* Ag =
      A + (size_t)(row0 + w * 8 + (lane >> 3)) * K + (lane & 7) * 8;
  const unsigned short* Bg =
      Bw + (size_t)(col0 + w * 8 + (lane >> 3)) * K + (lane & 7) * 8;

  auto stage = [&](int buf, int k0) {
#pragma unroll
    for (int it = 0; it < 4; ++it) {
      __builtin_amdgcn_global_load_lds(
          (as1_uint*)(Ag + (size_t)(it * 32) * K + k0),
          (as3_uint*)&As[buf * 8192 + (it * 32 + w * 8) * 64], 16, 0, 0);
      __builtin_amdgcn_global_load_lds(
          (as1_uint*)(Bg + (size_t)(it * 32) * K + k0),
          (as3_uint*)&Bs[buf * 8192 + (it * 32 + w * 8) * 64], 16, 0, 0);
    }
  };

  stage(0, 0);
  int buf = 0;
  for (int k0 = 0; k0 < K; k0 += 64) {
    __syncthreads();
    if (k0 + 64 < K) stage(buf ^ 1, k0 + 64);
#pragma unroll
    for (int ks = 0; ks < 2; ++ks) {
      bf16x8 af[4], bfr[4];
#pragma unroll
      for (int i = 0; i < 4; ++i)
        af[i] = *(const bf16x8*)&As[buf * 8192 + (wm + i * 16 + lq) * 64 + ks * 32 + g * 8];
#pragma unroll
      for (int j = 0; j < 4; ++j)
        bfr[j] = *(const bf16x8*)&Bs[buf * 8192 + (wn + j * 16 + lq) * 64 + ks * 32 + g * 8];
#pragma unroll
      for (int i = 0; i < 4; ++i)
#pragma unroll
        for (int j = 0; j < 4; ++j)
          acc[i][j] =
              __builtin_amdgcn_mfma_f32_16x16x32_bf16(af[i], bfr[j], acc[i][j], 0, 0, 0);
    }
    buf ^= 1;
  }
}

// QK gemm 128x128 (256 tiles) | Vt gemm 128x64 (256 tiles).
// XCD-aware: XCD x (bid&7) gets tiles x*32+s; s<32 -> QK, s>=32 -> Vt.
// Each XCD: 32 QK + 32 Vt (balanced), QK tiles span only cols {2x,2x+1} (L2 reuse).
__global__ __launch_bounds__(256) void gemm_qkv(
    const unsigned short* __restrict__ vbf, const unsigned short* __restrict__ wqk,
    const unsigned short* __restrict__ wvb, unsigned short* __restrict__ qb,
    unsigned short* __restrict__ kb, unsigned short* __restrict__ vtb) {
  __shared__ unsigned short As[2 * 8192];
  __shared__ unsigned short Bs[2 * 8192];
  int tid = threadIdx.x;
  int lane = tid & 63, w = tid >> 6;
  int lq = lane & 15, g = lane >> 4;
  int bid = blockIdx.x;
  int xcd = bid & 7, s = bid >> 3;

  if (s < 32) {
    int q = xcd * 32 + s;  // 0..255
    int wm = (w >> 1) * 64, wn = (w & 1) * 64;
    f32x4 acc[4][4] = {};
    int row0 = (q & 15) * 128, col0 = (q >> 4) * 128;
    gemm128_dbuf(vbf, wqk, 1024, row0, col0, As, Bs, acc);
    int headg = (col0 + wn) >> 6;  // 0..31 (0-15 q heads, 16-31 k heads)
    int qmode = (headg < 16) ? 1 : 0;
    unsigned short* dst = qmode ? qb : kb;
    size_t colb = (size_t)(headg & 15) * 64;
    float scale = qmode ? 0.125f : 1.f;
#pragma unroll
    for (int i = 0; i < 4; ++i)
#pragma unroll
      for (int r = 0; r < 4; ++r) {
        float sm = 0.f;
#pragma unroll
        for (int j = 0; j < 4; ++j) {
          float vc = fminf(fmaxf(acc[i][j][r], -5.f), 5.f);
          sm += (j == 0 && lq == 0) ? 0.f : vc * vc;  // exclude head col 0
        }
        sm += __shfl_xor(sm, 1);
        sm += __shfl_xor(sm, 2);
        sm += __shfl_xor(sm, 4);
        sm += __shfl_xor(sm, 8);
        float x0 = sqrtf(1.f + sm + EPSF);
        int row = row0 + wm + i * 16 + g * 4 + r;
#pragma unroll
        for (int j = 0; j < 4; ++j) {
          float vc = fminf(fmaxf(acc[i][j][r], -5.f), 5.f);
          float o = (j == 0 && lq == 0) ? (qmode ? -x0 : x0) : vc;
          dst[(size_t)row * 1024 + colb + j * 16 + lq] = f2bf(o * scale);
        }
      }
  } else {
    int t = xcd * 32 + (s - 32);  // 0..255 : Vt 128x64 tile
    int wm = (w >> 1) * 64, wn = (w & 1) * 32;
    int row0 = (t & 7) * 128, col0 = (t >> 3) * 64;
    f32x4 acc[4][2] = {};
    const unsigned short* Ag =
        wvb + (size_t)(row0 + w * 8 + (lane >> 3)) * 1024 + (lane & 7) * 8;
    const unsigned short* Bg =
        vbf + (size_t)(col0 + w * 8 + (lane >> 3)) * 1024 + (lane & 7) * 8;
    auto stage = [&](int buf, int k0) {
#pragma unroll
      for (int it = 0; it < 4; ++it)
        __builtin_amdgcn_global_load_lds(
            (as1_uint*)(Ag + (size_t)(it * 32) * 1024 + k0),
            (as3_uint*)&As[buf * 8192 + (it * 32 + w * 8) * 64], 16, 0, 0);
#pragma unroll
      for (int it = 0; it < 2; ++it)
        __builtin_amdgcn_global_load_lds(
            (as1_uint*)(Bg + (size_t)(it * 32) * 1024 + k0),
            (as3_uint*)&Bs[buf * 4096 + (it * 32 + w * 8) * 64], 16, 0, 0);
    };
    stage(0, 0);
    int buf = 0;
    for (int k0 = 0; k0 < 1024; k0 += 64) {
      __syncthreads();
      if (k0 + 64 < 1024) stage(buf ^ 1, k0 + 64);
#pragma unroll
      for (int ks = 0; ks < 2; ++ks) {
        bf16x8 af[4], bfr[2];
#pragma unroll
        for (int i = 0; i < 4; ++i)
          af[i] = *(const bf16x8*)&As[buf * 8192 + (wm + i * 16 + lq) * 64 + ks * 32 + g * 8];
#pragma unroll
        for (int j = 0; j < 2; ++j)
          bfr[j] = *(const bf16x8*)&Bs[buf * 4096 + (wn + j * 16 + lq) * 64 + ks * 32 + g * 8];
#pragma unroll
        for (int i = 0; i < 4; ++i)
#pragma unroll
          for (int j = 0; j < 2; ++j)
            acc[i][j] =
                __builtin_amdgcn_mfma_f32_16x16x32_bf16(af[i], bfr[j], acc[i][j], 0, 0, 0);
      }
      buf ^= 1;
    }
#pragma unroll
    for (int i = 0; i < 4; ++i)
#pragma unroll
      for (int j = 0; j < 2; ++j)
#pragma unroll
        for (int r = 0; r < 4; ++r)
          vtb[(size_t)(row0 + wm + i * 16 + g * 4 + r) * 2048 + col0 + wn + j * 16 + lq] =
              f2bf(acc[i][j][r]);
  }
}

// Wo gemm: BM=128 BN=64, dbuf staging; 256 blocks, XCD-aware tiling
__global__ __launch_bounds__(256) void gemm_wo(
    const unsigned short* __restrict__ A, const unsigned short* __restrict__ Bw,
    unsigned short* __restrict__ C) {
  __shared__ unsigned short As[2 * 8192];
  __shared__ unsigned short Bs[2 * 4096];
  int tid = threadIdx.x;
  int lane = tid & 63, w = tid >> 6;
  int wm = (w >> 1) * 64, wn = (w & 1) * 32;
  int lq = lane & 15, g = lane >> 4;
  int t = (blockIdx.x & 7) * 32 + (blockIdx.x >> 3);  // XCD-grouped tile id
  int row0 = (t & 15) * 128, col0 = (t >> 4) * 64;
  f32x4 acc[4][2] = {};
  const unsigned short* Ag =
      A + (size_t)(row0 + w * 8 + (lane >> 3)) * 1024 + (lane & 7) * 8;
  const unsigned short* Bg =
      Bw + (size_t)(col0 + w * 8 + (lane >> 3)) * 1024 + (lane & 7) * 8;

  auto stage = [&](int buf, int k0) {
#pragma unroll
    for (int it = 0; it < 4; ++it)
      __builtin_amdgcn_global_load_lds(
          (as1_uint*)(Ag + (size_t)(it * 32) * 1024 + k0),
          (as3_uint*)&As[buf * 8192 + (it * 32 + w * 8) * 64], 16, 0, 0);
#pragma unroll
    for (int it = 0; it < 2; ++it)
      __builtin_amdgcn_global_load_lds(
          (as1_uint*)(Bg + (size_t)(it * 32) * 1024 + k0),
          (as3_uint*)&Bs[buf * 4096 + (it * 32 + w * 8) * 64], 16, 0, 0);
  };

  stage(0, 0);
  int buf = 0;
  for (int k0 = 0; k0 < 1024; k0 += 64) {
    __syncthreads();
    if (k0 + 64 < 1024) stage(buf ^ 1, k0 + 64);
#pragma unroll
    for (int ks = 0; ks < 2; ++ks) {
      bf16x8 af[4], bfr[2];
#pragma unroll
      for (int i = 0; i < 4; ++i)
        af[i] = *(const bf16x8*)&As[buf * 8192 + (wm + i * 16 + lq) * 64 + ks * 32 + g * 8];
#pragma unroll
      for (int j = 0; j < 2; ++j)
        bfr[j] = *(const bf16x8*)&Bs[buf * 4096 + (wn + j * 16 + lq) * 64 + ks * 32 + g * 8];
#pragma unroll
      for (int i = 0; i < 4; ++i)
#pragma unroll
        for (int j = 0; j < 2; ++j)
          acc[i][j] =
              __builtin_amdgcn_mfma_f32_16x16x32_bf16(af[i], bfr[j], acc[i][j], 0, 0, 0);
    }
    buf ^= 1;
  }
#pragma unroll
  for (int i = 0; i < 4; ++i)
#pragma unroll
    for (int j = 0; j < 2; ++j)
#pragma unroll
      for (int r = 0; r < 4; ++r)
        C[(size_t)(row0 + wm + i * 16 + g * 4 + r) * 1024 + col0 + wn + j * 16 + lq] =
            f2bf(acc[i][j][r]);
}

// ---- MFMA flash attention: 4 waves, QBLK=64, KVBLK=128, gload_lds dbuf,
//      XCD-grouped, defer-max, setprio ----
__global__ __launch_bounds__(256) void attn_mfma(
    const unsigned short* __restrict__ Qb, const unsigned short* __restrict__ Kb,
    const unsigned short* __restrict__ Vtb, unsigned short* __restrict__ Obf) {
  __shared__ unsigned short Ks[2][128 * 64];   // K rows x d
  __shared__ unsigned short Vs[2][64 * 128];   // d rows x tokens
  __shared__ unsigned short Ps[4 * 16 * 128];
  int tid = threadIdx.x;
  int lane = tid & 63, w = tid >> 6;
  int g = lane >> 4, lq = lane & 15;
  int bid = blockIdx.x;
  int idx = bid >> 3;               // 0..63
  int bh = (bid & 7) * 4 + (idx & 3);
  int qt = idx >> 2;                // 0..15
  int b = bh >> 4, h = bh & 15;

  const unsigned short* qrow =
      Qb + (size_t)(b * 1024 + qt * 64 + w * 16 + lq) * 1024 + h * 64;
  bf16x8 qf0 = *(const bf16x8*)(qrow + g * 8);
  bf16x8 qf1 = *(const bf16x8*)(qrow + 32 + g * 8);

  float mreg = -1e30f, lreg = 0.f;
  f32x4 acc[4] = {};
  unsigned short* Pw = Ps + w * 16 * 128;
  int sx = 8 * (lq & 7);

  const unsigned short* Ksrc = Kb + (size_t)(b * 1024) * 1024 + h * 64;
  const unsigned short* Vsrc = Vtb + (size_t)(h * 64) * 2048 + b * 1024;

  int skr = lane >> 3;
  int scgk = (lane & 7) ^ skr;
  const unsigned short* Kp = Ksrc + (size_t)(w * 8 + skr) * 1024 + scgk * 8;
  int svr = w * 4 + (lane >> 4);  // 0..15
  int scgv = (lane & 15) ^ (svr & 7);
  const unsigned short* Vp = Vsrc + (size_t)svr * 2048 + scgv * 8;

  auto stage = [&](int buf, int kt) {
#pragma unroll
    for (int it = 0; it < 4; ++it) {
      __builtin_amdgcn_global_load_lds(
          (as1_uint*)(Kp + (size_t)(kt * 128 + it * 32) * 1024),
          (as3_uint*)&Ks[buf][(it * 32 + w * 8) * 64], 16, 0, 0);
      __builtin_amdgcn_global_load_lds(
          (as1_uint*)(Vp + (size_t)(it * 16) * 2048 + kt * 128),
          (as3_uint*)&Vs[buf][(it * 16 + w * 4) * 128], 16, 0, 0);
    }
  };

  auto compute = [&](int buf) {
    f32x4 st[8];
    __builtin_amdgcn_s_setprio(1);
#pragma unroll
    for (int i = 0; i < 8; ++i) {
      int ro = i * 16 + lq;
      int rb = ro * 64, xx = 8 * (ro & 7);
      bf16x8 a0 = *(const bf16x8*)&Ks[buf][rb + ((g * 8) ^ xx)];
      bf16x8 a1 = *(const bf16x8*)&Ks[buf][rb + ((32 + g * 8) ^ xx)];
      f32x4 z = {};
      z = __builtin_amdgcn_mfma_f32_16x16x32_bf16(a0, qf0, z, 0, 0, 0);
      st[i] = __builtin_amdgcn_mfma_f32_16x16x32_bf16(a1, qf1, z, 0, 0, 0);
    }
    __builtin_amdgcn_s_setprio(0);
    float pmax = st[0][0];
#pragma unroll
    for (int i = 0; i < 8; ++i)
#pragma unroll
      for (int r = 0; r < 4; ++r) pmax = fmaxf(pmax, st[i][r]);
    pmax = fmaxf(pmax, __shfl_xor(pmax, 16));
    pmax = fmaxf(pmax, __shfl_xor(pmax, 32));
    if (__any(pmax > mreg + 8.f)) {
      float nm = fmaxf(mreg, pmax);
      float sc_ = __expf(mreg - nm);
      mreg = nm;
      lreg *= sc_;
      float scr[4];
#pragma unroll
      for (int r = 0; r < 4; ++r) scr[r] = __shfl(sc_, g * 4 + r);
#pragma unroll
      for (int jj = 0; jj < 4; ++jj)
#pragma unroll
        for (int r = 0; r < 4; ++r) acc[jj][r] *= scr[r];
    }
    float ps = 0.f;
#pragma unroll
    for (int i = 0; i < 8; ++i) {
      ushort4 pq;
      float p0 = __expf(st[i][0] - mreg);
      float p1 = __expf(st[i][1] - mreg);
      float p2 = __expf(st[i][2] - mreg);
      float p3 = __expf(st[i][3] - mreg);
      ps += (p0 + p1) + (p2 + p3);
      pq.x = f2bf(p0); pq.y = f2bf(p1); pq.z = f2bf(p2); pq.w = f2bf(p3);
      *(ushort4*)&Pw[lq * 128 + ((g * 4 + i * 16) ^ sx)] = pq;
    }
    ps += __shfl_xor(ps, 16);
    ps += __shfl_xor(ps, 32);
    lreg += ps;

    __builtin_amdgcn_s_setprio(1);
#pragma unroll
    for (int ks = 0; ks < 4; ++ks) {
      bf16x8 pa = *(const bf16x8*)&Pw[lq * 128 + ((ks * 32 + g * 8) ^ sx)];
#pragma unroll
      for (int jj = 0; jj < 4; ++jj) {
        int vr = 16 * jj + lq;
        bf16x8 vb = *(const bf16x8*)&Vs[buf][vr * 128 + ((ks * 32 + g * 8) ^ (8 * (vr & 7)))];
        acc[jj] = __builtin_amdgcn_mfma_f32_16x16x32_bf16(pa, vb, acc[jj], 0, 0, 0);
      }
    }
    __builtin_amdgcn_s_setprio(0);
  };

  stage(0, 0);
  int buf = 0;
  for (int kt = 0; kt < 8; ++kt) {
    __syncthreads();
    if (kt + 1 < 8) stage(buf ^ 1, kt + 1);
    compute(buf);
    buf ^= 1;
  }

  float linv = 1.f / lreg;
  float ilr[4];
#pragma unroll
  for (int r = 0; r < 4; ++r) ilr[r] = __shfl(linv, g * 4 + r);
  unsigned short* obase =
      Obf + (size_t)(b * 1024 + qt * 64 + w * 16) * 1024 + h * 64;
#pragma unroll
  for (int r = 0; r < 4; ++r)
#pragma unroll
    for (int jj = 0; jj < 4; ++jj)
      obase[(size_t)(g * 4 + r) * 1024 + 16 * jj + lq] = f2bf(acc[jj][r] * ilr[r]);
}

// ---------------- exp_map at origin + project (bf16 in, f32 out) ----------------
__global__ __launch_bounds__(256) void expmap_project(
    const unsigned short* __restrict__ c2, float* __restrict__ out) {
  int row = blockIdx.x;
  int tid = threadIdx.x;
  const unsigned short* cr = c2 + (size_t)row * 1024;
  float vals[4];
  float ssq = 0.f;
#pragma unroll
  for (int i = 0; i < 4; ++i) {
    int c = tid + i * 256;
    float t = bf2f(cr[c]);
    vals[i] = (c == 0) ? 0.f : t;
    ssq += vals[i] * vals[i];
  }
#pragma unroll
  for (int off = 32; off; off >>= 1) ssq += __shfl_xor(ssq, off);
  __shared__ float red1[4], red2[4];
  int wv = tid >> 6;
  if ((tid & 63) == 0) red1[wv] = ssq;
  __syncthreads();
  ssq = red1[0] + red1[1] + red1[2] + red1[3];
  float vn = fminf(sqrtf(ssq + EPSF), 5.f);
  float bf = sinhf(vn) / (vn + EPSF);
  float s2 = 0.f;
#pragma unroll
  for (int i = 0; i < 4; ++i) {
    float r = fminf(fmaxf(bf * vals[i], -8.f), 8.f);
    vals[i] = r;
    s2 += r * r;
  }
#pragma unroll
  for (int off = 32; off; off >>= 1) s2 += __shfl_xor(s2, off);
  if ((tid & 63) == 0) red2[wv] = s2;
  __syncthreads();
  s2 = red2[0] + red2[1] + red2[2] + red2[3];
  float x0 = sqrtf(1.f + s2 + EPSF);
  float* orow = out + (size_t)row * 1024;
#pragma unroll
  for (int i = 0; i < 4; ++i) {
    int c = tid + i * 256;
    orow[c] = (c == 0) ? x0 : vals[i];
  }
}

extern "C" void kernel_launch(void* const* d_in, const int* in_sizes, int n_in,
                              void* d_out, int out_size, void* d_ws, size_t ws_size,
                              hipStream_t stream) {
  (void)in_sizes; (void)n_in; (void)out_size; (void)ws_size;
  const float* x  = (const float*)d_in[0];
  const float* Wq = (const float*)d_in[1];
  const float* Wk = (const float*)d_in[2];
  const float* Wv = (const float*)d_in[3];
  const float* Wo = (const float*)d_in[4];
  float* out = (float*)d_out;

  char* w = (char*)d_ws;
  unsigned short* vbf = (unsigned short*)w; w += (size_t)2048 * 1024 * 2;
  unsigned short* wqk = (unsigned short*)w; w += (size_t)2048 * 1024 * 2;
  unsigned short* wvb = (unsigned short*)w; w += (size_t)1024 * 1024 * 2;
  unsigned short* wob = (unsigned short*)w; w += (size_t)1024 * 1024 * 2;
  unsigned short* vtb = (unsigned short*)w; w += (size_t)1024 * 2048 * 2;
  unsigned short* qb  = (unsigned short*)w; w += (size_t)2048 * 1024 * 2;
  unsigned short* kb  = (unsigned short*)w; w += (size_t)2048 * 1024 * 2;
  unsigned short* aob = (unsigned short*)w; w += (size_t)2048 * 1024 * 2;
  unsigned short* c2  = (unsigned short*)w; w += (size_t)2048 * 1024 * 2;

  prep_and_conv<<<6144, 256, 0, stream>>>(x, Wq, Wk, Wv, Wo, vbf, wqk, wvb, wob);

  gemm_qkv<<<512, 256, 0, stream>>>(vbf, wqk, wvb, qb, kb, vtb);

  attn_mfma<<<512, 256, 0, stream>>>(qb, kb, vtb, aob);

  gemm_wo<<<256, 256, 0, stream>>>(aob, wob, c2);
  expmap_project<<<2048, 256, 0, stream>>>(c2, out);
}

// Round 13
// 79.709 us; speedup vs baseline: 1.0768x; 1.0080x over previous
//
#include <hip/hip_runtime.h>

#define EPSF 1e-6f

typedef __bf16 bf16x8 __attribute__((ext_vector_type(8)));
typedef __bf16 bf16x4 __attribute__((ext_vector_type(4)));
typedef float f32x4 __attribute__((ext_vector_type(4)));
typedef __attribute__((address_space(3))) unsigned int as3_uint;
typedef __attribute__((address_space(1))) const unsigned int as1_uint;

// Native cast: compiler emits v_cvt_pk_bf16_f32 and pairs conversions (m240).
__device__ __forceinline__ unsigned short f2bf(float f) {
  return __builtin_bit_cast(unsigned short, (__bf16)f);
}
__device__ __forceinline__ float bf2f(unsigned short u) {
  unsigned int v = (unsigned int)u << 16;
  return __builtin_bit_cast(float, v);
}

// ------- fused: log_map(x) -> vbf (blocks 0..2047) | weight conv (blocks 2048..6143) -------
__global__ __launch_bounds__(256) void prep_and_conv(
    const float* __restrict__ x, const float* __restrict__ Wq,
    const float* __restrict__ Wk, const float* __restrict__ Wv,
    const float* __restrict__ Wo, unsigned short* __restrict__ vbf,
    unsigned short* __restrict__ wqk, unsigned short* __restrict__ wvb,
    unsigned short* __restrict__ wob) {
  int bid = blockIdx.x;
  int tid = threadIdx.x;
  if (bid >= 2048) {
    int t = bid - 2048;
    int y = t >> 10;
    const float* src = (y == 0) ? Wq : (y == 1) ? Wk : (y == 2) ? Wv : Wo;
    unsigned short* dst = (y == 0) ? wqk : (y == 1) ? wqk + 1048576
                          : (y == 2) ? wvb : wob;
    int i = (t & 1023) * 256 + tid;
    f32x4 v = ((const f32x4*)src)[i];
    ushort4 o;
    o.x = f2bf(v[0]); o.y = f2bf(v[1]); o.z = f2bf(v[2]); o.w = f2bf(v[3]);
    ((ushort4*)dst)[i] = o;
    return;
  }
  int row = bid;
  const float* xr = x + (size_t)row * 1024;
  float vals[4];
  float ssq = 0.f;
#pragma unroll
  for (int i = 0; i < 4; ++i) {
    int c = tid + i * 256;
    float t = xr[c];
    if (c == 0) {
      vals[i] = 0.f;
    } else {
      t = fminf(fmaxf(t, -8.f), 8.f);
      vals[i] = t;
      ssq += t * t;
    }
  }
#pragma unroll
  for (int off = 32; off; off >>= 1) ssq += __shfl_xor(ssq, off);
  __shared__ float red[4];
  int wv = tid >> 6;
  if ((tid & 63) == 0) red[wv] = ssq;
  __syncthreads();
  ssq = red[0] + red[1] + red[2] + red[3];

  float y0 = sqrtf(1.f + ssq + EPSF);
  float xy = fminf(-y0, -(1.f + EPSF));
  float mxy = fmaxf(-xy, 1.f + EPSF);
  float dd = fmaxf(acoshf(mxy), 0.001f);
  float d0 = y0 + xy;
  float inn = ssq - d0 * d0;
  float dn = sqrtf(fmaxf(inn, EPSF));
  float inv = dd / (dn + EPSF);

  unsigned short* vr = vbf + (size_t)row * 1024;
#pragma unroll
  for (int i = 0; i < 4; ++i) {
    int c = tid + i * 256;
    float o = (c == 0) ? d0 * inv : vals[i] * inv;
    vr[c] = f2bf(o);
  }
}

// ---------- 128x128-tile GEMM body, double-buffered gload_lds staging ----------
__device__ __forceinline__ void gemm128_dbuf(
    const unsigned short* __restrict__ A, const unsigned short* __restrict__ Bw,
    int K, int row0, int col0, unsigned short* As, unsigned short* Bs,
    f32x4 (*acc)[4]) {
  int tid = threadIdx.x;
  int lane = tid & 63, w = tid >> 6;
  int wm = (w >> 1) * 64, wn = (w & 1) * 64;
  int lq = lane & 15, g = lane >> 4;
  const unsigned short* Ag =
      A + (size_t)(row0 + w * 8 + (lane >> 3)) * K + (lane & 7) * 8;
  const unsigned short* Bg =
      Bw + (size_t)(col0 + w * 8 + (lane >> 3)) * K + (lane & 7) * 8;

  auto stage = [&](int buf, int k0) {
#pragma unroll
    for (int it = 0; it < 4; ++it) {
      __builtin_amdgcn_global_load_lds(
          (as1_uint*)(Ag + (size_t)(it * 32) * K + k0),
          (as3_uint*)&As[buf * 8192 + (it * 32 + w * 8) * 64], 16, 0, 0);
      __builtin_amdgcn_global_load_lds(
          (as1_uint*)(Bg + (size_t)(it * 32) * K + k0),
          (as3_uint*)&Bs[buf * 8192 + (it * 32 + w * 8) * 64], 16, 0, 0);
    }
  };

  stage(0, 0);
  int buf = 0;
  for (int k0 = 0; k0 < K; k0 += 64) {
    __syncthreads();
    if (k0 + 64 < K) stage(buf ^ 1, k0 + 64);
#pragma unroll
    for (int ks = 0; ks < 2; ++ks) {
      bf16x8 af[4], bfr[4];
#pragma unroll
      for (int i = 0; i < 4; ++i)
        af[i] = *(const bf16x8*)&As[buf * 8192 + (wm + i * 16 + lq) * 64 + ks * 32 + g * 8];
#pragma unroll
      for (int j = 0; j < 4; ++j)
        bfr[j] = *(const bf16x8*)&Bs[buf * 8192 + (wn + j * 16 + lq) * 64 + ks * 32 + g * 8];
#pragma unroll
      for (int i = 0; i < 4; ++i)
#pragma unroll
        for (int j = 0; j < 4; ++j)
          acc[i][j] =
              __builtin_amdgcn_mfma_f32_16x16x32_bf16(af[i], bfr[j], acc[i][j], 0, 0, 0);
    }
    buf ^= 1;
  }
}

// QK gemm 128x128 (256 tiles) | Vt gemm 128x64 (256 tiles).
// XCD-aware: XCD x (bid&7) gets tiles x*32+s; s<32 -> QK, s>=32 -> Vt.
__global__ __launch_bounds__(256) void gemm_qkv(
    const unsigned short* __restrict__ vbf, const unsigned short* __restrict__ wqk,
    const unsigned short* __restrict__ wvb, unsigned short* __restrict__ qb,
    unsigned short* __restrict__ kb, unsigned short* __restrict__ vtb) {
  __shared__ unsigned short As[2 * 8192];
  __shared__ unsigned short Bs[2 * 8192];
  int tid = threadIdx.x;
  int lane = tid & 63, w = tid >> 6;
  int lq = lane & 15, g = lane >> 4;
  int bid = blockIdx.x;
  int xcd = bid & 7, s = bid >> 3;

  if (s < 32) {
    int q = xcd * 32 + s;  // 0..255
    int wm = (w >> 1) * 64, wn = (w & 1) * 64;
    f32x4 acc[4][4] = {};
    int row0 = (q & 15) * 128, col0 = (q >> 4) * 128;
    gemm128_dbuf(vbf, wqk, 1024, row0, col0, As, Bs, acc);
    int headg = (col0 + wn) >> 6;  // 0..31 (0-15 q heads, 16-31 k heads)
    int qmode = (headg < 16) ? 1 : 0;
    unsigned short* dst = qmode ? qb : kb;
    size_t colb = (size_t)(headg & 15) * 64;
    float scale = qmode ? 0.125f : 1.f;
#pragma unroll
    for (int i = 0; i < 4; ++i)
#pragma unroll
      for (int r = 0; r < 4; ++r) {
        float sm = 0.f;
#pragma unroll
        for (int j = 0; j < 4; ++j) {
          float vc = fminf(fmaxf(acc[i][j][r], -5.f), 5.f);
          sm += (j == 0 && lq == 0) ? 0.f : vc * vc;  // exclude head col 0
        }
        sm += __shfl_xor(sm, 1);
        sm += __shfl_xor(sm, 2);
        sm += __shfl_xor(sm, 4);
        sm += __shfl_xor(sm, 8);
        float x0 = sqrtf(1.f + sm + EPSF);
        int row = row0 + wm + i * 16 + g * 4 + r;
#pragma unroll
        for (int j = 0; j < 4; ++j) {
          float vc = fminf(fmaxf(acc[i][j][r], -5.f), 5.f);
          float o = (j == 0 && lq == 0) ? (qmode ? -x0 : x0) : vc;
          dst[(size_t)row * 1024 + colb + j * 16 + lq] = f2bf(o * scale);
        }
      }
  } else {
    int t = xcd * 32 + (s - 32);  // 0..255 : Vt 128x64 tile
    int wm = (w >> 1) * 64, wn = (w & 1) * 32;
    int row0 = (t & 7) * 128, col0 = (t >> 3) * 64;
    f32x4 acc[4][2] = {};
    const unsigned short* Ag =
        wvb + (size_t)(row0 + w * 8 + (lane >> 3)) * 1024 + (lane & 7) * 8;
    const unsigned short* Bg =
        vbf + (size_t)(col0 + w * 8 + (lane >> 3)) * 1024 + (lane & 7) * 8;
    auto stage = [&](int buf, int k0) {
#pragma unroll
      for (int it = 0; it < 4; ++it)
        __builtin_amdgcn_global_load_lds(
            (as1_uint*)(Ag + (size_t)(it * 32) * 1024 + k0),
            (as3_uint*)&As[buf * 8192 + (it * 32 + w * 8) * 64], 16, 0, 0);
#pragma unroll
      for (int it = 0; it < 2; ++it)
        __builtin_amdgcn_global_load_lds(
            (as1_uint*)(Bg + (size_t)(it * 32) * 1024 + k0),
            (as3_uint*)&Bs[buf * 4096 + (it * 32 + w * 8) * 64], 16, 0, 0);
    };
    stage(0, 0);
    int buf = 0;
    for (int k0 = 0; k0 < 1024; k0 += 64) {
      __syncthreads();
      if (k0 + 64 < 1024) stage(buf ^ 1, k0 + 64);
#pragma unroll
      for (int ks = 0; ks < 2; ++ks) {
        bf16x8 af[4], bfr[2];
#pragma unroll
        for (int i = 0; i < 4; ++i)
          af[i] = *(const bf16x8*)&As[buf * 8192 + (wm + i * 16 + lq) * 64 + ks * 32 + g * 8];
#pragma unroll
        for (int j = 0; j < 2; ++j)
          bfr[j] = *(const bf16x8*)&Bs[buf * 4096 + (wn + j * 16 + lq) * 64 + ks * 32 + g * 8];
#pragma unroll
        for (int i = 0; i < 4; ++i)
#pragma unroll
          for (int j = 0; j < 2; ++j)
            acc[i][j] =
                __builtin_amdgcn_mfma_f32_16x16x32_bf16(af[i], bfr[j], acc[i][j], 0, 0, 0);
      }
      buf ^= 1;
    }
#pragma unroll
    for (int i = 0; i < 4; ++i)
#pragma unroll
      for (int j = 0; j < 2; ++j)
#pragma unroll
        for (int r = 0; r < 4; ++r)
          vtb[(size_t)(row0 + wm + i * 16 + g * 4 + r) * 2048 + col0 + wn + j * 16 + lq] =
              f2bf(acc[i][j][r]);
  }
}

// Wo gemm: BM=128 BN=64, dbuf staging; 256 blocks, XCD-aware tiling
__global__ __launch_bounds__(256) void gemm_wo(
    const unsigned short* __restrict__ A, const unsigned short* __restrict__ Bw,
    unsigned short* __restrict__ C) {
  __shared__ unsigned short As[2 * 8192];
  __shared__ unsigned short Bs[2 * 4096];
  int tid = threadIdx.x;
  int lane = tid & 63, w = tid >> 6;
  int wm = (w >> 1) * 64, wn = (w & 1) * 32;
  int lq = lane & 15, g = lane >> 4;
  int t = (blockIdx.x & 7) * 32 + (blockIdx.x >> 3);  // XCD-grouped tile id
  int row0 = (t & 15) * 128, col0 = (t >> 4) * 64;
  f32x4 acc[4][2] = {};
  const unsigned short* Ag =
      A + (size_t)(row0 + w * 8 + (lane >> 3)) * 1024 + (lane & 7) * 8;
  const unsigned short* Bg =
      Bw + (size_t)(col0 + w * 8 + (lane >> 3)) * 1024 + (lane & 7) * 8;

  auto stage = [&](int buf, int k0) {
#pragma unroll
    for (int it = 0; it < 4; ++it)
      __builtin_amdgcn_global_load_lds(
          (as1_uint*)(Ag + (size_t)(it * 32) * 1024 + k0),
          (as3_uint*)&As[buf * 8192 + (it * 32 + w * 8) * 64], 16, 0, 0);
#pragma unroll
    for (int it = 0; it < 2; ++it)
      __builtin_amdgcn_global_load_lds(
          (as1_uint*)(Bg + (size_t)(it * 32) * 1024 + k0),
          (as3_uint*)&Bs[buf * 4096 + (it * 32 + w * 8) * 64], 16, 0, 0);
  };

  stage(0, 0);
  int buf = 0;
  for (int k0 = 0; k0 < 1024; k0 += 64) {
    __syncthreads();
    if (k0 + 64 < 1024) stage(buf ^ 1, k0 + 64);
#pragma unroll
    for (int ks = 0; ks < 2; ++ks) {
      bf16x8 af[4], bfr[2];
#pragma unroll
      for (int i = 0; i < 4; ++i)
        af[i] = *(const bf16x8*)&As[buf * 8192 + (wm + i * 16 + lq) * 64 + ks * 32 + g * 8];
#pragma unroll
      for (int j = 0; j < 2; ++j)
        bfr[j] = *(const bf16x8*)&Bs[buf * 4096 + (wn + j * 16 + lq) * 64 + ks * 32 + g * 8];
#pragma unroll
      for (int i = 0; i < 4; ++i)
#pragma unroll
        for (int j = 0; j < 2; ++j)
          acc[i][j] =
              __builtin_amdgcn_mfma_f32_16x16x32_bf16(af[i], bfr[j], acc[i][j], 0, 0, 0);
    }
    buf ^= 1;
  }
#pragma unroll
  for (int i = 0; i < 4; ++i)
#pragma unroll
    for (int j = 0; j < 2; ++j)
#pragma unroll
      for (int r = 0; r < 4; ++r)
        C[(size_t)(row0 + wm + i * 16 + g * 4 + r) * 1024 + col0 + wn + j * 16 + lq] =
            f2bf(acc[i][j][r]);
}

// ---- MFMA flash attention: 4 waves, QBLK=64, KVBLK=128, gload_lds dbuf,
//      XCD-grouped, defer-max, setprio, native-cvt P pack ----
__global__ __launch_bounds__(256) void attn_mfma(
    const unsigned short* __restrict__ Qb, const unsigned short* __restrict__ Kb,
    const unsigned short* __restrict__ Vtb, unsigned short* __restrict__ Obf) {
  __shared__ unsigned short Ks[2][128 * 64];   // K rows x d
  __shared__ unsigned short Vs[2][64 * 128];   // d rows x tokens
  __shared__ unsigned short Ps[4 * 16 * 128];
  int tid = threadIdx.x;
  int lane = tid & 63, w = tid >> 6;
  int g = lane >> 4, lq = lane & 15;
  int bid = blockIdx.x;
  int idx = bid >> 3;               // 0..63
  int bh = (bid & 7) * 4 + (idx & 3);
  int qt = idx >> 2;                // 0..15
  int b = bh >> 4, h = bh & 15;

  const unsigned short* qrow =
      Qb + (size_t)(b * 1024 + qt * 64 + w * 16 + lq) * 1024 + h * 64;
  bf16x8 qf0 = *(const bf16x8*)(qrow + g * 8);
  bf16x8 qf1 = *(const bf16x8*)(qrow + 32 + g * 8);

  float mreg = -1e30f, lreg = 0.f;
  f32x4 acc[4] = {};
  unsigned short* Pw = Ps + w * 16 * 128;
  int sx = 8 * (lq & 7);

  const unsigned short* Ksrc = Kb + (size_t)(b * 1024) * 1024 + h * 64;
  const unsigned short* Vsrc = Vtb + (size_t)(h * 64) * 2048 + b * 1024;

  int skr = lane >> 3;
  int scgk = (lane & 7) ^ skr;
  const unsigned short* Kp = Ksrc + (size_t)(w * 8 + skr) * 1024 + scgk * 8;
  int svr = w * 4 + (lane >> 4);  // 0..15
  int scgv = (lane & 15) ^ (svr & 7);
  const unsigned short* Vp = Vsrc + (size_t)svr * 2048 + scgv * 8;

  auto stage = [&](int buf, int kt) {
#pragma unroll
    for (int it = 0; it < 4; ++it) {
      __builtin_amdgcn_global_load_lds(
          (as1_uint*)(Kp + (size_t)(kt * 128 + it * 32) * 1024),
          (as3_uint*)&Ks[buf][(it * 32 + w * 8) * 64], 16, 0, 0);
      __builtin_amdgcn_global_load_lds(
          (as1_uint*)(Vp + (size_t)(it * 16) * 2048 + kt * 128),
          (as3_uint*)&Vs[buf][(it * 16 + w * 4) * 128], 16, 0, 0);
    }
  };

  auto compute = [&](int buf) {
    f32x4 st[8];
    __builtin_amdgcn_s_setprio(1);
#pragma unroll
    for (int i = 0; i < 8; ++i) {
      int ro = i * 16 + lq;
      int rb = ro * 64, xx = 8 * (ro & 7);
      bf16x8 a0 = *(const bf16x8*)&Ks[buf][rb + ((g * 8) ^ xx)];
      bf16x8 a1 = *(const bf16x8*)&Ks[buf][rb + ((32 + g * 8) ^ xx)];
      f32x4 z = {};
      z = __builtin_amdgcn_mfma_f32_16x16x32_bf16(a0, qf0, z, 0, 0, 0);
      st[i] = __builtin_amdgcn_mfma_f32_16x16x32_bf16(a1, qf1, z, 0, 0, 0);
    }
    __builtin_amdgcn_s_setprio(0);
    // max3-friendly tree reduction over 32 scores (log-depth, v_max3 fusable)
    float m4[8];
#pragma unroll
    for (int i = 0; i < 8; ++i)
      m4[i] = fmaxf(fmaxf(st[i][0], st[i][1]), fmaxf(st[i][2], st[i][3]));
    float m01 = fmaxf(fmaxf(m4[0], m4[1]), fmaxf(m4[2], m4[3]));
    float m23 = fmaxf(fmaxf(m4[4], m4[5]), fmaxf(m4[6], m4[7]));
    float pmax = fmaxf(m01, m23);
    pmax = fmaxf(pmax, __shfl_xor(pmax, 16));
    pmax = fmaxf(pmax, __shfl_xor(pmax, 32));
    if (__any(pmax > mreg + 8.f)) {
      float nm = fmaxf(mreg, pmax);
      float sc_ = __expf(mreg - nm);
      mreg = nm;
      lreg *= sc_;
      float scr[4];
#pragma unroll
      for (int r = 0; r < 4; ++r) scr[r] = __shfl(sc_, g * 4 + r);
#pragma unroll
      for (int jj = 0; jj < 4; ++jj)
#pragma unroll
        for (int r = 0; r < 4; ++r) acc[jj][r] *= scr[r];
    }
    float ps = 0.f;
#pragma unroll
    for (int i = 0; i < 8; ++i) {
      float p0 = __expf(st[i][0] - mreg);
      float p1 = __expf(st[i][1] - mreg);
      float p2 = __expf(st[i][2] - mreg);
      float p3 = __expf(st[i][3] - mreg);
      ps += (p0 + p1) + (p2 + p3);
      bf16x4 pv;
      pv[0] = (__bf16)p0; pv[1] = (__bf16)p1;
      pv[2] = (__bf16)p2; pv[3] = (__bf16)p3;  // -> v_cvt_pk_bf16_f32 x2
      *(bf16x4*)&Pw[lq * 128 + ((g * 4 + i * 16) ^ sx)] = pv;
    }
    ps += __shfl_xor(ps, 16);
    ps += __shfl_xor(ps, 32);
    lreg += ps;

    __builtin_amdgcn_s_setprio(1);
#pragma unroll
    for (int ks = 0; ks < 4; ++ks) {
      bf16x8 pa = *(const bf16x8*)&Pw[lq * 128 + ((ks * 32 + g * 8) ^ sx)];
#pragma unroll
      for (int jj = 0; jj < 4; ++jj) {
        int vr = 16 * jj + lq;
        bf16x8 vb = *(const bf16x8*)&Vs[buf][vr * 128 + ((ks * 32 + g * 8) ^ (8 * (vr & 7)))];
        acc[jj] = __builtin_amdgcn_mfma_f32_16x16x32_bf16(pa, vb, acc[jj], 0, 0, 0);
      }
    }
    __builtin_amdgcn_s_setprio(0);
  };

  stage(0, 0);
  int buf = 0;
  for (int kt = 0; kt < 8; ++kt) {
    __syncthreads();
    if (kt + 1 < 8) stage(buf ^ 1, kt + 1);
    compute(buf);
    buf ^= 1;
  }

  float linv = 1.f / lreg;
  float ilr[4];
#pragma unroll
  for (int r = 0; r < 4; ++r) ilr[r] = __shfl(linv, g * 4 + r);
  unsigned short* obase =
      Obf + (size_t)(b * 1024 + qt * 64 + w * 16) * 1024 + h * 64;
#pragma unroll
  for (int r = 0; r < 4; ++r)
#pragma unroll
    for (int jj = 0; jj < 4; ++jj)
      obase[(size_t)(g * 4 + r) * 1024 + 16 * jj + lq] = f2bf(acc[jj][r] * ilr[r]);
}

// ---------------- exp_map at origin + project (bf16 in, f32 out) ----------------
__global__ __launch_bounds__(256) void expmap_project(
    const unsigned short* __restrict__ c2, float* __restrict__ out) {
  int row = blockIdx.x;
  int tid = threadIdx.x;
  const unsigned short* cr = c2 + (size_t)row * 1024;
  float vals[4];
  float ssq = 0.f;
#pragma unroll
  for (int i = 0; i < 4; ++i) {
    int c = tid + i * 256;
    float t = bf2f(cr[c]);
    vals[i] = (c == 0) ? 0.f : t;
    ssq += vals[i] * vals[i];
  }
#pragma unroll
  for (int off = 32; off; off >>= 1) ssq += __shfl_xor(ssq, off);
  __shared__ float red1[4], red2[4];
  int wv = tid >> 6;
  if ((tid & 63) == 0) red1[wv] = ssq;
  __syncthreads();
  ssq = red1[0] + red1[1] + red1[2] + red1[3];
  float vn = fminf(sqrtf(ssq + EPSF), 5.f);
  float bf = sinhf(vn) / (vn + EPSF);
  float s2 = 0.f;
#pragma unroll
  for (int i = 0; i < 4; ++i) {
    float r = fminf(fmaxf(bf * vals[i], -8.f), 8.f);
    vals[i] = r;
    s2 += r * r;
  }
#pragma unroll
  for (int off = 32; off; off >>= 1) s2 += __shfl_xor(s2, off);
  if ((tid & 63) == 0) red2[wv] = s2;
  __syncthreads();
  s2 = red2[0] + red2[1] + red2[2] + red2[3];
  float x0 = sqrtf(1.f + s2 + EPSF);
  float* orow = out + (size_t)row * 1024;
#pragma unroll
  for (int i = 0; i < 4; ++i) {
    int c = tid + i * 256;
    orow[c] = (c == 0) ? x0 : vals[i];
  }
}

extern "C" void kernel_launch(void* const* d_in, const int* in_sizes, int n_in,
                              void* d_out, int out_size, void* d_ws, size_t ws_size,
                              hipStream_t stream) {
  (void)in_sizes; (void)n_in; (void)out_size; (void)ws_size;
  const float* x  = (const float*)d_in[0];
  const float* Wq = (const float*)d_in[1];
  const float* Wk = (const float*)d_in[2];
  const float* Wv = (const float*)d_in[3];
  const float* Wo = (const float*)d_in[4];
  float* out = (float*)d_out;

  char* w = (char*)d_ws;
  unsigned short* vbf = (unsigned short*)w; w += (size_t)2048 * 1024 * 2;
  unsigned short* wqk = (unsigned short*)w; w += (size_t)2048 * 1024 * 2;
  unsigned short* wvb = (unsigned short*)w; w += (size_t)1024 * 1024 * 2;
  unsigned short* wob = (unsigned short*)w; w += (size_t)1024 * 1024 * 2;
  unsigned short* vtb = (unsigned short*)w; w += (size_t)1024 * 2048 * 2;
  unsigned short* qb  = (unsigned short*)w; w += (size_t)2048 * 1024 * 2;
  unsigned short* kb  = (unsigned short*)w; w += (size_t)2048 * 1024 * 2;
  unsigned short* aob = (unsigned short*)w; w += (size_t)2048 * 1024 * 2;
  unsigned short* c2  = (unsigned short*)w; w += (size_t)2048 * 1024 * 2;

  prep_and_conv<<<6144, 256, 0, stream>>>(x, Wq, Wk, Wv, Wo, vbf, wqk, wvb, wob);

  gemm_qkv<<<512, 256, 0, stream>>>(vbf, wqk, wvb, qb, kb, vtb);

  attn_mfma<<<512, 256, 0, stream>>>(qb, kb, vtb, aob);

  gemm_wo<<<256, 256, 0, stream>>>(aob, wob, c2);
  expmap_project<<<2048, 256, 0, stream>>>(c2, out);
}

// Round 14
// 79.563 us; speedup vs baseline: 1.0788x; 1.0018x over previous
//
#include <hip/hip_runtime.h>

#define EPSF 1e-6f

typedef __bf16 bf16x8 __attribute__((ext_vector_type(8)));
typedef __bf16 bf16x4 __attribute__((ext_vector_type(4)));
typedef float f32x4 __attribute__((ext_vector_type(4)));
typedef __attribute__((address_space(3))) unsigned int as3_uint;
typedef __attribute__((address_space(1))) const unsigned int as1_uint;

// Native cast: compiler emits v_cvt_pk_bf16_f32 and pairs conversions (m240).
__device__ __forceinline__ unsigned short f2bf(float f) {
  return __builtin_bit_cast(unsigned short, (__bf16)f);
}
__device__ __forceinline__ float bf2f(unsigned short u) {
  unsigned int v = (unsigned int)u << 16;
  return __builtin_bit_cast(float, v);
}

// ------- fused: log_map(x) -> vbf (blocks 0..2047) | weight conv (blocks 2048..6143) -------
// logmap path vectorized: thread owns 4 consecutive cols (f32x4 load, ushort4 store).
__global__ __launch_bounds__(256) void prep_and_conv(
    const float* __restrict__ x, const float* __restrict__ Wq,
    const float* __restrict__ Wk, const float* __restrict__ Wv,
    const float* __restrict__ Wo, unsigned short* __restrict__ vbf,
    unsigned short* __restrict__ wqk, unsigned short* __restrict__ wvb,
    unsigned short* __restrict__ wob) {
  int bid = blockIdx.x;
  int tid = threadIdx.x;
  if (bid >= 2048) {
    int t = bid - 2048;
    int y = t >> 10;
    const float* src = (y == 0) ? Wq : (y == 1) ? Wk : (y == 2) ? Wv : Wo;
    unsigned short* dst = (y == 0) ? wqk : (y == 1) ? wqk + 1048576
                          : (y == 2) ? wvb : wob;
    int i = (t & 1023) * 256 + tid;
    f32x4 v = ((const f32x4*)src)[i];
    ushort4 o;
    o.x = f2bf(v[0]); o.y = f2bf(v[1]); o.z = f2bf(v[2]); o.w = f2bf(v[3]);
    ((ushort4*)dst)[i] = o;
    return;
  }
  int row = bid;
  const float* xr = x + (size_t)row * 1024;
  f32x4 xv = *(const f32x4*)&xr[tid * 4];
  float vals[4];
  float ssq = 0.f;
#pragma unroll
  for (int i = 0; i < 4; ++i) {
    float t = xv[i];
    if (tid == 0 && i == 0) {
      vals[i] = 0.f;
    } else {
      t = fminf(fmaxf(t, -8.f), 8.f);
      vals[i] = t;
      ssq += t * t;
    }
  }
#pragma unroll
  for (int off = 32; off; off >>= 1) ssq += __shfl_xor(ssq, off);
  __shared__ float red[4];
  int wv = tid >> 6;
  if ((tid & 63) == 0) red[wv] = ssq;
  __syncthreads();
  ssq = red[0] + red[1] + red[2] + red[3];

  float y0 = sqrtf(1.f + ssq + EPSF);
  float xy = fminf(-y0, -(1.f + EPSF));
  float mxy = fmaxf(-xy, 1.f + EPSF);
  float dd = fmaxf(acoshf(mxy), 0.001f);
  float d0 = y0 + xy;
  float inn = ssq - d0 * d0;
  float dn = sqrtf(fmaxf(inn, EPSF));
  float inv = dd / (dn + EPSF);

  unsigned short* vr = vbf + (size_t)row * 1024;
  ushort4 o4;
  o4.x = f2bf((tid == 0) ? d0 * inv : vals[0] * inv);
  o4.y = f2bf(vals[1] * inv);
  o4.z = f2bf(vals[2] * inv);
  o4.w = f2bf(vals[3] * inv);
  *(ushort4*)&vr[tid * 4] = o4;
}

// ---------- 128x128-tile GEMM body, double-buffered gload_lds staging ----------
__device__ __forceinline__ void gemm128_dbuf(
    const unsigned short* __restrict__ A, const unsigned short* __restrict__ Bw,
    int K, int row0, int col0, unsigned short* As, unsigned short* Bs,
    f32x4 (*acc)[4]) {
  int tid = threadIdx.x;
  int lane = tid & 63, w = tid >> 6;
  int wm = (w >> 1) * 64, wn = (w & 1) * 64;
  int lq = lane & 15, g = lane >> 4;
  const unsigned short* Ag =
      A + (size_t)(row0 + w * 8 + (lane >> 3)) * K + (lane & 7) * 8;
  const unsigned short* Bg =
      Bw + (size_t)(col0 + w * 8 + (lane >> 3)) * K + (lane & 7) * 8;

  auto stage = [&](int buf, int k0) {
#pragma unroll
    for (int it = 0; it < 4; ++it) {
      __builtin_amdgcn_global_load_lds(
          (as1_uint*)(Ag + (size_t)(it * 32) * K + k0),
          (as3_uint*)&As[buf * 8192 + (it * 32 + w * 8) * 64], 16, 0, 0);
      __builtin_amdgcn_global_load_lds(
          (as1_uint*)(Bg + (size_t)(it * 32) * K + k0),
          (as3_uint*)&Bs[buf * 8192 + (it * 32 + w * 8) * 64], 16, 0, 0);
    }
  };

  stage(0, 0);
  int buf = 0;
  for (int k0 = 0; k0 < K; k0 += 64) {
    __syncthreads();
    if (k0 + 64 < K) stage(buf ^ 1, k0 + 64);
#pragma unroll
    for (int ks = 0; ks < 2; ++ks) {
      bf16x8 af[4], bfr[4];
#pragma unroll
      for (int i = 0; i < 4; ++i)
        af[i] = *(const bf16x8*)&As[buf * 8192 + (wm + i * 16 + lq) * 64 + ks * 32 + g * 8];
#pragma unroll
      for (int j = 0; j < 4; ++j)
        bfr[j] = *(const bf16x8*)&Bs[buf * 8192 + (wn + j * 16 + lq) * 64 + ks * 32 + g * 8];
#pragma unroll
      for (int i = 0; i < 4; ++i)
#pragma unroll
        for (int j = 0; j < 4; ++j)
          acc[i][j] =
              __builtin_amdgcn_mfma_f32_16x16x32_bf16(af[i], bfr[j], acc[i][j], 0, 0, 0);
    }
    buf ^= 1;
  }
}

// QK gemm 128x128 (256 tiles) | Vt gemm 128x64 (256 tiles).
// XCD-aware: XCD x (bid&7) gets tiles x*32+s; s<32 -> QK, s>=32 -> Vt.
__global__ __launch_bounds__(256) void gemm_qkv(
    const unsigned short* __restrict__ vbf, const unsigned short* __restrict__ wqk,
    const unsigned short* __restrict__ wvb, unsigned short* __restrict__ qb,
    unsigned short* __restrict__ kb, unsigned short* __restrict__ vtb) {
  __shared__ unsigned short As[2 * 8192];
  __shared__ unsigned short Bs[2 * 8192];
  int tid = threadIdx.x;
  int lane = tid & 63, w = tid >> 6;
  int lq = lane & 15, g = lane >> 4;
  int bid = blockIdx.x;
  int xcd = bid & 7, s = bid >> 3;

  if (s < 32) {
    int q = xcd * 32 + s;  // 0..255
    int wm = (w >> 1) * 64, wn = (w & 1) * 64;
    f32x4 acc[4][4] = {};
    int row0 = (q & 15) * 128, col0 = (q >> 4) * 128;
    gemm128_dbuf(vbf, wqk, 1024, row0, col0, As, Bs, acc);
    int headg = (col0 + wn) >> 6;  // 0..31 (0-15 q heads, 16-31 k heads)
    int qmode = (headg < 16) ? 1 : 0;
    unsigned short* dst = qmode ? qb : kb;
    size_t colb = (size_t)(headg & 15) * 64;
    float scale = qmode ? 0.125f : 1.f;
#pragma unroll
    for (int i = 0; i < 4; ++i)
#pragma unroll
      for (int r = 0; r < 4; ++r) {
        float sm = 0.f;
#pragma unroll
        for (int j = 0; j < 4; ++j) {
          float vc = fminf(fmaxf(acc[i][j][r], -5.f), 5.f);
          sm += (j == 0 && lq == 0) ? 0.f : vc * vc;  // exclude head col 0
        }
        sm += __shfl_xor(sm, 1);
        sm += __shfl_xor(sm, 2);
        sm += __shfl_xor(sm, 4);
        sm += __shfl_xor(sm, 8);
        float x0 = sqrtf(1.f + sm + EPSF);
        int row = row0 + wm + i * 16 + g * 4 + r;
#pragma unroll
        for (int j = 0; j < 4; ++j) {
          float vc = fminf(fmaxf(acc[i][j][r], -5.f), 5.f);
          float o = (j == 0 && lq == 0) ? (qmode ? -x0 : x0) : vc;
          dst[(size_t)row * 1024 + colb + j * 16 + lq] = f2bf(o * scale);
        }
      }
  } else {
    int t = xcd * 32 + (s - 32);  // 0..255 : Vt 128x64 tile
    int wm = (w >> 1) * 64, wn = (w & 1) * 32;
    int row0 = (t & 7) * 128, col0 = (t >> 3) * 64;
    f32x4 acc[4][2] = {};
    const unsigned short* Ag =
        wvb + (size_t)(row0 + w * 8 + (lane >> 3)) * 1024 + (lane & 7) * 8;
    const unsigned short* Bg =
        vbf + (size_t)(col0 + w * 8 + (lane >> 3)) * 1024 + (lane & 7) * 8;
    auto stage = [&](int buf, int k0) {
#pragma unroll
      for (int it = 0; it < 4; ++it)
        __builtin_amdgcn_global_load_lds(
            (as1_uint*)(Ag + (size_t)(it * 32) * 1024 + k0),
            (as3_uint*)&As[buf * 8192 + (it * 32 + w * 8) * 64], 16, 0, 0);
#pragma unroll
      for (int it = 0; it < 2; ++it)
        __builtin_amdgcn_global_load_lds(
            (as1_uint*)(Bg + (size_t)(it * 32) * 1024 + k0),
            (as3_uint*)&Bs[buf * 4096 + (it * 32 + w * 8) * 64], 16, 0, 0);
    };
    stage(0, 0);
    int buf = 0;
    for (int k0 = 0; k0 < 1024; k0 += 64) {
      __syncthreads();
      if (k0 + 64 < 1024) stage(buf ^ 1, k0 + 64);
#pragma unroll
      for (int ks = 0; ks < 2; ++ks) {
        bf16x8 af[4], bfr[2];
#pragma unroll
        for (int i = 0; i < 4; ++i)
          af[i] = *(const bf16x8*)&As[buf * 8192 + (wm + i * 16 + lq) * 64 + ks * 32 + g * 8];
#pragma unroll
        for (int j = 0; j < 2; ++j)
          bfr[j] = *(const bf16x8*)&Bs[buf * 4096 + (wn + j * 16 + lq) * 64 + ks * 32 + g * 8];
#pragma unroll
        for (int i = 0; i < 4; ++i)
#pragma unroll
          for (int j = 0; j < 2; ++j)
            acc[i][j] =
                __builtin_amdgcn_mfma_f32_16x16x32_bf16(af[i], bfr[j], acc[i][j], 0, 0, 0);
      }
      buf ^= 1;
    }
#pragma unroll
    for (int i = 0; i < 4; ++i)
#pragma unroll
      for (int j = 0; j < 2; ++j)
#pragma unroll
        for (int r = 0; r < 4; ++r)
          vtb[(size_t)(row0 + wm + i * 16 + g * 4 + r) * 2048 + col0 + wn + j * 16 + lq] =
              f2bf(acc[i][j][r]);
  }
}

// Wo gemm: BM=128 BN=64, dbuf staging; 256 blocks, XCD-aware tiling
__global__ __launch_bounds__(256) void gemm_wo(
    const unsigned short* __restrict__ A, const unsigned short* __restrict__ Bw,
    unsigned short* __restrict__ C) {
  __shared__ unsigned short As[2 * 8192];
  __shared__ unsigned short Bs[2 * 4096];
  int tid = threadIdx.x;
  int lane = tid & 63, w = tid >> 6;
  int wm = (w >> 1) * 64, wn = (w & 1) * 32;
  int lq = lane & 15, g = lane >> 4;
  int t = (blockIdx.x & 7) * 32 + (blockIdx.x >> 3);  // XCD-grouped tile id
  int row0 = (t & 15) * 128, col0 = (t >> 4) * 64;
  f32x4 acc[4][2] = {};
  const unsigned short* Ag =
      A + (size_t)(row0 + w * 8 + (lane >> 3)) * 1024 + (lane & 7) * 8;
  const unsigned short* Bg =
      Bw + (size_t)(col0 + w * 8 + (lane >> 3)) * 1024 + (lane & 7) * 8;

  auto stage = [&](int buf, int k0) {
#pragma unroll
    for (int it = 0; it < 4; ++it)
      __builtin_amdgcn_global_load_lds(
          (as1_uint*)(Ag + (size_t)(it * 32) * 1024 + k0),
          (as3_uint*)&As[buf * 8192 + (it * 32 + w * 8) * 64], 16, 0, 0);
#pragma unroll
    for (int it = 0; it < 2; ++it)
      __builtin_amdgcn_global_load_lds(
          (as1_uint*)(Bg + (size_t)(it * 32) * 1024 + k0),
          (as3_uint*)&Bs[buf * 4096 + (it * 32 + w * 8) * 64], 16, 0, 0);
  };

  stage(0, 0);
  int buf = 0;
  for (int k0 = 0; k0 < 1024; k0 += 64) {
    __syncthreads();
    if (k0 + 64 < 1024) stage(buf ^ 1, k0 + 64);
#pragma unroll
    for (int ks = 0; ks < 2; ++ks) {
      bf16x8 af[4], bfr[2];
#pragma unroll
      for (int i = 0; i < 4; ++i)
        af[i] = *(const bf16x8*)&As[buf * 8192 + (wm + i * 16 + lq) * 64 + ks * 32 + g * 8];
#pragma unroll
      for (int j = 0; j < 2; ++j)
        bfr[j] = *(const bf16x8*)&Bs[buf * 4096 + (wn + j * 16 + lq) * 64 + ks * 32 + g * 8];
#pragma unroll
      for (int i = 0; i < 4; ++i)
#pragma unroll
        for (int j = 0; j < 2; ++j)
          acc[i][j] =
              __builtin_amdgcn_mfma_f32_16x16x32_bf16(af[i], bfr[j], acc[i][j], 0, 0, 0);
    }
    buf ^= 1;
  }
#pragma unroll
  for (int i = 0; i < 4; ++i)
#pragma unroll
    for (int j = 0; j < 2; ++j)
#pragma unroll
      for (int r = 0; r < 4; ++r)
        C[(size_t)(row0 + wm + i * 16 + g * 4 + r) * 1024 + col0 + wn + j * 16 + lq] =
            f2bf(acc[i][j][r]);
}

// ---- MFMA flash attention: 4 waves, QBLK=64, KVBLK=128, gload_lds dbuf,
//      XCD-grouped, defer-max, setprio, native-cvt P pack ----
__global__ __launch_bounds__(256) void attn_mfma(
    const unsigned short* __restrict__ Qb, const unsigned short* __restrict__ Kb,
    const unsigned short* __restrict__ Vtb, unsigned short* __restrict__ Obf) {
  __shared__ unsigned short Ks[2][128 * 64];   // K rows x d
  __shared__ unsigned short Vs[2][64 * 128];   // d rows x tokens
  __shared__ unsigned short Ps[4 * 16 * 128];
  int tid = threadIdx.x;
  int lane = tid & 63, w = tid >> 6;
  int g = lane >> 4, lq = lane & 15;
  int bid = blockIdx.x;
  int idx = bid >> 3;               // 0..63
  int bh = (bid & 7) * 4 + (idx & 3);
  int qt = idx >> 2;                // 0..15
  int b = bh >> 4, h = bh & 15;

  const unsigned short* qrow =
      Qb + (size_t)(b * 1024 + qt * 64 + w * 16 + lq) * 1024 + h * 64;
  bf16x8 qf0 = *(const bf16x8*)(qrow + g * 8);
  bf16x8 qf1 = *(const bf16x8*)(qrow + 32 + g * 8);

  float mreg = -1e30f, lreg = 0.f;
  f32x4 acc[4] = {};
  unsigned short* Pw = Ps + w * 16 * 128;
  int sx = 8 * (lq & 7);

  const unsigned short* Ksrc = Kb + (size_t)(b * 1024) * 1024 + h * 64;
  const unsigned short* Vsrc = Vtb + (size_t)(h * 64) * 2048 + b * 1024;

  int skr = lane >> 3;
  int scgk = (lane & 7) ^ skr;
  const unsigned short* Kp = Ksrc + (size_t)(w * 8 + skr) * 1024 + scgk * 8;
  int svr = w * 4 + (lane >> 4);  // 0..15
  int scgv = (lane & 15) ^ (svr & 7);
  const unsigned short* Vp = Vsrc + (size_t)svr * 2048 + scgv * 8;

  auto stage = [&](int buf, int kt) {
#pragma unroll
    for (int it = 0; it < 4; ++it) {
      __builtin_amdgcn_global_load_lds(
          (as1_uint*)(Kp + (size_t)(kt * 128 + it * 32) * 1024),
          (as3_uint*)&Ks[buf][(it * 32 + w * 8) * 64], 16, 0, 0);
      __builtin_amdgcn_global_load_lds(
          (as1_uint*)(Vp + (size_t)(it * 16) * 2048 + kt * 128),
          (as3_uint*)&Vs[buf][(it * 16 + w * 4) * 128], 16, 0, 0);
    }
  };

  auto compute = [&](int buf) {
    f32x4 st[8];
    __builtin_amdgcn_s_setprio(1);
#pragma unroll
    for (int i = 0; i < 8; ++i) {
      int ro = i * 16 + lq;
      int rb = ro * 64, xx = 8 * (ro & 7);
      bf16x8 a0 = *(const bf16x8*)&Ks[buf][rb + ((g * 8) ^ xx)];
      bf16x8 a1 = *(const bf16x8*)&Ks[buf][rb + ((32 + g * 8) ^ xx)];
      f32x4 z = {};
      z = __builtin_amdgcn_mfma_f32_16x16x32_bf16(a0, qf0, z, 0, 0, 0);
      st[i] = __builtin_amdgcn_mfma_f32_16x16x32_bf16(a1, qf1, z, 0, 0, 0);
    }
    __builtin_amdgcn_s_setprio(0);
    // max3-friendly tree reduction over 32 scores
    float m4[8];
#pragma unroll
    for (int i = 0; i < 8; ++i)
      m4[i] = fmaxf(fmaxf(st[i][0], st[i][1]), fmaxf(st[i][2], st[i][3]));
    float m01 = fmaxf(fmaxf(m4[0], m4[1]), fmaxf(m4[2], m4[3]));
    float m23 = fmaxf(fmaxf(m4[4], m4[5]), fmaxf(m4[6], m4[7]));
    float pmax = fmaxf(m01, m23);
    pmax = fmaxf(pmax, __shfl_xor(pmax, 16));
    pmax = fmaxf(pmax, __shfl_xor(pmax, 32));
    if (__any(pmax > mreg + 8.f)) {
      float nm = fmaxf(mreg, pmax);
      float sc_ = __expf(mreg - nm);
      mreg = nm;
      lreg *= sc_;
      float scr[4];
#pragma unroll
      for (int r = 0; r < 4; ++r) scr[r] = __shfl(sc_, g * 4 + r);
#pragma unroll
      for (int jj = 0; jj < 4; ++jj)
#pragma unroll
        for (int r = 0; r < 4; ++r) acc[jj][r] *= scr[r];
    }
    float ps = 0.f;
#pragma unroll
    for (int i = 0; i < 8; ++i) {
      float p0 = __expf(st[i][0] - mreg);
      float p1 = __expf(st[i][1] - mreg);
      float p2 = __expf(st[i][2] - mreg);
      float p3 = __expf(st[i][3] - mreg);
      ps += (p0 + p1) + (p2 + p3);
      bf16x4 pv;
      pv[0] = (__bf16)p0; pv[1] = (__bf16)p1;
      pv[2] = (__bf16)p2; pv[3] = (__bf16)p3;  // -> v_cvt_pk_bf16_f32 x2
      *(bf16x4*)&Pw[lq * 128 + ((g * 4 + i * 16) ^ sx)] = pv;
    }
    ps += __shfl_xor(ps, 16);
    ps += __shfl_xor(ps, 32);
    lreg += ps;

    __builtin_amdgcn_s_setprio(1);
#pragma unroll
    for (int ks = 0; ks < 4; ++ks) {
      bf16x8 pa = *(const bf16x8*)&Pw[lq * 128 + ((ks * 32 + g * 8) ^ sx)];
#pragma unroll
      for (int jj = 0; jj < 4; ++jj) {
        int vr = 16 * jj + lq;
        bf16x8 vb = *(const bf16x8*)&Vs[buf][vr * 128 + ((ks * 32 + g * 8) ^ (8 * (vr & 7)))];
        acc[jj] = __builtin_amdgcn_mfma_f32_16x16x32_bf16(pa, vb, acc[jj], 0, 0, 0);
      }
    }
    __builtin_amdgcn_s_setprio(0);
  };

  stage(0, 0);
  int buf = 0;
  for (int kt = 0; kt < 8; ++kt) {
    __syncthreads();
    if (kt + 1 < 8) stage(buf ^ 1, kt + 1);
    compute(buf);
    buf ^= 1;
  }

  float linv = 1.f / lreg;
  float ilr[4];
#pragma unroll
  for (int r = 0; r < 4; ++r) ilr[r] = __shfl(linv, g * 4 + r);
  unsigned short* obase =
      Obf + (size_t)(b * 1024 + qt * 64 + w * 16) * 1024 + h * 64;
#pragma unroll
  for (int r = 0; r < 4; ++r)
#pragma unroll
    for (int jj = 0; jj < 4; ++jj)
      obase[(size_t)(g * 4 + r) * 1024 + 16 * jj + lq] = f2bf(acc[jj][r] * ilr[r]);
}

// ---------------- exp_map at origin + project (bf16 in, f32 out), vectorized ----------------
__global__ __launch_bounds__(256) void expmap_project(
    const unsigned short* __restrict__ c2, float* __restrict__ out) {
  int row = blockIdx.x;
  int tid = threadIdx.x;
  const unsigned short* cr = c2 + (size_t)row * 1024;
  ushort4 cv = *(const ushort4*)&cr[tid * 4];
  float vals[4];
  vals[0] = (tid == 0) ? 0.f : bf2f(cv.x);
  vals[1] = bf2f(cv.y);
  vals[2] = bf2f(cv.z);
  vals[3] = bf2f(cv.w);
  float ssq = vals[0] * vals[0] + vals[1] * vals[1] +
              vals[2] * vals[2] + vals[3] * vals[3];
#pragma unroll
  for (int off = 32; off; off >>= 1) ssq += __shfl_xor(ssq, off);
  __shared__ float red1[4], red2[4];
  int wv = tid >> 6;
  if ((tid & 63) == 0) red1[wv] = ssq;
  __syncthreads();
  ssq = red1[0] + red1[1] + red1[2] + red1[3];
  float vn = fminf(sqrtf(ssq + EPSF), 5.f);
  float bf = sinhf(vn) / (vn + EPSF);
  float s2 = 0.f;
#pragma unroll
  for (int i = 0; i < 4; ++i) {
    float r = fminf(fmaxf(bf * vals[i], -8.f), 8.f);
    vals[i] = r;
    s2 += r * r;
  }
#pragma unroll
  for (int off = 32; off; off >>= 1) s2 += __shfl_xor(s2, off);
  if ((tid & 63) == 0) red2[wv] = s2;
  __syncthreads();
  s2 = red2[0] + red2[1] + red2[2] + red2[3];
  float x0 = sqrtf(1.f + s2 + EPSF);
  float* orow = out + (size_t)row * 1024;
  f32x4 ov;
  ov[0] = (tid == 0) ? x0 : vals[0];
  ov[1] = vals[1];
  ov[2] = vals[2];
  ov[3] = vals[3];
  *(f32x4*)&orow[tid * 4] = ov;
}

extern "C" void kernel_launch(void* const* d_in, const int* in_sizes, int n_in,
                              void* d_out, int out_size, void* d_ws, size_t ws_size,
                              hipStream_t stream) {
  (void)in_sizes; (void)n_in; (void)out_size; (void)ws_size;
  const float* x  = (const float*)d_in[0];
  const float* Wq = (const float*)d_in[1];
  const float* Wk = (const float*)d_in[2];
  const float* Wv = (const float*)d_in[3];
  const float* Wo = (const float*)d_in[4];
  float* out = (float*)d_out;

  char* w = (char*)d_ws;
  unsigned short* vbf = (unsigned short*)w; w += (size_t)2048 * 1024 * 2;
  unsigned short* wqk = (unsigned short*)w; w += (size_t)2048 * 1024 * 2;
  unsigned short* wvb = (unsigned short*)w; w += (size_t)1024 * 1024 * 2;
  unsigned short* wob = (unsigned short*)w; w += (size_t)1024 * 1024 * 2;
  unsigned short* vtb = (unsigned short*)w; w += (size_t)1024 * 2048 * 2;
  unsigned short* qb  = (unsigned short*)w; w += (size_t)2048 * 1024 * 2;
  unsigned short* kb  = (unsigned short*)w; w += (size_t)2048 * 1024 * 2;
  unsigned short* aob = (unsigned short*)w; w += (size_t)2048 * 1024 * 2;
  unsigned short* c2  = (unsigned short*)w; w += (size_t)2048 * 1024 * 2;

  prep_and_conv<<<6144, 256, 0, stream>>>(x, Wq, Wk, Wv, Wo, vbf, wqk, wvb, wob);

  gemm_qkv<<<512, 256, 0, stream>>>(vbf, wqk, wvb, qb, kb, vtb);

  attn_mfma<<<512, 256, 0, stream>>>(qb, kb, vtb, aob);

  gemm_wo<<<256, 256, 0, stream>>>(aob, wob, c2);
  expmap_project<<<2048, 256, 0, stream>>>(c2, out);
}

// Round 15
// 78.013 us; speedup vs baseline: 1.1002x; 1.0199x over previous
//
#include <hip/hip_runtime.h>

#define EPSF 1e-6f

typedef __bf16 bf16x8 __attribute__((ext_vector_type(8)));
typedef __bf16 bf16x4 __attribute__((ext_vector_type(4)));
typedef float f32x4 __attribute__((ext_vector_type(4)));
typedef __attribute__((address_space(3))) unsigned int as3_uint;
typedef __attribute__((address_space(1))) const unsigned int as1_uint;

// Native cast: compiler emits v_cvt_pk_bf16_f32 and pairs conversions (m240).
__device__ __forceinline__ unsigned short f2bf(float f) {
  return __builtin_bit_cast(unsigned short, (__bf16)f);
}
__device__ __forceinline__ float bf2f(unsigned short u) {
  unsigned int v = (unsigned int)u << 16;
  return __builtin_bit_cast(float, v);
}

// ------- fused: log_map(x) -> vbf (blocks 0..2047) | weight conv (blocks 2048..6143) -------
__global__ __launch_bounds__(256) void prep_and_conv(
    const float* __restrict__ x, const float* __restrict__ Wq,
    const float* __restrict__ Wk, const float* __restrict__ Wv,
    const float* __restrict__ Wo, unsigned short* __restrict__ vbf,
    unsigned short* __restrict__ wqk, unsigned short* __restrict__ wvb,
    unsigned short* __restrict__ wob) {
  int bid = blockIdx.x;
  int tid = threadIdx.x;
  if (bid >= 2048) {
    int t = bid - 2048;
    int y = t >> 10;
    const float* src = (y == 0) ? Wq : (y == 1) ? Wk : (y == 2) ? Wv : Wo;
    unsigned short* dst = (y == 0) ? wqk : (y == 1) ? wqk + 1048576
                          : (y == 2) ? wvb : wob;
    int i = (t & 1023) * 256 + tid;
    f32x4 v = ((const f32x4*)src)[i];
    ushort4 o;
    o.x = f2bf(v[0]); o.y = f2bf(v[1]); o.z = f2bf(v[2]); o.w = f2bf(v[3]);
    ((ushort4*)dst)[i] = o;
    return;
  }
  int row = bid;
  const float* xr = x + (size_t)row * 1024;
  f32x4 xv = *(const f32x4*)&xr[tid * 4];
  float vals[4];
  float ssq = 0.f;
#pragma unroll
  for (int i = 0; i < 4; ++i) {
    float t = xv[i];
    if (tid == 0 && i == 0) {
      vals[i] = 0.f;
    } else {
      t = fminf(fmaxf(t, -8.f), 8.f);
      vals[i] = t;
      ssq += t * t;
    }
  }
#pragma unroll
  for (int off = 32; off; off >>= 1) ssq += __shfl_xor(ssq, off);
  __shared__ float red[4];
  int wv = tid >> 6;
  if ((tid & 63) == 0) red[wv] = ssq;
  __syncthreads();
  ssq = red[0] + red[1] + red[2] + red[3];

  float y0 = sqrtf(1.f + ssq + EPSF);
  float xy = fminf(-y0, -(1.f + EPSF));
  float mxy = fmaxf(-xy, 1.f + EPSF);
  float dd = fmaxf(acoshf(mxy), 0.001f);
  float d0 = y0 + xy;
  float inn = ssq - d0 * d0;
  float dn = sqrtf(fmaxf(inn, EPSF));
  float inv = dd / (dn + EPSF);

  unsigned short* vr = vbf + (size_t)row * 1024;
  ushort4 o4;
  o4.x = f2bf((tid == 0) ? d0 * inv : vals[0] * inv);
  o4.y = f2bf(vals[1] * inv);
  o4.z = f2bf(vals[2] * inv);
  o4.w = f2bf(vals[3] * inv);
  *(ushort4*)&vr[tid * 4] = o4;
}

// ---------- 128x128-tile GEMM body, double-buffered gload_lds staging ----------
__device__ __forceinline__ void gemm128_dbuf(
    const unsigned short* __restrict__ A, const unsigned short* __restrict__ Bw,
    int K, int row0, int col0, unsigned short* As, unsigned short* Bs,
    f32x4 (*acc)[4]) {
  int tid = threadIdx.x;
  int lane = tid & 63, w = tid >> 6;
  int wm = (w >> 1) * 64, wn = (w & 1) * 64;
  int lq = lane & 15, g = lane >> 4;
  const unsigned short* Ag =
      A + (size_t)(row0 + w * 8 + (lane >> 3)) * K + (lane & 7) * 8;
  const unsigned short* Bg =
      Bw + (size_t)(col0 + w * 8 + (lane >> 3)) * K + (lane & 7) * 8;

  auto stage = [&](int buf, int k0) {
#pragma unroll
    for (int it = 0; it < 4; ++it) {
      __builtin_amdgcn_global_load_lds(
          (as1_uint*)(Ag + (size_t)(it * 32) * K + k0),
          (as3_uint*)&As[buf * 8192 + (it * 32 + w * 8) * 64], 16, 0, 0);
      __builtin_amdgcn_global_load_lds(
          (as1_uint*)(Bg + (size_t)(it * 32) * K + k0),
          (as3_uint*)&Bs[buf * 8192 + (it * 32 + w * 8) * 64], 16, 0, 0);
    }
  };

  stage(0, 0);
  int buf = 0;
  for (int k0 = 0; k0 < K; k0 += 64) {
    __syncthreads();
    if (k0 + 64 < K) stage(buf ^ 1, k0 + 64);
#pragma unroll
    for (int ks = 0; ks < 2; ++ks) {
      bf16x8 af[4], bfr[4];
#pragma unroll
      for (int i = 0; i < 4; ++i)
        af[i] = *(const bf16x8*)&As[buf * 8192 + (wm + i * 16 + lq) * 64 + ks * 32 + g * 8];
#pragma unroll
      for (int j = 0; j < 4; ++j)
        bfr[j] = *(const bf16x8*)&Bs[buf * 8192 + (wn + j * 16 + lq) * 64 + ks * 32 + g * 8];
#pragma unroll
      for (int i = 0; i < 4; ++i)
#pragma unroll
        for (int j = 0; j < 4; ++j)
          acc[i][j] =
              __builtin_amdgcn_mfma_f32_16x16x32_bf16(af[i], bfr[j], acc[i][j], 0, 0, 0);
    }
    buf ^= 1;
  }
}

// QK gemm 128x128 (256 tiles) | Vt gemm 128x64 (256 tiles).
// XCD-aware: XCD x (bid&7) gets tiles x*32+s; s<32 -> QK, s>=32 -> Vt.
__global__ __launch_bounds__(256) void gemm_qkv(
    const unsigned short* __restrict__ vbf, const unsigned short* __restrict__ wqk,
    const unsigned short* __restrict__ wvb, unsigned short* __restrict__ qb,
    unsigned short* __restrict__ kb, unsigned short* __restrict__ vtb) {
  __shared__ unsigned short As[2 * 8192];
  __shared__ unsigned short Bs[2 * 8192];
  int tid = threadIdx.x;
  int lane = tid & 63, w = tid >> 6;
  int lq = lane & 15, g = lane >> 4;
  int bid = blockIdx.x;
  int xcd = bid & 7, s = bid >> 3;

  if (s < 32) {
    int q = xcd * 32 + s;  // 0..255
    int wm = (w >> 1) * 64, wn = (w & 1) * 64;
    f32x4 acc[4][4] = {};
    int row0 = (q & 15) * 128, col0 = (q >> 4) * 128;
    gemm128_dbuf(vbf, wqk, 1024, row0, col0, As, Bs, acc);
    int headg = (col0 + wn) >> 6;  // 0..31 (0-15 q heads, 16-31 k heads)
    int qmode = (headg < 16) ? 1 : 0;
    unsigned short* dst = qmode ? qb : kb;
    size_t colb = (size_t)(headg & 15) * 64;
    float scale = qmode ? 0.125f : 1.f;
#pragma unroll
    for (int i = 0; i < 4; ++i)
#pragma unroll
      for (int r = 0; r < 4; ++r) {
        float sm = 0.f;
#pragma unroll
        for (int j = 0; j < 4; ++j) {
          float vc = fminf(fmaxf(acc[i][j][r], -5.f), 5.f);
          sm += (j == 0 && lq == 0) ? 0.f : vc * vc;  // exclude head col 0
        }
        sm += __shfl_xor(sm, 1);
        sm += __shfl_xor(sm, 2);
        sm += __shfl_xor(sm, 4);
        sm += __shfl_xor(sm, 8);
        float x0 = sqrtf(1.f + sm + EPSF);
        int row = row0 + wm + i * 16 + g * 4 + r;
#pragma unroll
        for (int j = 0; j < 4; ++j) {
          float vc = fminf(fmaxf(acc[i][j][r], -5.f), 5.f);
          float o = (j == 0 && lq == 0) ? (qmode ? -x0 : x0) : vc;
          dst[(size_t)row * 1024 + colb + j * 16 + lq] = f2bf(o * scale);
        }
      }
  } else {
    int t = xcd * 32 + (s - 32);  // 0..255 : Vt 128x64 tile
    int wm = (w >> 1) * 64, wn = (w & 1) * 32;
    int row0 = (t & 7) * 128, col0 = (t >> 3) * 64;
    f32x4 acc[4][2] = {};
    const unsigned short* Ag =
        wvb + (size_t)(row0 + w * 8 + (lane >> 3)) * 1024 + (lane & 7) * 8;
    const unsigned short* Bg =
        vbf + (size_t)(col0 + w * 8 + (lane >> 3)) * 1024 + (lane & 7) * 8;
    auto stage = [&](int buf, int k0) {
#pragma unroll
      for (int it = 0; it < 4; ++it)
        __builtin_amdgcn_global_load_lds(
            (as1_uint*)(Ag + (size_t)(it * 32) * 1024 + k0),
            (as3_uint*)&As[buf * 8192 + (it * 32 + w * 8) * 64], 16, 0, 0);
#pragma unroll
      for (int it = 0; it < 2; ++it)
        __builtin_amdgcn_global_load_lds(
            (as1_uint*)(Bg + (size_t)(it * 32) * 1024 + k0),
            (as3_uint*)&Bs[buf * 4096 + (it * 32 + w * 8) * 64], 16, 0, 0);
    };
    stage(0, 0);
    int buf = 0;
    for (int k0 = 0; k0 < 1024; k0 += 64) {
      __syncthreads();
      if (k0 + 64 < 1024) stage(buf ^ 1, k0 + 64);
#pragma unroll
      for (int ks = 0; ks < 2; ++ks) {
        bf16x8 af[4], bfr[2];
#pragma unroll
        for (int i = 0; i < 4; ++i)
          af[i] = *(const bf16x8*)&As[buf * 8192 + (wm + i * 16 + lq) * 64 + ks * 32 + g * 8];
#pragma unroll
        for (int j = 0; j < 2; ++j)
          bfr[j] = *(const bf16x8*)&Bs[buf * 4096 + (wn + j * 16 + lq) * 64 + ks * 32 + g * 8];
#pragma unroll
        for (int i = 0; i < 4; ++i)
#pragma unroll
          for (int j = 0; j < 2; ++j)
            acc[i][j] =
                __builtin_amdgcn_mfma_f32_16x16x32_bf16(af[i], bfr[j], acc[i][j], 0, 0, 0);
      }
      buf ^= 1;
    }
#pragma unroll
    for (int i = 0; i < 4; ++i)
#pragma unroll
      for (int j = 0; j < 2; ++j)
#pragma unroll
        for (int r = 0; r < 4; ++r)
          vtb[(size_t)(row0 + wm + i * 16 + g * 4 + r) * 2048 + col0 + wn + j * 16 + lq] =
              f2bf(acc[i][j][r]);
  }
}

// Wo gemm: BM=64 BN=64 -> 512 blocks (2/CU for cross-block drain hiding).
// XCD-aware: XCD x gets tiles x*64+s -> all 32 row-panels x 2 col-panels (L2 reuse).
__global__ __launch_bounds__(256) void gemm_wo(
    const unsigned short* __restrict__ A, const unsigned short* __restrict__ Bw,
    unsigned short* __restrict__ C) {
  __shared__ unsigned short As[2 * 4096];
  __shared__ unsigned short Bs[2 * 4096];
  int tid = threadIdx.x;
  int lane = tid & 63, w = tid >> 6;
  int wm = (w >> 1) * 32, wn = (w & 1) * 32;
  int lq = lane & 15, g = lane >> 4;
  int t = (blockIdx.x & 7) * 64 + (blockIdx.x >> 3);  // XCD-grouped tile id
  int row0 = (t & 31) * 64, col0 = (t >> 5) * 64;
  f32x4 acc[2][2] = {};
  const unsigned short* Ag =
      A + (size_t)(row0 + w * 8 + (lane >> 3)) * 1024 + (lane & 7) * 8;
  const unsigned short* Bg =
      Bw + (size_t)(col0 + w * 8 + (lane >> 3)) * 1024 + (lane & 7) * 8;

  auto stage = [&](int buf, int k0) {
#pragma unroll
    for (int it = 0; it < 2; ++it) {
      __builtin_amdgcn_global_load_lds(
          (as1_uint*)(Ag + (size_t)(it * 32) * 1024 + k0),
          (as3_uint*)&As[buf * 4096 + (it * 32 + w * 8) * 64], 16, 0, 0);
      __builtin_amdgcn_global_load_lds(
          (as1_uint*)(Bg + (size_t)(it * 32) * 1024 + k0),
          (as3_uint*)&Bs[buf * 4096 + (it * 32 + w * 8) * 64], 16, 0, 0);
    }
  };

  stage(0, 0);
  int buf = 0;
  for (int k0 = 0; k0 < 1024; k0 += 64) {
    __syncthreads();
    if (k0 + 64 < 1024) stage(buf ^ 1, k0 + 64);
#pragma unroll
    for (int ks = 0; ks < 2; ++ks) {
      bf16x8 af[2], bfr[2];
#pragma unroll
      for (int i = 0; i < 2; ++i)
        af[i] = *(const bf16x8*)&As[buf * 4096 + (wm + i * 16 + lq) * 64 + ks * 32 + g * 8];
#pragma unroll
      for (int j = 0; j < 2; ++j)
        bfr[j] = *(const bf16x8*)&Bs[buf * 4096 + (wn + j * 16 + lq) * 64 + ks * 32 + g * 8];
#pragma unroll
      for (int i = 0; i < 2; ++i)
#pragma unroll
        for (int j = 0; j < 2; ++j)
          acc[i][j] =
              __builtin_amdgcn_mfma_f32_16x16x32_bf16(af[i], bfr[j], acc[i][j], 0, 0, 0);
    }
    buf ^= 1;
  }
#pragma unroll
  for (int i = 0; i < 2; ++i)
#pragma unroll
    for (int j = 0; j < 2; ++j)
#pragma unroll
      for (int r = 0; r < 4; ++r)
        C[(size_t)(row0 + wm + i * 16 + g * 4 + r) * 1024 + col0 + wn + j * 16 + lq] =
            f2bf(acc[i][j][r]);
}

// ---- MFMA flash attention: 4 waves, QBLK=64, KVBLK=128, gload_lds dbuf,
//      XCD-grouped, defer-max, setprio, native-cvt P pack ----
__global__ __launch_bounds__(256) void attn_mfma(
    const unsigned short* __restrict__ Qb, const unsigned short* __restrict__ Kb,
    const unsigned short* __restrict__ Vtb, unsigned short* __restrict__ Obf) {
  __shared__ unsigned short Ks[2][128 * 64];   // K rows x d
  __shared__ unsigned short Vs[2][64 * 128];   // d rows x tokens
  __shared__ unsigned short Ps[4 * 16 * 128];
  int tid = threadIdx.x;
  int lane = tid & 63, w = tid >> 6;
  int g = lane >> 4, lq = lane & 15;
  int bid = blockIdx.x;
  int idx = bid >> 3;               // 0..63
  int bh = (bid & 7) * 4 + (idx & 3);
  int qt = idx >> 2;                // 0..15
  int b = bh >> 4, h = bh & 15;

  const unsigned short* qrow =
      Qb + (size_t)(b * 1024 + qt * 64 + w * 16 + lq) * 1024 + h * 64;
  bf16x8 qf0 = *(const bf16x8*)(qrow + g * 8);
  bf16x8 qf1 = *(const bf16x8*)(qrow + 32 + g * 8);

  float mreg = -1e30f, lreg = 0.f;
  f32x4 acc[4] = {};
  unsigned short* Pw = Ps + w * 16 * 128;
  int sx = 8 * (lq & 7);

  const unsigned short* Ksrc = Kb + (size_t)(b * 1024) * 1024 + h * 64;
  const unsigned short* Vsrc = Vtb + (size_t)(h * 64) * 2048 + b * 1024;

  int skr = lane >> 3;
  int scgk = (lane & 7) ^ skr;
  const unsigned short* Kp = Ksrc + (size_t)(w * 8 + skr) * 1024 + scgk * 8;
  int svr = w * 4 + (lane >> 4);  // 0..15
  int scgv = (lane & 15) ^ (svr & 7);
  const unsigned short* Vp = Vsrc + (size_t)svr * 2048 + scgv * 8;

  auto stage = [&](int buf, int kt) {
#pragma unroll
    for (int it = 0; it < 4; ++it) {
      __builtin_amdgcn_global_load_lds(
          (as1_uint*)(Kp + (size_t)(kt * 128 + it * 32) * 1024),
          (as3_uint*)&Ks[buf][(it * 32 + w * 8) * 64], 16, 0, 0);
      __builtin_amdgcn_global_load_lds(
          (as1_uint*)(Vp + (size_t)(it * 16) * 2048 + kt * 128),
          (as3_uint*)&Vs[buf][(it * 16 + w * 4) * 128], 16, 0, 0);
    }
  };

  auto compute = [&](int buf) {
    f32x4 st[8];
    __builtin_amdgcn_s_setprio(1);
#pragma unroll
    for (int i = 0; i < 8; ++i) {
      int ro = i * 16 + lq;
      int rb = ro * 64, xx = 8 * (ro & 7);
      bf16x8 a0 = *(const bf16x8*)&Ks[buf][rb + ((g * 8) ^ xx)];
      bf16x8 a1 = *(const bf16x8*)&Ks[buf][rb + ((32 + g * 8) ^ xx)];
      f32x4 z = {};
      z = __builtin_amdgcn_mfma_f32_16x16x32_bf16(a0, qf0, z, 0, 0, 0);
      st[i] = __builtin_amdgcn_mfma_f32_16x16x32_bf16(a1, qf1, z, 0, 0, 0);
    }
    __builtin_amdgcn_s_setprio(0);
    // max3-friendly tree reduction over 32 scores
    float m4[8];
#pragma unroll
    for (int i = 0; i < 8; ++i)
      m4[i] = fmaxf(fmaxf(st[i][0], st[i][1]), fmaxf(st[i][2], st[i][3]));
    float m01 = fmaxf(fmaxf(m4[0], m4[1]), fmaxf(m4[2], m4[3]));
    float m23 = fmaxf(fmaxf(m4[4], m4[5]), fmaxf(m4[6], m4[7]));
    float pmax = fmaxf(m01, m23);
    pmax = fmaxf(pmax, __shfl_xor(pmax, 16));
    pmax = fmaxf(pmax, __shfl_xor(pmax, 32));
    if (__any(pmax > mreg + 8.f)) {
      float nm = fmaxf(mreg, pmax);
      float sc_ = __expf(mreg - nm);
      mreg = nm;
      lreg *= sc_;
      float scr[4];
#pragma unroll
      for (int r = 0; r < 4; ++r) scr[r] = __shfl(sc_, g * 4 + r);
#pragma unroll
      for (int jj = 0; jj < 4; ++jj)
#pragma unroll
        for (int r = 0; r < 4; ++r) acc[jj][r] *= scr[r];
    }
    float ps = 0.f;
#pragma unroll
    for (int i = 0; i < 8; ++i) {
      float p0 = __expf(st[i][0] - mreg);
      float p1 = __expf(st[i][1] - mreg);
      float p2 = __expf(st[i][2] - mreg);
      float p3 = __expf(st[i][3] - mreg);
      ps += (p0 + p1) + (p2 + p3);
      bf16x4 pv;
      pv[0] = (__bf16)p0; pv[1] = (__bf16)p1;
      pv[2] = (__bf16)p2; pv[3] = (__bf16)p3;  // -> v_cvt_pk_bf16_f32 x2
      *(bf16x4*)&Pw[lq * 128 + ((g * 4 + i * 16) ^ sx)] = pv;
    }
    ps += __shfl_xor(ps, 16);
    ps += __shfl_xor(ps, 32);
    lreg += ps;

    __builtin_amdgcn_s_setprio(1);
#pragma unroll
    for (int ks = 0; ks < 4; ++ks) {
      bf16x8 pa = *(const bf16x8*)&Pw[lq * 128 + ((ks * 32 + g * 8) ^ sx)];
#pragma unroll
      for (int jj = 0; jj < 4; ++jj) {
        int vr = 16 * jj + lq;
        bf16x8 vb = *(const bf16x8*)&Vs[buf][vr * 128 + ((ks * 32 + g * 8) ^ (8 * (vr & 7)))];
        acc[jj] = __builtin_amdgcn_mfma_f32_16x16x32_bf16(pa, vb, acc[jj], 0, 0, 0);
      }
    }
    __builtin_amdgcn_s_setprio(0);
  };

  stage(0, 0);
  int buf = 0;
  for (int kt = 0; kt < 8; ++kt) {
    __syncthreads();
    if (kt + 1 < 8) stage(buf ^ 1, kt + 1);
    compute(buf);
    buf ^= 1;
  }

  float linv = 1.f / lreg;
  float ilr[4];
#pragma unroll
  for (int r = 0; r < 4; ++r) ilr[r] = __shfl(linv, g * 4 + r);
  unsigned short* obase =
      Obf + (size_t)(b * 1024 + qt * 64 + w * 16) * 1024 + h * 64;
#pragma unroll
  for (int r = 0; r < 4; ++r)
#pragma unroll
    for (int jj = 0; jj < 4; ++jj)
      obase[(size_t)(g * 4 + r) * 1024 + 16 * jj + lq] = f2bf(acc[jj][r] * ilr[r]);
}

// ---------------- exp_map at origin + project (bf16 in, f32 out), vectorized ----------------
__global__ __launch_bounds__(256) void expmap_project(
    const unsigned short* __restrict__ c2, float* __restrict__ out) {
  int row = blockIdx.x;
  int tid = threadIdx.x;
  const unsigned short* cr = c2 + (size_t)row * 1024;
  ushort4 cv = *(const ushort4*)&cr[tid * 4];
  float vals[4];
  vals[0] = (tid == 0) ? 0.f : bf2f(cv.x);
  vals[1] = bf2f(cv.y);
  vals[2] = bf2f(cv.z);
  vals[3] = bf2f(cv.w);
  float ssq = vals[0] * vals[0] + vals[1] * vals[1] +
              vals[2] * vals[2] + vals[3] * vals[3];
#pragma unroll
  for (int off = 32; off; off >>= 1) ssq += __shfl_xor(ssq, off);
  __shared__ float red1[4], red2[4];
  int wv = tid >> 6;
  if ((tid & 63) == 0) red1[wv] = ssq;
  __syncthreads();
  ssq = red1[0] + red1[1] + red1[2] + red1[3];
  float vn = fminf(sqrtf(ssq + EPSF), 5.f);
  float bf = sinhf(vn) / (vn + EPSF);
  float s2 = 0.f;
#pragma unroll
  for (int i = 0; i < 4; ++i) {
    float r = fminf(fmaxf(bf * vals[i], -8.f), 8.f);
    vals[i] = r;
    s2 += r * r;
  }
#pragma unroll
  for (int off = 32; off; off >>= 1) s2 += __shfl_xor(s2, off);
  if ((tid & 63) == 0) red2[wv] = s2;
  __syncthreads();
  s2 = red2[0] + red2[1] + red2[2] + red2[3];
  float x0 = sqrtf(1.f + s2 + EPSF);
  float* orow = out + (size_t)row * 1024;
  f32x4 ov;
  ov[0] = (tid == 0) ? x0 : vals[0];
  ov[1] = vals[1];
  ov[2] = vals[2];
  ov[3] = vals[3];
  *(f32x4*)&orow[tid * 4] = ov;
}

extern "C" void kernel_launch(void* const* d_in, const int* in_sizes, int n_in,
                              void* d_out, int out_size, void* d_ws, size_t ws_size,
                              hipStream_t stream) {
  (void)in_sizes; (void)n_in; (void)out_size; (void)ws_size;
  const float* x  = (const float*)d_in[0];
  const float* Wq = (const float*)d_in[1];
  const float* Wk = (const float*)d_in[2];
  const float* Wv = (const float*)d_in[3];
  const float* Wo = (const float*)d_in[4];
  float* out = (float*)d_out;

  char* w = (char*)d_ws;
  unsigned short* vbf = (unsigned short*)w; w += (size_t)2048 * 1024 * 2;
  unsigned short* wqk = (unsigned short*)w; w += (size_t)2048 * 1024 * 2;
  unsigned short* wvb = (unsigned short*)w; w += (size_t)1024 * 1024 * 2;
  unsigned short* wob = (unsigned short*)w; w += (size_t)1024 * 1024 * 2;
  unsigned short* vtb = (unsigned short*)w; w += (size_t)1024 * 2048 * 2;
  unsigned short* qb  = (unsigned short*)w; w += (size_t)2048 * 1024 * 2;
  unsigned short* kb  = (unsigned short*)w; w += (size_t)2048 * 1024 * 2;
  unsigned short* aob = (unsigned short*)w; w += (size_t)2048 * 1024 * 2;
  unsigned short* c2  = (unsigned short*)w; w += (size_t)2048 * 1024 * 2;

  prep_and_conv<<<6144, 256, 0, stream>>>(x, Wq, Wk, Wv, Wo, vbf, wqk, wvb, wob);

  gemm_qkv<<<512, 256, 0, stream>>>(vbf, wqk, wvb, qb, kb, vtb);

  attn_mfma<<<512, 256, 0, stream>>>(qb, kb, vtb, aob);

  gemm_wo<<<512, 256, 0, stream>>>(aob, wob, c2);
  expmap_project<<<2048, 256, 0, stream>>>(c2, out);
}

// Round 16
// 77.938 us; speedup vs baseline: 1.1013x; 1.0010x over previous
//
#include <hip/hip_runtime.h>

#define EPSF 1e-6f

typedef __bf16 bf16x8 __attribute__((ext_vector_type(8)));
typedef __bf16 bf16x4 __attribute__((ext_vector_type(4)));
typedef float f32x4 __attribute__((ext_vector_type(4)));
typedef __attribute__((address_space(3))) unsigned int as3_uint;
typedef __attribute__((address_space(1))) const unsigned int as1_uint;

// Native cast: compiler emits v_cvt_pk_bf16_f32 and pairs conversions (m240).
__device__ __forceinline__ unsigned short f2bf(float f) {
  return __builtin_bit_cast(unsigned short, (__bf16)f);
}
__device__ __forceinline__ float bf2f(unsigned short u) {
  unsigned int v = (unsigned int)u << 16;
  return __builtin_bit_cast(float, v);
}

// ------- fused: log_map(x) -> vbf (blocks 0..2047) | weight conv (blocks 2048..6143) -------
__global__ __launch_bounds__(256) void prep_and_conv(
    const float* __restrict__ x, const float* __restrict__ Wq,
    const float* __restrict__ Wk, const float* __restrict__ Wv,
    const float* __restrict__ Wo, unsigned short* __restrict__ vbf,
    unsigned short* __restrict__ wqk, unsigned short* __restrict__ wvb,
    unsigned short* __restrict__ wob) {
  int bid = blockIdx.x;
  int tid = threadIdx.x;
  if (bid >= 2048) {
    int t = bid - 2048;
    int y = t >> 10;
    const float* src = (y == 0) ? Wq : (y == 1) ? Wk : (y == 2) ? Wv : Wo;
    unsigned short* dst = (y == 0) ? wqk : (y == 1) ? wqk + 1048576
                          : (y == 2) ? wvb : wob;
    int i = (t & 1023) * 256 + tid;
    f32x4 v = ((const f32x4*)src)[i];
    ushort4 o;
    o.x = f2bf(v[0]); o.y = f2bf(v[1]); o.z = f2bf(v[2]); o.w = f2bf(v[3]);
    ((ushort4*)dst)[i] = o;
    return;
  }
  int row = bid;
  const float* xr = x + (size_t)row * 1024;
  f32x4 xv = *(const f32x4*)&xr[tid * 4];
  float vals[4];
  float ssq = 0.f;
#pragma unroll
  for (int i = 0; i < 4; ++i) {
    float t = xv[i];
    if (tid == 0 && i == 0) {
      vals[i] = 0.f;
    } else {
      t = fminf(fmaxf(t, -8.f), 8.f);
      vals[i] = t;
      ssq += t * t;
    }
  }
#pragma unroll
  for (int off = 32; off; off >>= 1) ssq += __shfl_xor(ssq, off);
  __shared__ float red[4];
  int wv = tid >> 6;
  if ((tid & 63) == 0) red[wv] = ssq;
  __syncthreads();
  ssq = red[0] + red[1] + red[2] + red[3];

  float y0 = sqrtf(1.f + ssq + EPSF);
  float xy = fminf(-y0, -(1.f + EPSF));
  float mxy = fmaxf(-xy, 1.f + EPSF);
  float dd = fmaxf(acoshf(mxy), 0.001f);
  float d0 = y0 + xy;
  float inn = ssq - d0 * d0;
  float dn = sqrtf(fmaxf(inn, EPSF));
  float inv = dd / (dn + EPSF);

  unsigned short* vr = vbf + (size_t)row * 1024;
  ushort4 o4;
  o4.x = f2bf((tid == 0) ? d0 * inv : vals[0] * inv);
  o4.y = f2bf(vals[1] * inv);
  o4.z = f2bf(vals[2] * inv);
  o4.w = f2bf(vals[3] * inv);
  *(ushort4*)&vr[tid * 4] = o4;
}

// ---------- 128x128-tile GEMM body, double-buffered gload_lds staging ----------
__device__ __forceinline__ void gemm128_dbuf(
    const unsigned short* __restrict__ A, const unsigned short* __restrict__ Bw,
    int K, int row0, int col0, unsigned short* As, unsigned short* Bs,
    f32x4 (*acc)[4]) {
  int tid = threadIdx.x;
  int lane = tid & 63, w = tid >> 6;
  int wm = (w >> 1) * 64, wn = (w & 1) * 64;
  int lq = lane & 15, g = lane >> 4;
  const unsigned short* Ag =
      A + (size_t)(row0 + w * 8 + (lane >> 3)) * K + (lane & 7) * 8;
  const unsigned short* Bg =
      Bw + (size_t)(col0 + w * 8 + (lane >> 3)) * K + (lane & 7) * 8;

  auto stage = [&](int buf, int k0) {
#pragma unroll
    for (int it = 0; it < 4; ++it) {
      __builtin_amdgcn_global_load_lds(
          (as1_uint*)(Ag + (size_t)(it * 32) * K + k0),
          (as3_uint*)&As[buf * 8192 + (it * 32 + w * 8) * 64], 16, 0, 0);
      __builtin_amdgcn_global_load_lds(
          (as1_uint*)(Bg + (size_t)(it * 32) * K + k0),
          (as3_uint*)&Bs[buf * 8192 + (it * 32 + w * 8) * 64], 16, 0, 0);
    }
  };

  stage(0, 0);
  int buf = 0;
  for (int k0 = 0; k0 < K; k0 += 64) {
    __syncthreads();
    if (k0 + 64 < K) stage(buf ^ 1, k0 + 64);
#pragma unroll
    for (int ks = 0; ks < 2; ++ks) {
      bf16x8 af[4], bfr[4];
#pragma unroll
      for (int i = 0; i < 4; ++i)
        af[i] = *(const bf16x8*)&As[buf * 8192 + (wm + i * 16 + lq) * 64 + ks * 32 + g * 8];
#pragma unroll
      for (int j = 0; j < 4; ++j)
        bfr[j] = *(const bf16x8*)&Bs[buf * 8192 + (wn + j * 16 + lq) * 64 + ks * 32 + g * 8];
#pragma unroll
      for (int i = 0; i < 4; ++i)
#pragma unroll
        for (int j = 0; j < 4; ++j)
          acc[i][j] =
              __builtin_amdgcn_mfma_f32_16x16x32_bf16(af[i], bfr[j], acc[i][j], 0, 0, 0);
    }
    buf ^= 1;
  }
}

// QK gemm 128x128 (256 tiles) | Vt gemm 128x64 (256 tiles).
// XCD-aware with L2-fitting working sets:
//   QK: XCD x gets rows [4*(x&3),+4) x cols [8*(x>>2),+8)  -> 1MB A + 2MB B < 4MB L2.
//   Vt: XCD x gets all 8 row-panels x cols [4x,+4)         -> 2MB A + 0.5MB B.
__global__ __launch_bounds__(256) void gemm_qkv(
    const unsigned short* __restrict__ vbf, const unsigned short* __restrict__ wqk,
    const unsigned short* __restrict__ wvb, unsigned short* __restrict__ qb,
    unsigned short* __restrict__ kb, unsigned short* __restrict__ vtb) {
  __shared__ unsigned short As[2 * 8192];
  __shared__ unsigned short Bs[2 * 8192];
  int tid = threadIdx.x;
  int lane = tid & 63, w = tid >> 6;
  int lq = lane & 15, g = lane >> 4;
  int bid = blockIdx.x;
  int xcd = bid & 7, s = bid >> 3;

  if (s < 32) {
    // QK tile: 4 row-panels x 8 col-panels per XCD (L2-resident)
    int qrow = 4 * (xcd & 3) + (s & 3);    // 0..15
    int qcol = 8 * (xcd >> 2) + (s >> 2);  // 0..15
    int wm = (w >> 1) * 64, wn = (w & 1) * 64;
    f32x4 acc[4][4] = {};
    int row0 = qrow * 128, col0 = qcol * 128;
    gemm128_dbuf(vbf, wqk, 1024, row0, col0, As, Bs, acc);
    int headg = (col0 + wn) >> 6;  // 0..31 (0-15 q heads, 16-31 k heads)
    int qmode = (headg < 16) ? 1 : 0;
    unsigned short* dst = qmode ? qb : kb;
    size_t colb = (size_t)(headg & 15) * 64;
    float scale = qmode ? 0.125f : 1.f;
#pragma unroll
    for (int i = 0; i < 4; ++i)
#pragma unroll
      for (int r = 0; r < 4; ++r) {
        float sm = 0.f;
#pragma unroll
        for (int j = 0; j < 4; ++j) {
          float vc = fminf(fmaxf(acc[i][j][r], -5.f), 5.f);
          sm += (j == 0 && lq == 0) ? 0.f : vc * vc;  // exclude head col 0
        }
        sm += __shfl_xor(sm, 1);
        sm += __shfl_xor(sm, 2);
        sm += __shfl_xor(sm, 4);
        sm += __shfl_xor(sm, 8);
        float x0 = sqrtf(1.f + sm + EPSF);
        int row = row0 + wm + i * 16 + g * 4 + r;
#pragma unroll
        for (int j = 0; j < 4; ++j) {
          float vc = fminf(fmaxf(acc[i][j][r], -5.f), 5.f);
          float o = (j == 0 && lq == 0) ? (qmode ? -x0 : x0) : vc;
          dst[(size_t)row * 1024 + colb + j * 16 + lq] = f2bf(o * scale);
        }
      }
  } else {
    int t = xcd * 32 + (s - 32);  // 0..255 : Vt 128x64 tile
    int wm = (w >> 1) * 64, wn = (w & 1) * 32;
    int row0 = (t & 7) * 128, col0 = (t >> 3) * 64;
    f32x4 acc[4][2] = {};
    const unsigned short* Ag =
        wvb + (size_t)(row0 + w * 8 + (lane >> 3)) * 1024 + (lane & 7) * 8;
    const unsigned short* Bg =
        vbf + (size_t)(col0 + w * 8 + (lane >> 3)) * 1024 + (lane & 7) * 8;
    auto stage = [&](int buf, int k0) {
#pragma unroll
      for (int it = 0; it < 4; ++it)
        __builtin_amdgcn_global_load_lds(
            (as1_uint*)(Ag + (size_t)(it * 32) * 1024 + k0),
            (as3_uint*)&As[buf * 8192 + (it * 32 + w * 8) * 64], 16, 0, 0);
#pragma unroll
      for (int it = 0; it < 2; ++it)
        __builtin_amdgcn_global_load_lds(
            (as1_uint*)(Bg + (size_t)(it * 32) * 1024 + k0),
            (as3_uint*)&Bs[buf * 4096 + (it * 32 + w * 8) * 64], 16, 0, 0);
    };
    stage(0, 0);
    int buf = 0;
    for (int k0 = 0; k0 < 1024; k0 += 64) {
      __syncthreads();
      if (k0 + 64 < 1024) stage(buf ^ 1, k0 + 64);
#pragma unroll
      for (int ks = 0; ks < 2; ++ks) {
        bf16x8 af[4], bfr[2];
#pragma unroll
        for (int i = 0; i < 4; ++i)
          af[i] = *(const bf16x8*)&As[buf * 8192 + (wm + i * 16 + lq) * 64 + ks * 32 + g * 8];
#pragma unroll
        for (int j = 0; j < 2; ++j)
          bfr[j] = *(const bf16x8*)&Bs[buf * 4096 + (wn + j * 16 + lq) * 64 + ks * 32 + g * 8];
#pragma unroll
        for (int i = 0; i < 4; ++i)
#pragma unroll
          for (int j = 0; j < 2; ++j)
            acc[i][j] =
                __builtin_amdgcn_mfma_f32_16x16x32_bf16(af[i], bfr[j], acc[i][j], 0, 0, 0);
      }
      buf ^= 1;
    }
#pragma unroll
    for (int i = 0; i < 4; ++i)
#pragma unroll
      for (int j = 0; j < 2; ++j)
#pragma unroll
        for (int r = 0; r < 4; ++r)
          vtb[(size_t)(row0 + wm + i * 16 + g * 4 + r) * 2048 + col0 + wn + j * 16 + lq] =
              f2bf(acc[i][j][r]);
  }
}

// Wo gemm: BM=64 BN=64 -> 512 blocks (2/CU).
// XCD-aware L2-fitting: XCD x gets rows [8*(x&3),+8) x cols [8*(x>>2),+8) -> 2MB.
__global__ __launch_bounds__(256) void gemm_wo(
    const unsigned short* __restrict__ A, const unsigned short* __restrict__ Bw,
    unsigned short* __restrict__ C) {
  __shared__ unsigned short As[2 * 4096];
  __shared__ unsigned short Bs[2 * 4096];
  int tid = threadIdx.x;
  int lane = tid & 63, w = tid >> 6;
  int wm = (w >> 1) * 32, wn = (w & 1) * 32;
  int lq = lane & 15, g = lane >> 4;
  int xcd = blockIdx.x & 7, s = blockIdx.x >> 3;  // s in [0,64)
  int row0 = (8 * (xcd & 3) + (s & 7)) * 64;      // 32 row-panels
  int col0 = (8 * (xcd >> 2) + (s >> 3)) * 64;    // 16 col-panels
  f32x4 acc[2][2] = {};
  const unsigned short* Ag =
      A + (size_t)(row0 + w * 8 + (lane >> 3)) * 1024 + (lane & 7) * 8;
  const unsigned short* Bg =
      Bw + (size_t)(col0 + w * 8 + (lane >> 3)) * 1024 + (lane & 7) * 8;

  auto stage = [&](int buf, int k0) {
#pragma unroll
    for (int it = 0; it < 2; ++it) {
      __builtin_amdgcn_global_load_lds(
          (as1_uint*)(Ag + (size_t)(it * 32) * 1024 + k0),
          (as3_uint*)&As[buf * 4096 + (it * 32 + w * 8) * 64], 16, 0, 0);
      __builtin_amdgcn_global_load_lds(
          (as1_uint*)(Bg + (size_t)(it * 32) * 1024 + k0),
          (as3_uint*)&Bs[buf * 4096 + (it * 32 + w * 8) * 64], 16, 0, 0);
    }
  };

  stage(0, 0);
  int buf = 0;
  for (int k0 = 0; k0 < 1024; k0 += 64) {
    __syncthreads();
    if (k0 + 64 < 1024) stage(buf ^ 1, k0 + 64);
#pragma unroll
    for (int ks = 0; ks < 2; ++ks) {
      bf16x8 af[2], bfr[2];
#pragma unroll
      for (int i = 0; i < 2; ++i)
        af[i] = *(const bf16x8*)&As[buf * 4096 + (wm + i * 16 + lq) * 64 + ks * 32 + g * 8];
#pragma unroll
      for (int j = 0; j < 2; ++j)
        bfr[j] = *(const bf16x8*)&Bs[buf * 4096 + (wn + j * 16 + lq) * 64 + ks * 32 + g * 8];
#pragma unroll
      for (int i = 0; i < 2; ++i)
#pragma unroll
        for (int j = 0; j < 2; ++j)
          acc[i][j] =
              __builtin_amdgcn_mfma_f32_16x16x32_bf16(af[i], bfr[j], acc[i][j], 0, 0, 0);
    }
    buf ^= 1;
  }
#pragma unroll
  for (int i = 0; i < 2; ++i)
#pragma unroll
    for (int j = 0; j < 2; ++j)
#pragma unroll
      for (int r = 0; r < 4; ++r)
        C[(size_t)(row0 + wm + i * 16 + g * 4 + r) * 1024 + col0 + wn + j * 16 + lq] =
            f2bf(acc[i][j][r]);
}

// ---- MFMA flash attention: 4 waves, QBLK=64, KVBLK=128, gload_lds dbuf,
//      XCD-grouped, defer-max, setprio, native-cvt P pack ----
__global__ __launch_bounds__(256) void attn_mfma(
    const unsigned short* __restrict__ Qb, const unsigned short* __restrict__ Kb,
    const unsigned short* __restrict__ Vtb, unsigned short* __restrict__ Obf) {
  __shared__ unsigned short Ks[2][128 * 64];   // K rows x d
  __shared__ unsigned short Vs[2][64 * 128];   // d rows x tokens
  __shared__ unsigned short Ps[4 * 16 * 128];
  int tid = threadIdx.x;
  int lane = tid & 63, w = tid >> 6;
  int g = lane >> 4, lq = lane & 15;
  int bid = blockIdx.x;
  int idx = bid >> 3;               // 0..63
  int bh = (bid & 7) * 4 + (idx & 3);
  int qt = idx >> 2;                // 0..15
  int b = bh >> 4, h = bh & 15;

  const unsigned short* qrow =
      Qb + (size_t)(b * 1024 + qt * 64 + w * 16 + lq) * 1024 + h * 64;
  bf16x8 qf0 = *(const bf16x8*)(qrow + g * 8);
  bf16x8 qf1 = *(const bf16x8*)(qrow + 32 + g * 8);

  float mreg = -1e30f, lreg = 0.f;
  f32x4 acc[4] = {};
  unsigned short* Pw = Ps + w * 16 * 128;
  int sx = 8 * (lq & 7);

  const unsigned short* Ksrc = Kb + (size_t)(b * 1024) * 1024 + h * 64;
  const unsigned short* Vsrc = Vtb + (size_t)(h * 64) * 2048 + b * 1024;

  int skr = lane >> 3;
  int scgk = (lane & 7) ^ skr;
  const unsigned short* Kp = Ksrc + (size_t)(w * 8 + skr) * 1024 + scgk * 8;
  int svr = w * 4 + (lane >> 4);  // 0..15
  int scgv = (lane & 15) ^ (svr & 7);
  const unsigned short* Vp = Vsrc + (size_t)svr * 2048 + scgv * 8;

  auto stage = [&](int buf, int kt) {
#pragma unroll
    for (int it = 0; it < 4; ++it) {
      __builtin_amdgcn_global_load_lds(
          (as1_uint*)(Kp + (size_t)(kt * 128 + it * 32) * 1024),
          (as3_uint*)&Ks[buf][(it * 32 + w * 8) * 64], 16, 0, 0);
      __builtin_amdgcn_global_load_lds(
          (as1_uint*)(Vp + (size_t)(it * 16) * 2048 + kt * 128),
          (as3_uint*)&Vs[buf][(it * 16 + w * 4) * 128], 16, 0, 0);
    }
  };

  auto compute = [&](int buf) {
    f32x4 st[8];
    __builtin_amdgcn_s_setprio(1);
#pragma unroll
    for (int i = 0; i < 8; ++i) {
      int ro = i * 16 + lq;
      int rb = ro * 64, xx = 8 * (ro & 7);
      bf16x8 a0 = *(const bf16x8*)&Ks[buf][rb + ((g * 8) ^ xx)];
      bf16x8 a1 = *(const bf16x8*)&Ks[buf][rb + ((32 + g * 8) ^ xx)];
      f32x4 z = {};
      z = __builtin_amdgcn_mfma_f32_16x16x32_bf16(a0, qf0, z, 0, 0, 0);
      st[i] = __builtin_amdgcn_mfma_f32_16x16x32_bf16(a1, qf1, z, 0, 0, 0);
    }
    __builtin_amdgcn_s_setprio(0);
    // max3-friendly tree reduction over 32 scores
    float m4[8];
#pragma unroll
    for (int i = 0; i < 8; ++i)
      m4[i] = fmaxf(fmaxf(st[i][0], st[i][1]), fmaxf(st[i][2], st[i][3]));
    float m01 = fmaxf(fmaxf(m4[0], m4[1]), fmaxf(m4[2], m4[3]));
    float m23 = fmaxf(fmaxf(m4[4], m4[5]), fmaxf(m4[6], m4[7]));
    float pmax = fmaxf(m01, m23);
    pmax = fmaxf(pmax, __shfl_xor(pmax, 16));
    pmax = fmaxf(pmax, __shfl_xor(pmax, 32));
    if (__any(pmax > mreg + 8.f)) {
      float nm = fmaxf(mreg, pmax);
      float sc_ = __expf(mreg - nm);
      mreg = nm;
      lreg *= sc_;
      float scr[4];
#pragma unroll
      for (int r = 0; r < 4; ++r) scr[r] = __shfl(sc_, g * 4 + r);
#pragma unroll
      for (int jj = 0; jj < 4; ++jj)
#pragma unroll
        for (int r = 0; r < 4; ++r) acc[jj][r] *= scr[r];
    }
    float ps = 0.f;
#pragma unroll
    for (int i = 0; i < 8; ++i) {
      float p0 = __expf(st[i][0] - mreg);
      float p1 = __expf(st[i][1] - mreg);
      float p2 = __expf(st[i][2] - mreg);
      float p3 = __expf(st[i][3] - mreg);
      ps += (p0 + p1) + (p2 + p3);
      bf16x4 pv;
      pv[0] = (__bf16)p0; pv[1] = (__bf16)p1;
      pv[2] = (__bf16)p2; pv[3] = (__bf16)p3;  // -> v_cvt_pk_bf16_f32 x2
      *(bf16x4*)&Pw[lq * 128 + ((g * 4 + i * 16) ^ sx)] = pv;
    }
    ps += __shfl_xor(ps, 16);
    ps += __shfl_xor(ps, 32);
    lreg += ps;

    __builtin_amdgcn_s_setprio(1);
#pragma unroll
    for (int ks = 0; ks < 4; ++ks) {
      bf16x8 pa = *(const bf16x8*)&Pw[lq * 128 + ((ks * 32 + g * 8) ^ sx)];
#pragma unroll
      for (int jj = 0; jj < 4; ++jj) {
        int vr = 16 * jj + lq;
        bf16x8 vb = *(const bf16x8*)&Vs[buf][vr * 128 + ((ks * 32 + g * 8) ^ (8 * (vr & 7)))];
        acc[jj] = __builtin_amdgcn_mfma_f32_16x16x32_bf16(pa, vb, acc[jj], 0, 0, 0);
      }
    }
    __builtin_amdgcn_s_setprio(0);
  };

  stage(0, 0);
  int buf = 0;
  for (int kt = 0; kt < 8; ++kt) {
    __syncthreads();
    if (kt + 1 < 8) stage(buf ^ 1, kt + 1);
    compute(buf);
    buf ^= 1;
  }

  float linv = 1.f / lreg;
  float ilr[4];
#pragma unroll
  for (int r = 0; r < 4; ++r) ilr[r] = __shfl(linv, g * 4 + r);
  unsigned short* obase =
      Obf + (size_t)(b * 1024 + qt * 64 + w * 16) * 1024 + h * 64;
#pragma unroll
  for (int r = 0; r < 4; ++r)
#pragma unroll
    for (int jj = 0; jj < 4; ++jj)
      obase[(size_t)(g * 4 + r) * 1024 + 16 * jj + lq] = f2bf(acc[jj][r] * ilr[r]);
}

// ---------------- exp_map at origin + project (bf16 in, f32 out), vectorized ----------------
__global__ __launch_bounds__(256) void expmap_project(
    const unsigned short* __restrict__ c2, float* __restrict__ out) {
  int row = blockIdx.x;
  int tid = threadIdx.x;
  const unsigned short* cr = c2 + (size_t)row * 1024;
  ushort4 cv = *(const ushort4*)&cr[tid * 4];
  float vals[4];
  vals[0] = (tid == 0) ? 0.f : bf2f(cv.x);
  vals[1] = bf2f(cv.y);
  vals[2] = bf2f(cv.z);
  vals[3] = bf2f(cv.w);
  float ssq = vals[0] * vals[0] + vals[1] * vals[1] +
              vals[2] * vals[2] + vals[3] * vals[3];
#pragma unroll
  for (int off = 32; off; off >>= 1) ssq += __shfl_xor(ssq, off);
  __shared__ float red1[4], red2[4];
  int wv = tid >> 6;
  if ((tid & 63) == 0) red1[wv] = ssq;
  __syncthreads();
  ssq = red1[0] + red1[1] + red1[2] + red1[3];
  float vn = fminf(sqrtf(ssq + EPSF), 5.f);
  float bf = sinhf(vn) / (vn + EPSF);
  float s2 = 0.f;
#pragma unroll
  for (int i = 0; i < 4; ++i) {
    float r = fminf(fmaxf(bf * vals[i], -8.f), 8.f);
    vals[i] = r;
    s2 += r * r;
  }
#pragma unroll
  for (int off = 32; off; off >>= 1) s2 += __shfl_xor(s2, off);
  if ((tid & 63) == 0) red2[wv] = s2;
  __syncthreads();
  s2 = red2[0] + red2[1] + red2[2] + red2[3];
  float x0 = sqrtf(1.f + s2 + EPSF);
  float* orow = out + (size_t)row * 1024;
  f32x4 ov;
  ov[0] = (tid == 0) ? x0 : vals[0];
  ov[1] = vals[1];
  ov[2] = vals[2];
  ov[3] = vals[3];
  *(f32x4*)&orow[tid * 4] = ov;
}

extern "C" void kernel_launch(void* const* d_in, const int* in_sizes, int n_in,
                              void* d_out, int out_size, void* d_ws, size_t ws_size,
                              hipStream_t stream) {
  (void)in_sizes; (void)n_in; (void)out_size; (void)ws_size;
  const float* x  = (const float*)d_in[0];
  const float* Wq = (const float*)d_in[1];
  const float* Wk = (const float*)d_in[2];
  const float* Wv = (const float*)d_in[3];
  const float* Wo = (const float*)d_in[4];
  float* out = (float*)d_out;

  char* w = (char*)d_ws;
  unsigned short* vbf = (unsigned short*)w; w += (size_t)2048 * 1024 * 2;
  unsigned short* wqk = (unsigned short*)w; w += (size_t)2048 * 1024 * 2;
  unsigned short* wvb = (unsigned short*)w; w += (size_t)1024 * 1024 * 2;
  unsigned short* wob = (unsigned short*)w; w += (size_t)1024 * 1024 * 2;
  unsigned short* vtb = (unsigned short*)w; w += (size_t)1024 * 2048 * 2;
  unsigned short* qb  = (unsigned short*)w; w += (size_t)2048 * 1024 * 2;
  unsigned short* kb  = (unsigned short*)w; w += (size_t)2048 * 1024 * 2;
  unsigned short* aob = (unsigned short*)w; w += (size_t)2048 * 1024 * 2;
  unsigned short* c2  = (unsigned short*)w; w += (size_t)2048 * 1024 * 2;

  prep_and_conv<<<6144, 256, 0, stream>>>(x, Wq, Wk, Wv, Wo, vbf, wqk, wvb, wob);

  gemm_qkv<<<512, 256, 0, stream>>>(vbf, wqk, wvb, qb, kb, vtb);

  attn_mfma<<<512, 256, 0, stream>>>(qb, kb, vtb, aob);

  gemm_wo<<<512, 256, 0, stream>>>(aob, wob, c2);
  expmap_project<<<2048, 256, 0, stream>>>(c2, out);
}